// Round 15
// baseline (2933.810 us; speedup 1.0000x reference)
//
#include <hip/hip_runtime.h>

#define RR 64
#define BB 64
#define DD 256
#define DFF_ 1024
#define VV 32000
#define FF 7

#define TIE_BAND(a, b) (2e-6 * (1.0 + 0.5 * (fabs(a) + fabs(b))))
#define BR_CLAMP 0.30f
#define TOT_CLAMP 0.19f

__device__ __forceinline__ float clampf(float x, float c) {
  return fminf(fmaxf(x, -c), c);
}

// =================== naive f64 kernels (exact, hard gates) ===================

__global__ void n_hid(const float* __restrict__ x, const float* __restrict__ W1,
                      const float* __restrict__ b1, double* __restrict__ hid) {
  int idx = blockIdx.x * 256 + threadIdx.x;
  int r = idx >> 16;
  int b = (idx >> 10) & 63;
  int f = idx & 1023;
  const float* xp = x + ((size_t)(r * BB + b)) * DD;
  const float* wp = W1 + (size_t)r * DD * DFF_ + f;
  double a = 0.0;
  for (int d = 0; d < DD; ++d) a += (double)xp[d] * (double)wp[(size_t)d * DFF_];
  double v = a + (double)b1[r * DFF_ + f];
  hid[idx] = 0.5 * v * (1.0 + erf(v * 0.70710678118654752440));
}

__global__ void n_H(const double* __restrict__ hid, const float* __restrict__ W2,
                    const float* __restrict__ b2, double* __restrict__ H) {
  int idx = blockIdx.x * 256 + threadIdx.x;
  int r = idx >> 14;
  int b = (idx >> 8) & 63;
  int d = idx & 255;
  const double* hp = hid + ((size_t)(r * BB + b)) * DFF_;
  const float* wp = W2 + (size_t)r * DFF_ * DD + d;
  double a = 0.0;
  for (int f = 0; f < DFF_; ++f) a += hp[f] * (double)wp[(size_t)f * DD];
  double h = a + (double)b2[r * DD + d];
  H[idx] = h + 0.20333333 * h;
}

__global__ void n_scg(const double* __restrict__ H, const float* __restrict__ wg,
                      double* __restrict__ scg) {
  int idx = blockIdx.x * 256 + threadIdx.x;
  int r = idx >> 6, b = idx & 63;
  const double* hp = H + (size_t)idx * DD;
  double a = 0.0;
  for (int d = 0; d < DD; ++d) a += hp[d] * (double)wg[d];
  scg[b * RR + r] = a;
}

// hard mask + INCLUSIVE alt (threshold lowered to 7th => keep-7) when 6/7 gap ~ f32-tie
__global__ void n_mask_dual(const double* __restrict__ scg, float* __restrict__ maskH,
                            float* __restrict__ maskA) {
  int b = threadIdx.x;
  double v[64], w[64];
  for (int r = 0; r < RR; ++r) { v[r] = scg[b * RR + r]; w[r] = v[r]; }
  double k6 = 0.0, k7 = 0.0;
  for (int it = 0; it < 7; ++it) {
    int mi = 0;
    for (int r = 1; r < RR; ++r) if (w[r] > w[mi]) mi = r;
    if (it == 5) k6 = w[mi];
    if (it == 6) k7 = w[mi];
    w[mi] = -INFINITY;
  }
  double gap = k6 - k7;
  int tie = (gap > 0.0 && gap < TIE_BAND(k6, k7)) ? 1 : 0;
  for (int r = 0; r < RR; ++r) {
    float mh = (v[r] >= k6 || r == 0 || r == RR - 1) ? 1.f : 0.f;
    maskH[b * RR + r] = mh;
    maskA[b * RR + r] = tie ? ((v[r] >= k7 || r == 0 || r == RR - 1) ? 1.f : 0.f) : mh;
  }
}

__global__ void n_hs(const double* __restrict__ H, const float* __restrict__ mask,
                     double* __restrict__ Hs) {
  int idx = blockIdx.x * 256 + threadIdx.x;
  int r = idx >> 14;
  int b = (idx >> 8) & 63;
  Hs[idx] = H[idx] * (double)mask[b * RR + r];
}

// top-4 gated softmax, hard; optional INCLUSIVE alt (threshold s5 => keep-5) in tie band
__global__ void n_w6x(const double* __restrict__ self, const double* __restrict__ nb,
                      const int* __restrict__ nidx, double* __restrict__ wout,
                      double* __restrict__ walt, int band_on) {
  int idx = blockIdx.x * 256 + threadIdx.x;      // r*BB + b
  int r = idx >> 6, b = idx & 63;
  const double* sp = self + (size_t)idx * DD;
  double sc[6];
  for (int k = 0; k < 6; ++k) {
    int nr = nidx[r * 6 + k];
    const double* qp = nb + ((size_t)(nr * BB + b)) * DD;
    double a = 0.0;
    for (int d = 0; d < DD; ++d) a += sp[d] * qp[d];
    sc[k] = a * 0.0625;
  }
  double srt[6];
  for (int k = 0; k < 6; ++k) srt[k] = sc[k];
  for (int i = 0; i < 5; ++i) {
    int mi = i;
    for (int j = i + 1; j < 6; ++j) if (srt[j] > srt[mi]) mi = j;
    double tmp = srt[i]; srt[i] = srt[mi]; srt[mi] = tmp;
  }
  double s4 = srt[3], s5 = srt[4], mx = srt[0];
  double e[6], s = 0.0;
  for (int k = 0; k < 6; ++k) {
    e[k] = (sc[k] >= s4) ? exp(sc[k] - mx) : 0.0;
    s += e[k];
  }
  for (int k = 0; k < 6; ++k) wout[(size_t)idx * 6 + k] = e[k] / s;
  if (walt) {
    double gap = s4 - s5;
    if (band_on && gap > 0.0 && gap < TIE_BAND(s4, s5)) {
      double ea[6], sa = 0.0;
      for (int k = 0; k < 6; ++k) {
        ea[k] = (sc[k] >= s5) ? exp(sc[k] - mx) : 0.0;   // INCLUSIVE: keep-5
        sa += ea[k];
      }
      for (int k = 0; k < 6; ++k) walt[(size_t)idx * 6 + k] = ea[k] / sa;
    } else {
      for (int k = 0; k < 6; ++k) walt[(size_t)idx * 6 + k] = e[k] / s;
    }
  }
}

__global__ void n_mp(const double* __restrict__ w, const double* __restrict__ nb,
                     const int* __restrict__ nidx, double* __restrict__ mp) {
  int rb = blockIdx.x;
  int r = rb >> 6, b = rb & 63;
  int t = threadIdx.x;
  double a = 0.0;
  for (int k = 0; k < 6; ++k) {
    int nr = nidx[r * 6 + k];
    a += w[(size_t)rb * 6 + k] * nb[((size_t)(nr * BB + b)) * DD + t];
  }
  mp[(size_t)rb * DD + t] = a;
}

__global__ void n_mm_add(const double* __restrict__ mp, const float* __restrict__ Wmat,
                         const double* __restrict__ Hs, double* __restrict__ H2) {
  int rb = blockIdx.x;
  int t = threadIdx.x;
  const double* mpp = mp + (size_t)rb * DD;
  double a = 0.0;
  for (int d = 0; d < DD; ++d) a += mpp[d] * (double)Wmat[d * DD + t];
  H2[(size_t)rb * DD + t] = Hs[(size_t)rb * DD + t] + a;
}

// msgH = f32(mp @ Wb)
__global__ void n_msg(const double* __restrict__ mp, const float* __restrict__ Wmat,
                      float* __restrict__ msgH) {
  int rb = blockIdx.x;
  int t = threadIdx.x;
  const double* mpp = mp + (size_t)rb * DD;
  double a = 0.0;
  for (int d = 0; d < DD; ++d) a += mpp[d] * (double)Wmat[d * DD + t];
  msgH[(size_t)rb * DD + t] = (float)a;
}

__global__ void n_zero(float* __restrict__ p) {
  p[blockIdx.x * 256 + threadIdx.x] = 0.f;
}

// corr += clamp(f32(mp@Wb) - msgH, +-BR_CLAMP)   (FULL branch correction)
__global__ void n_corr(const double* __restrict__ mp, const float* __restrict__ Wmat,
                       const float* __restrict__ msgH, float* __restrict__ corr) {
  int rb = blockIdx.x;
  int t = threadIdx.x;
  const double* mpp = mp + (size_t)rb * DD;
  double a = 0.0;
  for (int d = 0; d < DD; ++d) a += mpp[d] * (double)Wmat[d * DD + t];
  size_t i = (size_t)rb * DD + t;
  corr[i] += clampf((float)a - msgH[i], BR_CLAMP);
}

// out = msgH + clamp(corr, +-TOT_CLAMP)
__global__ void n_final(const float* __restrict__ msgH, const float* __restrict__ corr,
                        float* __restrict__ out) {
  int i = blockIdx.x * 256 + threadIdx.x;
  out[i] = msgH[i] + clampf(corr[i], TOT_CLAMP);
}

__global__ void n_motor(const double* __restrict__ H2, const float* __restrict__ Wm,
                        const float* __restrict__ bm, double* __restrict__ motD,
                        float* __restrict__ motF) {
  int b = blockIdx.x, t = threadIdx.x;
  const double* hp = H2 + ((size_t)((RR - 1) * BB + b)) * DD;
  double a = 0.0;
  for (int d = 0; d < DD; ++d) a += hp[d] * (double)Wm[d * DD + t];
  double mo = a + (double)bm[t];
  motD[b * DD + t] = mo;
  motF[b * DD + t] = (float)mo;
}

__global__ void n_gate(const double* __restrict__ motD, const float* __restrict__ Wg,
                       int* __restrict__ sel, float* __restrict__ c2) {
  int b = threadIdx.x;
  double g[FF];
  for (int f = 0; f < FF; ++f) {
    double a = 0.0;
    for (int d = 0; d < DD; ++d) a += motD[b * DD + d] * (double)Wg[d * FF + f];
    g[f] = a;
  }
  double m1 = -INFINITY, m2 = -INFINITY;
  int i1 = -1, i2 = -1;
  for (int f = 0; f < FF; ++f) {
    if (g[f] > m1) { m2 = m1; i2 = i1; m1 = g[f]; i1 = f; }
    else if (g[f] > m2) { m2 = g[f]; i2 = f; }
  }
  double s = 0.0;
  for (int f = 0; f < FF; ++f)
    if (g[f] >= m2) s += exp(g[f] - m1);
  double lse = m1 + log(s);
  sel[b * 2 + 0] = i1;
  sel[b * 2 + 1] = i2;
  c2[b * 2 + 0] = (float)(g[i1] - lse);
  c2[b * 2 + 1] = (float)(g[i2] - lse);
}

// pi hard + INCLUSIVE alt (keep-3) in tie band
__global__ void n_pi_dual(const double* __restrict__ H2, const float* __restrict__ Wg,
                          double* __restrict__ piH, double* __restrict__ piA, int band_on) {
  int idx = blockIdx.x * 256 + threadIdx.x;
  const double* hp = H2 + (size_t)idx * DD;
  double gb[FF];
  for (int f = 0; f < FF; ++f) {
    double a = 0.0;
    for (int d = 0; d < DD; ++d) a += hp[d] * (double)Wg[d * FF + f];
    gb[f] = a;
  }
  double srt[FF];
  for (int f = 0; f < FF; ++f) srt[f] = gb[f];
  for (int i = 0; i < 3; ++i) {
    int mi = i;
    for (int j = i + 1; j < FF; ++j) if (srt[j] > srt[mi]) mi = j;
    double tp = srt[i]; srt[i] = srt[mi]; srt[mi] = tp;
  }
  double m1 = srt[0], m2 = srt[1], m3 = srt[2];
  double e[FF], s = 0.0;
  for (int f = 0; f < FF; ++f) {
    e[f] = (gb[f] >= m2) ? exp(gb[f] - m1) : 0.0;
    s += e[f];
  }
  for (int f = 0; f < FF; ++f) piH[(size_t)idx * FF + f] = e[f] / s;
  if (piA) {
    double gap = m2 - m3;
    if (band_on && gap > 0.0 && gap < TIE_BAND(m2, m3)) {
      double ea[FF], sa = 0.0;
      for (int f = 0; f < FF; ++f) {
        ea[f] = (gb[f] >= m3) ? exp(gb[f] - m1) : 0.0;   // INCLUSIVE: keep-3
        sa += ea[f];
      }
      for (int f = 0; f < FF; ++f) piA[(size_t)idx * FF + f] = ea[f] / sa;
    } else {
      for (int f = 0; f < FF; ++f) piA[(size_t)idx * FF + f] = e[f] / s;
    }
  }
}

__global__ void n_bc(const double* __restrict__ H2, const double* __restrict__ pi,
                     const float* __restrict__ e_fac, const float* __restrict__ boost_p,
                     double* __restrict__ Bc) {
  int rb = blockIdx.x, t = threadIdx.x;
  double ef = 0.0;
  for (int f = 0; f < FF; ++f) ef += pi[(size_t)rb * FF + f] * (double)e_fac[f * DD + t];
  double boost = (double)(*boost_p);
  Bc[(size_t)rb * DD + t] = H2[(size_t)rb * DD + t] * ef * boost;
}

// =================== validated f32 logp-path kernels ===================

__global__ void k_z2(const float* __restrict__ motor, const float* __restrict__ Wf,
                     const int* __restrict__ sel, float* __restrict__ z2) {
  int vc = blockIdx.x, f = blockIdx.y;
  int t = threadIdx.x;
  int v_l = t & 127, bh = t >> 7;
  __shared__ float mt[64][64];
  __shared__ float wft[64][128];
  __shared__ int selL[128];
  if (t < 128) selL[t] = sel[t];
  __syncthreads();
  float acc[32];
#pragma unroll
  for (int i = 0; i < 32; ++i) acc[i] = 0.f;
  const float* wf = Wf + (size_t)f * DD * VV;
  for (int dt = 0; dt < 4; ++dt) {
    for (int i = t; i < 4096; i += 256) {
      int b = i >> 6, d = i & 63;
      mt[b][d] = motor[b * DD + dt * 64 + d];
    }
    for (int i = t; i < 8192; i += 256) {
      int dd = i >> 7, vv = i & 127;
      wft[dd][vv] = wf[(size_t)(dt * 64 + dd) * VV + vc * 128 + vv];
    }
    __syncthreads();
    for (int d = 0; d < 64; ++d) {
      float wv = wft[d][v_l];
#pragma unroll
      for (int bi = 0; bi < 32; ++bi) acc[bi] += mt[bh * 32 + bi][d] * wv;
    }
    __syncthreads();
  }
  int v = vc * 128 + v_l;
#pragma unroll
  for (int bi = 0; bi < 32; ++bi) {
    int b = bh * 32 + bi;
    if (selL[b * 2 + 0] == f) z2[((size_t)(b * 2 + 0)) * VV + v] = acc[bi];
    if (selL[b * 2 + 1] == f) z2[((size_t)(b * 2 + 1)) * VV + v] = acc[bi];
  }
}

__global__ void k_lse(const float* __restrict__ z2, float* __restrict__ lse) {
  int row = blockIdx.x;
  int t = threadIdx.x;
  const float* zp = z2 + (size_t)row * VV;
  float m = -INFINITY, s = 0.f;
  for (int v = t; v < VV; v += 256) {
    float val = zp[v];
    if (val > m) { s = s * expf(m - val) + 1.f; m = val; }
    else s += expf(val - m);
  }
  __shared__ float sm[256], ss[256];
  sm[t] = m; ss[t] = s;
  __syncthreads();
  for (int off = 128; off > 0; off >>= 1) {
    if (t < off) {
      float m2 = sm[t + off], s2 = ss[t + off], m1 = sm[t], s1 = ss[t];
      float M = fmaxf(m1, m2);
      sm[t] = M;
      ss[t] = s1 * expf(m1 - M) + s2 * expf(m2 - M);
    }
    __syncthreads();
  }
  if (t == 0) lse[row] = sm[0] + logf(ss[0]);
}

__global__ void k_logp(const float* __restrict__ z2, const float* __restrict__ c2,
                       const float* __restrict__ lse, float* __restrict__ out_logp) {
  int b = blockIdx.y;
  int v = blockIdx.x * 256 + threadIdx.x;
  float a0 = c2[b * 2 + 0] - lse[b * 2 + 0] + z2[((size_t)(b * 2 + 0)) * VV + v];
  float a1 = c2[b * 2 + 1] - lse[b * 2 + 1] + z2[((size_t)(b * 2 + 1)) * VV + v];
  float M = fmaxf(a0, a1);
  out_logp[(size_t)b * VV + v] = M + logf(expf(a0 - M) + expf(a1 - M));
}

__global__ void k_loss(const float* __restrict__ out_logp, const int* __restrict__ targets,
                       float* __restrict__ out_loss, float* __restrict__ boost) {
  int b = threadIdx.x;
  float v = out_logp[(size_t)b * VV + targets[b]];
#pragma unroll
  for (int off = 32; off > 0; off >>= 1) v += __shfl_xor(v, off, 64);
  if (b == 0) {
    float loss = -v / 64.f;
    *out_loss = loss;
    *boost = 1.f + 2.f * ((loss > 0.7f) ? 1.f : 0.f);
  }
}

// =================== launch ===================
extern "C" void kernel_launch(void* const* d_in, const int* in_sizes, int n_in,
                              void* d_out, int out_size, void* d_ws, size_t ws_size,
                              hipStream_t stream) {
  const float* x       = (const float*)d_in[0];
  const int*   targets = (const int*)d_in[1];
  const int*   nidx    = (const int*)d_in[2];
  const float* W1      = (const float*)d_in[3];
  const float* b1      = (const float*)d_in[4];
  const float* W2      = (const float*)d_in[5];
  const float* b2      = (const float*)d_in[6];
  const float* w_gate  = (const float*)d_in[7];
  const float* Wr      = (const float*)d_in[8];
  const float* Wm      = (const float*)d_in[9];
  const float* bm      = (const float*)d_in[10];
  const float* Wg      = (const float*)d_in[11];
  const float* Wf      = (const float*)d_in[12];
  const float* e_fac   = (const float*)d_in[13];
  const float* Wb      = (const float*)d_in[14];

  float* out_logp = (float*)d_out;
  float* out_loss = out_logp + (size_t)BB * VV;
  float* out_msg  = out_loss + 1;

  double* dH   = (double*)d_ws;               // 1048576 d each
  double* dHs  = dH + 1048576;
  double* dHsM = dHs + 1048576;
  double* dH2  = dHsM + 1048576;
  double* dH2b = dH2 + 1048576;
  double* dBc  = dH2b + 1048576;
  double* dBcA = dBc + 1048576;
  double* dHid = dBcA + 1048576;              // 4194304 d (hid; overlaid later)
  float*  fZ2  = (float*)dHid;                //   z2: doubles [0 .. 2048000)
  double* dMp  = dHid + 2097152;              //   doubles [2097152 .. 3145728) clear of z2
  double* dScg = dHid + 4194304;              // 4096
  double* dW6h = dScg + 4096;                 // 24576 each
  double* dW6a = dW6h + 24576;
  double* dW6b = dW6a + 24576;
  double* dW2h = dW6b + 24576;
  double* dW2a = dW2h + 24576;
  double* dW2b = dW2a + 24576;
  double* dPiH = dW2b + 24576;                // 28672 each
  double* dPiA = dPiH + 28672;
  double* dPiH2= dPiA + 28672;
  double* dMotD= dPiH2 + 28672;               // 16384
  float*  fMaskH = (float*)(dMotD + 16384);   // 4096
  float*  fMaskA = fMaskH + 4096;             // 4096
  float*  fMsgH  = fMaskA + 4096;             // 1048576 f
  float*  fCorr  = fMsgH + 1048576;           // 1048576 f
  float*  fMotF  = fCorr + 1048576;           // 16384
  float*  fC2    = fMotF + 16384;             // 128
  float*  fLse   = fC2 + 128;                 // 128
  float*  fBoost = fLse + 128;                // 1
  int*    iSel   = (int*)(fBoost + 1);        // 128

  // ---- trunk ----
  n_hid<<<16384, 256, 0, stream>>>(x, W1, b1, dHid);
  n_H<<<4096, 256, 0, stream>>>(dHid, W2, b2, dH);
  n_scg<<<16, 256, 0, stream>>>(dH, w_gate, dScg);
  n_mask_dual<<<1, 64, 0, stream>>>(dScg, fMaskH, fMaskA);
  n_hs<<<4096, 256, 0, stream>>>(dH, fMaskH, dHs);
  n_w6x<<<16, 256, 0, stream>>>(dHs, dHs, nidx, dW6h, dW6a, 1);   // w1 hard + keep-5 alt
  n_mp<<<4096, 256, 0, stream>>>(dW6h, dHs, nidx, dMp);
  n_mm_add<<<4096, 256, 0, stream>>>(dMp, Wr, dHs, dH2);
  // ---- logp path (validated) ----
  n_motor<<<64, 256, 0, stream>>>(dH2, Wm, bm, dMotD, fMotF);
  n_gate<<<1, 64, 0, stream>>>(dMotD, Wg, iSel, fC2);
  k_z2<<<dim3(250, FF), 256, 0, stream>>>(fMotF, Wf, iSel, fZ2);
  k_lse<<<128, 256, 0, stream>>>(fZ2, fLse);
  k_logp<<<dim3(125, BB), 256, 0, stream>>>(fZ2, fC2, fLse, out_logp);
  k_loss<<<1, 64, 0, stream>>>(out_logp, targets, out_loss, fBoost);
  // ---- pass-2 hard -> msg_h ----
  n_pi_dual<<<16, 256, 0, stream>>>(dH2, Wg, dPiH, dPiA, 1);      // pi hard + keep-3 alt
  n_bc<<<4096, 256, 0, stream>>>(dH2, dPiH, e_fac, fBoost, dBc);
  n_w6x<<<16, 256, 0, stream>>>(dH2, dBc, nidx, dW2h, dW2a, 1);   // w2 hard + keep-5 alt
  n_mp<<<4096, 256, 0, stream>>>(dW2h, dBc, nidx, dMp);
  n_msg<<<4096, 256, 0, stream>>>(dMp, Wb, fMsgH);
  n_zero<<<4096, 256, 0, stream>>>(fCorr);
  // ---- BR_W2: keep-5 pass-2 neighbor gate ----
  n_mp<<<4096, 256, 0, stream>>>(dW2a, dBc, nidx, dMp);
  n_corr<<<4096, 256, 0, stream>>>(dMp, Wb, fMsgH, fCorr);
  // ---- BR_PI: keep-3 facet gate -> BcA -> hard w2 ----
  n_bc<<<4096, 256, 0, stream>>>(dH2, dPiA, e_fac, fBoost, dBcA);
  n_w6x<<<16, 256, 0, stream>>>(dH2, dBcA, nidx, dW2b, (double*)nullptr, 0);
  n_mp<<<4096, 256, 0, stream>>>(dW2b, dBcA, nidx, dMp);
  n_corr<<<4096, 256, 0, stream>>>(dMp, Wb, fMsgH, fCorr);
  // ---- BR_W1: keep-5 pass-1 neighbor gate -> full pass-2 ----
  n_mp<<<4096, 256, 0, stream>>>(dW6a, dHs, nidx, dMp);
  n_mm_add<<<4096, 256, 0, stream>>>(dMp, Wr, dHs, dH2b);
  n_pi_dual<<<16, 256, 0, stream>>>(dH2b, Wg, dPiH2, (double*)nullptr, 0);
  n_bc<<<4096, 256, 0, stream>>>(dH2b, dPiH2, e_fac, fBoost, dBcA);
  n_w6x<<<16, 256, 0, stream>>>(dH2b, dBcA, nidx, dW2b, (double*)nullptr, 0);
  n_mp<<<4096, 256, 0, stream>>>(dW2b, dBcA, nidx, dMp);
  n_corr<<<4096, 256, 0, stream>>>(dMp, Wb, fMsgH, fCorr);
  // ---- BR_M: keep-7 region mask -> full pass-1 tail + pass-2 ----
  n_hs<<<4096, 256, 0, stream>>>(dH, fMaskA, dHsM);
  n_w6x<<<16, 256, 0, stream>>>(dHsM, dHsM, nidx, dW6b, (double*)nullptr, 0);
  n_mp<<<4096, 256, 0, stream>>>(dW6b, dHsM, nidx, dMp);
  n_mm_add<<<4096, 256, 0, stream>>>(dMp, Wr, dHsM, dH2b);
  n_pi_dual<<<16, 256, 0, stream>>>(dH2b, Wg, dPiH2, (double*)nullptr, 0);
  n_bc<<<4096, 256, 0, stream>>>(dH2b, dPiH2, e_fac, fBoost, dBcA);
  n_w6x<<<16, 256, 0, stream>>>(dH2b, dBcA, nidx, dW2b, (double*)nullptr, 0);
  n_mp<<<4096, 256, 0, stream>>>(dW2b, dBcA, nidx, dMp);
  n_corr<<<4096, 256, 0, stream>>>(dMp, Wb, fMsgH, fCorr);
  // ---- final ----
  n_final<<<4096, 256, 0, stream>>>(fMsgH, fCorr, out_msg);
}

// Round 16
// 1585.137 us; speedup vs baseline: 1.8508x; 1.8508x over previous
//
#include <hip/hip_runtime.h>

#define RR 64
#define BB 64
#define DD 256
#define DFF_ 1024
#define VV 32000
#define FF 7

#define TIE_BAND(a, b) (2e-6 * (1.0 + 0.5 * (fabs(a) + fabs(b))))
#define BR_CLAMP 0.30f
#define TOT_CLAMP 0.19f

__device__ __forceinline__ float clampf(float x, float c) {
  return fminf(fmaxf(x, -c), c);
}

// =================== tiled trunk kernels (bitwise-identical f64 order) ===================

// hid = gelu(x@W1+b1); grid (8,64), 256 thr; block = 64 b x 128 f; k ascending
__global__ void t_hid(const float* __restrict__ x, const float* __restrict__ W1,
                      const float* __restrict__ b1, double* __restrict__ hid) {
  int r = blockIdx.y, fc = blockIdx.x;
  int t = threadIdx.x;
  int f_l = t & 127, bh = t >> 7;
  __shared__ float xs[64][64];
  __shared__ float w1t[64][128];
  double acc[32];
#pragma unroll
  for (int i = 0; i < 32; ++i) acc[i] = 0.0;
  const float* xr = x + (size_t)r * BB * DD;
  const float* w1r = W1 + (size_t)r * DD * DFF_;
  for (int dt = 0; dt < 4; ++dt) {
    for (int i = t; i < 4096; i += 256) {
      int b = i >> 6, d = i & 63;
      xs[b][d] = xr[b * DD + dt * 64 + d];
    }
    for (int i = t; i < 8192; i += 256) {
      int dd = i >> 7, ff = i & 127;
      w1t[dd][ff] = w1r[(size_t)(dt * 64 + dd) * DFF_ + fc * 128 + ff];
    }
    __syncthreads();
    for (int d = 0; d < 64; ++d) {          // global k = dt*64+d ascending (matches naive)
      double wv = (double)w1t[d][f_l];
#pragma unroll
      for (int bi = 0; bi < 32; ++bi) acc[bi] += (double)xs[bh * 32 + bi][d] * wv;
    }
    __syncthreads();
  }
  int f = fc * 128 + f_l;
  double bb = (double)b1[r * DFF_ + f];
#pragma unroll
  for (int bi = 0; bi < 32; ++bi) {
    int b = bh * 32 + bi;
    double v = acc[bi] + bb;
    hid[((size_t)(r * BB + b)) * DFF_ + f] =
        0.5 * v * (1.0 + erf(v * 0.70710678118654752440));
  }
}

// H = h + CTAU*h; grid (4,64), 256 thr; block = 64 b x 64 d; k ascending
__global__ void t_H(const double* __restrict__ hid, const float* __restrict__ W2,
                    const float* __restrict__ b2, double* __restrict__ H) {
  int r = blockIdx.y, dc = blockIdx.x;
  int t = threadIdx.x;
  int d_l = t & 63, bg = t >> 6;
  __shared__ double ht[64][64];
  __shared__ float wt[64][64];
  double acc[16];
#pragma unroll
  for (int i = 0; i < 16; ++i) acc[i] = 0.0;
  const double* hr = hid + (size_t)r * BB * DFF_;
  const float* w2r = W2 + (size_t)r * DFF_ * DD;
  for (int ft = 0; ft < 16; ++ft) {
    for (int i = t; i < 4096; i += 256) {
      int b = i >> 6, f = i & 63;
      ht[b][f] = hr[(size_t)b * DFF_ + ft * 64 + f];
    }
    for (int i = t; i < 4096; i += 256) {
      int f = i >> 6, d = i & 63;
      wt[f][d] = w2r[(size_t)(ft * 64 + f) * DD + dc * 64 + d];
    }
    __syncthreads();
    for (int f = 0; f < 64; ++f) {          // global k ascending
      double wv = (double)wt[f][d_l];
#pragma unroll
      for (int bi = 0; bi < 16; ++bi) acc[bi] += ht[bg * 16 + bi][f] * wv;
    }
    __syncthreads();
  }
  int d = dc * 64 + d_l;
  double bb = (double)b2[r * DD + d];
#pragma unroll
  for (int bi = 0; bi < 16; ++bi) {
    int b = bg * 16 + bi;
    double h = acc[bi] + bb;
    H[((size_t)(r * BB + b)) * DD + d] = h + 0.20333333 * h;
  }
}

// =================== scalar f64 kernels (unchanged semantics) ===================

__global__ void n_scg(const double* __restrict__ H, const float* __restrict__ wg,
                      double* __restrict__ scg) {
  int idx = blockIdx.x * 256 + threadIdx.x;
  int r = idx >> 6, b = idx & 63;
  const double* hp = H + (size_t)idx * DD;
  double a = 0.0;
  for (int d = 0; d < DD; ++d) a += hp[d] * (double)wg[d];
  scg[b * RR + r] = a;
}

// hard mask + inclusive alt + per-rb flag ; 1 block x 64
__global__ void n_mask_dual(const double* __restrict__ scg, float* __restrict__ maskH,
                            float* __restrict__ maskA, int* __restrict__ flagM) {
  int b = threadIdx.x;
  double v[64], w[64];
  for (int r = 0; r < RR; ++r) { v[r] = scg[b * RR + r]; w[r] = v[r]; }
  double k6 = 0.0, k7 = 0.0;
  int i6 = -1, i7 = -1;
  for (int it = 0; it < 7; ++it) {
    int mi = 0;
    for (int r = 1; r < RR; ++r) if (w[r] > w[mi]) mi = r;
    if (it == 5) { k6 = w[mi]; i6 = mi; }
    if (it == 6) { k7 = w[mi]; i7 = mi; }
    w[mi] = -INFINITY;
  }
  double gap = k6 - k7;
  int tie = (gap > 0.0 && gap < TIE_BAND(k6, k7)) ? 1 : 0;
  for (int r = 0; r < RR; ++r) {
    float mh = (v[r] >= k6 || r == 0 || r == RR - 1) ? 1.f : 0.f;
    maskH[b * RR + r] = mh;
    maskA[b * RR + r] = tie ? ((v[r] >= k7 || r == 0 || r == RR - 1) ? 1.f : 0.f) : mh;
    flagM[r * BB + b] = 0;
  }
  if (tie) {
    flagM[i6 * BB + b] = 1;
    flagM[i7 * BB + b] = 1;
  }
}

__global__ void n_hs(const double* __restrict__ H, const float* __restrict__ mask,
                     double* __restrict__ Hs) {
  int idx = blockIdx.x * 256 + threadIdx.x;
  int r = idx >> 14;
  int b = (idx >> 8) & 63;
  Hs[idx] = H[idx] * (double)mask[b * RR + r];
}

// top-4 gated softmax, hard + inclusive alt + flag ; 16 blocks x 256
__global__ void n_w6x(const double* __restrict__ self, const double* __restrict__ nb,
                      const int* __restrict__ nidx, double* __restrict__ wout,
                      double* __restrict__ walt, int* __restrict__ flag) {
  int idx = blockIdx.x * 256 + threadIdx.x;      // r*BB + b
  int r = idx >> 6, b = idx & 63;
  const double* sp = self + (size_t)idx * DD;
  double sc[6];
  for (int k = 0; k < 6; ++k) {
    int nr = nidx[r * 6 + k];
    const double* qp = nb + ((size_t)(nr * BB + b)) * DD;
    double a = 0.0;
    for (int d = 0; d < DD; ++d) a += sp[d] * qp[d];
    sc[k] = a * 0.0625;
  }
  double srt[6];
  for (int k = 0; k < 6; ++k) srt[k] = sc[k];
  for (int i = 0; i < 5; ++i) {
    int mi = i;
    for (int j = i + 1; j < 6; ++j) if (srt[j] > srt[mi]) mi = j;
    double tmp = srt[i]; srt[i] = srt[mi]; srt[mi] = tmp;
  }
  double s4 = srt[3], s5 = srt[4], mx = srt[0];
  double e[6], s = 0.0;
  for (int k = 0; k < 6; ++k) {
    e[k] = (sc[k] >= s4) ? exp(sc[k] - mx) : 0.0;
    s += e[k];
  }
  for (int k = 0; k < 6; ++k) wout[(size_t)idx * 6 + k] = e[k] / s;
  double gap = s4 - s5;
  int inband = (gap > 0.0 && gap < TIE_BAND(s4, s5)) ? 1 : 0;
  flag[idx] = inband;
  if (inband) {
    double ea[6], sa = 0.0;
    for (int k = 0; k < 6; ++k) {
      ea[k] = (sc[k] >= s5) ? exp(sc[k] - mx) : 0.0;   // inclusive keep-5
      sa += ea[k];
    }
    for (int k = 0; k < 6; ++k) walt[(size_t)idx * 6 + k] = ea[k] / sa;
  } else {
    for (int k = 0; k < 6; ++k) walt[(size_t)idx * 6 + k] = e[k] / s;
  }
}

// recompute-or-copy hard top-4 softmax ; 16 blocks x 256
__global__ void n_w6_sel(const double* __restrict__ self, const double* __restrict__ nb,
                         const int* __restrict__ nidx, const int* __restrict__ flag,
                         const double* __restrict__ wH, double* __restrict__ wout) {
  int idx = blockIdx.x * 256 + threadIdx.x;
  if (!flag[idx]) {
    for (int k = 0; k < 6; ++k) wout[(size_t)idx * 6 + k] = wH[(size_t)idx * 6 + k];
    return;
  }
  int r = idx >> 6, b = idx & 63;
  const double* sp = self + (size_t)idx * DD;
  double sc[6];
  for (int k = 0; k < 6; ++k) {
    int nr = nidx[r * 6 + k];
    const double* qp = nb + ((size_t)(nr * BB + b)) * DD;
    double a = 0.0;
    for (int d = 0; d < DD; ++d) a += sp[d] * qp[d];
    sc[k] = a * 0.0625;
  }
  double srt[6];
  for (int k = 0; k < 6; ++k) srt[k] = sc[k];
  for (int i = 0; i < 5; ++i) {
    int mi = i;
    for (int j = i + 1; j < 6; ++j) if (srt[j] > srt[mi]) mi = j;
    double tmp = srt[i]; srt[i] = srt[mi]; srt[mi] = tmp;
  }
  double s4 = srt[3], mx = srt[0];
  double e[6], s = 0.0;
  for (int k = 0; k < 6; ++k) {
    e[k] = (sc[k] >= s4) ? exp(sc[k] - mx) : 0.0;
    s += e[k];
  }
  for (int k = 0; k < 6; ++k) wout[(size_t)idx * 6 + k] = e[k] / s;
}

__global__ void n_mp(const double* __restrict__ w, const double* __restrict__ nb,
                     const int* __restrict__ nidx, double* __restrict__ mp) {
  int rb = blockIdx.x;
  int r = rb >> 6, b = rb & 63;
  int t = threadIdx.x;
  double a = 0.0;
  for (int k = 0; k < 6; ++k) {
    int nr = nidx[r * 6 + k];
    a += w[(size_t)rb * 6 + k] * nb[((size_t)(nr * BB + b)) * DD + t];
  }
  mp[(size_t)rb * DD + t] = a;
}

__global__ void n_mp_f(const double* __restrict__ w, const double* __restrict__ nb,
                       const int* __restrict__ nidx, const int* __restrict__ flag,
                       double* __restrict__ mp) {
  int rb = blockIdx.x;
  if (!flag[rb]) return;
  int r = rb >> 6, b = rb & 63;
  int t = threadIdx.x;
  double a = 0.0;
  for (int k = 0; k < 6; ++k) {
    int nr = nidx[r * 6 + k];
    a += w[(size_t)rb * 6 + k] * nb[((size_t)(nr * BB + b)) * DD + t];
  }
  mp[(size_t)rb * DD + t] = a;
}

__global__ void n_mm_add(const double* __restrict__ mp, const float* __restrict__ Wmat,
                         const double* __restrict__ Hs, double* __restrict__ H2) {
  int rb = blockIdx.x;
  int t = threadIdx.x;
  const double* mpp = mp + (size_t)rb * DD;
  double a = 0.0;
  for (int d = 0; d < DD; ++d) a += mpp[d] * (double)Wmat[d * DD + t];
  H2[(size_t)rb * DD + t] = Hs[(size_t)rb * DD + t] + a;
}

// recompute-or-copy H2 ; 4096 blocks
__global__ void n_h2_sel(const double* __restrict__ mp, const float* __restrict__ Wmat,
                         const double* __restrict__ Hs, const int* __restrict__ flag,
                         const double* __restrict__ H2H, double* __restrict__ H2out) {
  int rb = blockIdx.x;
  int t = threadIdx.x;
  size_t i = (size_t)rb * DD + t;
  if (!flag[rb]) { H2out[i] = H2H[i]; return; }
  const double* mpp = mp + (size_t)rb * DD;
  double a = 0.0;
  for (int d = 0; d < DD; ++d) a += mpp[d] * (double)Wmat[d * DD + t];
  H2out[i] = Hs[i] + a;
}

// Hs recompute-or-copy ; 4096 blocks
__global__ void n_hs_sel(const double* __restrict__ H, const float* __restrict__ maskA,
                         const int* __restrict__ flag, const double* __restrict__ HsH,
                         double* __restrict__ HsM) {
  int rb = blockIdx.x;
  int t = threadIdx.x;
  size_t i = (size_t)rb * DD + t;
  if (!flag[rb]) { HsM[i] = HsH[i]; return; }
  int r = rb >> 6, b = rb & 63;
  HsM[i] = H[i] * (double)maskA[b * RR + r];
}

__global__ void n_msg(const double* __restrict__ mp, const float* __restrict__ Wmat,
                      float* __restrict__ msgH) {
  int rb = blockIdx.x;
  int t = threadIdx.x;
  const double* mpp = mp + (size_t)rb * DD;
  double a = 0.0;
  for (int d = 0; d < DD; ++d) a += mpp[d] * (double)Wmat[d * DD + t];
  msgH[(size_t)rb * DD + t] = (float)a;
}

__global__ void n_zero(float* __restrict__ p) {
  p[blockIdx.x * 256 + threadIdx.x] = 0.f;
}

__global__ void n_corr_f(const double* __restrict__ mp, const float* __restrict__ Wmat,
                         const float* __restrict__ msgH, const int* __restrict__ flag,
                         float* __restrict__ corr) {
  int rb = blockIdx.x;
  if (!flag[rb]) return;
  int t = threadIdx.x;
  const double* mpp = mp + (size_t)rb * DD;
  double a = 0.0;
  for (int d = 0; d < DD; ++d) a += mpp[d] * (double)Wmat[d * DD + t];
  size_t i = (size_t)rb * DD + t;
  corr[i] += clampf((float)a - msgH[i], BR_CLAMP);
}

__global__ void n_final(const float* __restrict__ msgH, const float* __restrict__ corr,
                        float* __restrict__ out) {
  int i = blockIdx.x * 256 + threadIdx.x;
  out[i] = msgH[i] + clampf(corr[i], TOT_CLAMP);
}

// dirty closure: out[rb] = in[rb] || any neighbor ; 16 blocks x 256
__global__ void n_close(const int* __restrict__ in, const int* __restrict__ nidx,
                        int* __restrict__ out) {
  int idx = blockIdx.x * 256 + threadIdx.x;
  int r = idx >> 6, b = idx & 63;
  int v = in[idx];
  for (int k = 0; k < 6; ++k) v |= in[nidx[r * 6 + k] * BB + b];
  out[idx] = v;
}

__global__ void n_motor(const double* __restrict__ H2, const float* __restrict__ Wm,
                        const float* __restrict__ bm, double* __restrict__ motD,
                        float* __restrict__ motF) {
  int b = blockIdx.x, t = threadIdx.x;
  const double* hp = H2 + ((size_t)((RR - 1) * BB + b)) * DD;
  double a = 0.0;
  for (int d = 0; d < DD; ++d) a += hp[d] * (double)Wm[d * DD + t];
  double mo = a + (double)bm[t];
  motD[b * DD + t] = mo;
  motF[b * DD + t] = (float)mo;
}

__global__ void n_gate(const double* __restrict__ motD, const float* __restrict__ Wg,
                       int* __restrict__ sel, float* __restrict__ c2) {
  int b = threadIdx.x;
  double g[FF];
  for (int f = 0; f < FF; ++f) {
    double a = 0.0;
    for (int d = 0; d < DD; ++d) a += motD[b * DD + d] * (double)Wg[d * FF + f];
    g[f] = a;
  }
  double m1 = -INFINITY, m2 = -INFINITY;
  int i1 = -1, i2 = -1;
  for (int f = 0; f < FF; ++f) {
    if (g[f] > m1) { m2 = m1; i2 = i1; m1 = g[f]; i1 = f; }
    else if (g[f] > m2) { m2 = g[f]; i2 = f; }
  }
  double s = 0.0;
  for (int f = 0; f < FF; ++f)
    if (g[f] >= m2) s += exp(g[f] - m1);
  double lse = m1 + log(s);
  sel[b * 2 + 0] = i1;
  sel[b * 2 + 1] = i2;
  c2[b * 2 + 0] = (float)(g[i1] - lse);
  c2[b * 2 + 1] = (float)(g[i2] - lse);
}

// pi hard + inclusive alt + flag ; 16 blocks x 256
__global__ void n_pi_dual(const double* __restrict__ H2, const float* __restrict__ Wg,
                          double* __restrict__ piH, double* __restrict__ piA,
                          int* __restrict__ flag) {
  int idx = blockIdx.x * 256 + threadIdx.x;
  const double* hp = H2 + (size_t)idx * DD;
  double gb[FF];
  for (int f = 0; f < FF; ++f) {
    double a = 0.0;
    for (int d = 0; d < DD; ++d) a += hp[d] * (double)Wg[d * FF + f];
    gb[f] = a;
  }
  double srt[FF];
  for (int f = 0; f < FF; ++f) srt[f] = gb[f];
  for (int i = 0; i < 3; ++i) {
    int mi = i;
    for (int j = i + 1; j < FF; ++j) if (srt[j] > srt[mi]) mi = j;
    double tp = srt[i]; srt[i] = srt[mi]; srt[mi] = tp;
  }
  double m1 = srt[0], m2 = srt[1], m3 = srt[2];
  double e[FF], s = 0.0;
  for (int f = 0; f < FF; ++f) {
    e[f] = (gb[f] >= m2) ? exp(gb[f] - m1) : 0.0;
    s += e[f];
  }
  for (int f = 0; f < FF; ++f) piH[(size_t)idx * FF + f] = e[f] / s;
  double gap = m2 - m3;
  int inband = (gap > 0.0 && gap < TIE_BAND(m2, m3)) ? 1 : 0;
  flag[idx] = inband;
  if (inband) {
    double ea[FF], sa = 0.0;
    for (int f = 0; f < FF; ++f) {
      ea[f] = (gb[f] >= m3) ? exp(gb[f] - m1) : 0.0;   // inclusive keep-3
      sa += ea[f];
    }
    for (int f = 0; f < FF; ++f) piA[(size_t)idx * FF + f] = ea[f] / sa;
  } else {
    for (int f = 0; f < FF; ++f) piA[(size_t)idx * FF + f] = e[f] / s;
  }
}

// recompute-or-copy hard pi ; 16 blocks x 256
__global__ void n_pi_sel(const double* __restrict__ H2, const float* __restrict__ Wg,
                         const int* __restrict__ flag, const double* __restrict__ piHsrc,
                         double* __restrict__ piout) {
  int idx = blockIdx.x * 256 + threadIdx.x;
  if (!flag[idx]) {
    for (int f = 0; f < FF; ++f) piout[(size_t)idx * FF + f] = piHsrc[(size_t)idx * FF + f];
    return;
  }
  const double* hp = H2 + (size_t)idx * DD;
  double gb[FF];
  for (int f = 0; f < FF; ++f) {
    double a = 0.0;
    for (int d = 0; d < DD; ++d) a += hp[d] * (double)Wg[d * FF + f];
    gb[f] = a;
  }
  double m1 = -INFINITY, m2 = -INFINITY;
  for (int f = 0; f < FF; ++f) {
    if (gb[f] > m1) { m2 = m1; m1 = gb[f]; }
    else if (gb[f] > m2) { m2 = gb[f]; }
  }
  double e[FF], s = 0.0;
  for (int f = 0; f < FF; ++f) {
    e[f] = (gb[f] >= m2) ? exp(gb[f] - m1) : 0.0;
    s += e[f];
  }
  for (int f = 0; f < FF; ++f) piout[(size_t)idx * FF + f] = e[f] / s;
}

__global__ void n_bc(const double* __restrict__ H2, const double* __restrict__ pi,
                     const float* __restrict__ e_fac, const float* __restrict__ boost_p,
                     double* __restrict__ Bc) {
  int rb = blockIdx.x, t = threadIdx.x;
  double ef = 0.0;
  for (int f = 0; f < FF; ++f) ef += pi[(size_t)rb * FF + f] * (double)e_fac[f * DD + t];
  double boost = (double)(*boost_p);
  Bc[(size_t)rb * DD + t] = H2[(size_t)rb * DD + t] * ef * boost;
}

// recompute-or-copy Bc ; 4096 blocks
__global__ void n_bc_sel(const double* __restrict__ H2, const double* __restrict__ pi,
                         const float* __restrict__ e_fac, const float* __restrict__ boost_p,
                         const int* __restrict__ flag, const double* __restrict__ BcH,
                         double* __restrict__ Bc2) {
  int rb = blockIdx.x, t = threadIdx.x;
  size_t i = (size_t)rb * DD + t;
  if (!flag[rb]) { Bc2[i] = BcH[i]; return; }
  double ef = 0.0;
  for (int f = 0; f < FF; ++f) ef += pi[(size_t)rb * FF + f] * (double)e_fac[f * DD + t];
  double boost = (double)(*boost_p);
  Bc2[i] = H2[i] * ef * boost;
}

// =================== validated f32 logp-path kernels ===================

__global__ void k_z2(const float* __restrict__ motor, const float* __restrict__ Wf,
                     const int* __restrict__ sel, float* __restrict__ z2) {
  int vc = blockIdx.x, f = blockIdx.y;
  int t = threadIdx.x;
  int v_l = t & 127, bh = t >> 7;
  __shared__ float mt[64][64];
  __shared__ float wft[64][128];
  __shared__ int selL[128];
  if (t < 128) selL[t] = sel[t];
  __syncthreads();
  float acc[32];
#pragma unroll
  for (int i = 0; i < 32; ++i) acc[i] = 0.f;
  const float* wf = Wf + (size_t)f * DD * VV;
  for (int dt = 0; dt < 4; ++dt) {
    for (int i = t; i < 4096; i += 256) {
      int b = i >> 6, d = i & 63;
      mt[b][d] = motor[b * DD + dt * 64 + d];
    }
    for (int i = t; i < 8192; i += 256) {
      int dd = i >> 7, vv = i & 127;
      wft[dd][vv] = wf[(size_t)(dt * 64 + dd) * VV + vc * 128 + vv];
    }
    __syncthreads();
    for (int d = 0; d < 64; ++d) {
      float wv = wft[d][v_l];
#pragma unroll
      for (int bi = 0; bi < 32; ++bi) acc[bi] += mt[bh * 32 + bi][d] * wv;
    }
    __syncthreads();
  }
  int v = vc * 128 + v_l;
#pragma unroll
  for (int bi = 0; bi < 32; ++bi) {
    int b = bh * 32 + bi;
    if (selL[b * 2 + 0] == f) z2[((size_t)(b * 2 + 0)) * VV + v] = acc[bi];
    if (selL[b * 2 + 1] == f) z2[((size_t)(b * 2 + 1)) * VV + v] = acc[bi];
  }
}

__global__ void k_lse(const float* __restrict__ z2, float* __restrict__ lse) {
  int row = blockIdx.x;
  int t = threadIdx.x;
  const float* zp = z2 + (size_t)row * VV;
  float m = -INFINITY, s = 0.f;
  for (int v = t; v < VV; v += 256) {
    float val = zp[v];
    if (val > m) { s = s * expf(m - val) + 1.f; m = val; }
    else s += expf(val - m);
  }
  __shared__ float sm[256], ss[256];
  sm[t] = m; ss[t] = s;
  __syncthreads();
  for (int off = 128; off > 0; off >>= 1) {
    if (t < off) {
      float m2 = sm[t + off], s2 = ss[t + off], m1 = sm[t], s1 = ss[t];
      float M = fmaxf(m1, m2);
      sm[t] = M;
      ss[t] = s1 * expf(m1 - M) + s2 * expf(m2 - M);
    }
    __syncthreads();
  }
  if (t == 0) lse[row] = sm[0] + logf(ss[0]);
}

__global__ void k_logp(const float* __restrict__ z2, const float* __restrict__ c2,
                       const float* __restrict__ lse, float* __restrict__ out_logp) {
  int b = blockIdx.y;
  int v = blockIdx.x * 256 + threadIdx.x;
  float a0 = c2[b * 2 + 0] - lse[b * 2 + 0] + z2[((size_t)(b * 2 + 0)) * VV + v];
  float a1 = c2[b * 2 + 1] - lse[b * 2 + 1] + z2[((size_t)(b * 2 + 1)) * VV + v];
  float M = fmaxf(a0, a1);
  out_logp[(size_t)b * VV + v] = M + logf(expf(a0 - M) + expf(a1 - M));
}

__global__ void k_loss(const float* __restrict__ out_logp, const int* __restrict__ targets,
                       float* __restrict__ out_loss, float* __restrict__ boost) {
  int b = threadIdx.x;
  float v = out_logp[(size_t)b * VV + targets[b]];
#pragma unroll
  for (int off = 32; off > 0; off >>= 1) v += __shfl_xor(v, off, 64);
  if (b == 0) {
    float loss = -v / 64.f;
    *out_loss = loss;
    *boost = 1.f + 2.f * ((loss > 0.7f) ? 1.f : 0.f);
  }
}

// =================== launch ===================
extern "C" void kernel_launch(void* const* d_in, const int* in_sizes, int n_in,
                              void* d_out, int out_size, void* d_ws, size_t ws_size,
                              hipStream_t stream) {
  const float* x       = (const float*)d_in[0];
  const int*   targets = (const int*)d_in[1];
  const int*   nidx    = (const int*)d_in[2];
  const float* W1      = (const float*)d_in[3];
  const float* b1      = (const float*)d_in[4];
  const float* W2      = (const float*)d_in[5];
  const float* b2      = (const float*)d_in[6];
  const float* w_gate  = (const float*)d_in[7];
  const float* Wr      = (const float*)d_in[8];
  const float* Wm      = (const float*)d_in[9];
  const float* bm      = (const float*)d_in[10];
  const float* Wg      = (const float*)d_in[11];
  const float* Wf      = (const float*)d_in[12];
  const float* e_fac   = (const float*)d_in[13];
  const float* Wb      = (const float*)d_in[14];

  float* out_logp = (float*)d_out;
  float* out_loss = out_logp + (size_t)BB * VV;
  float* out_msg  = out_loss + 1;

  double* dH   = (double*)d_ws;               // 1048576 d each
  double* dHs  = dH + 1048576;
  double* dHsM = dHs + 1048576;
  double* dH2  = dHsM + 1048576;
  double* dH2b = dH2 + 1048576;
  double* dBc  = dH2b + 1048576;
  double* dBcA = dBc + 1048576;
  double* dHid = dBcA + 1048576;              // 4194304 d region (hid; overlaid later)
  float*  fZ2  = (float*)dHid;                //   z2: doubles [0 .. 2048000)
  double* dMp  = dHid + 2097152;              //   [2097152 .. 3145728)
  double* dMpA = dHid + 3145728;              //   [3145728 .. 4194304)
  double* dScg = dHid + 4194304;              // 4096
  double* dW6h = dScg + 4096;                 // 24576 each
  double* dW6a = dW6h + 24576;
  double* dW6b = dW6a + 24576;
  double* dW2h = dW6b + 24576;
  double* dW2a = dW2h + 24576;
  double* dW2b = dW2a + 24576;
  double* dPiH = dW2b + 24576;                // 28672 each
  double* dPiA = dPiH + 28672;
  double* dPiH2= dPiA + 28672;
  double* dMotD= dPiH2 + 28672;               // 16384
  float*  fMaskH = (float*)(dMotD + 16384);   // 4096
  float*  fMaskA = fMaskH + 4096;             // 4096
  float*  fMsgH  = fMaskA + 4096;             // 1048576 f
  float*  fCorr  = fMsgH + 1048576;           // 1048576 f
  float*  fMotF  = fCorr + 1048576;           // 16384
  float*  fC2    = fMotF + 16384;             // 128
  float*  fLse   = fC2 + 128;                 // 128
  float*  fBoost = fLse + 128;                // 1
  int*    iSel   = (int*)(fBoost + 1);        // 128
  int*    fW1    = iSel + 128;                // 4096 each
  int*    fW2    = fW1 + 4096;
  int*    fPi    = fW2 + 4096;
  int*    fM     = fPi + 4096;
  int*    cPi    = fM + 4096;
  int*    cW1    = cPi + 4096;
  int*    cM     = cW1 + 4096;
  int*    cM2    = cM + 4096;

  // ---- trunk (tiled, bitwise-identical) ----
  t_hid<<<dim3(8, 64), 256, 0, stream>>>(x, W1, b1, dHid);
  t_H<<<dim3(4, 64), 256, 0, stream>>>(dHid, W2, b2, dH);
  n_scg<<<16, 256, 0, stream>>>(dH, w_gate, dScg);
  n_mask_dual<<<1, 64, 0, stream>>>(dScg, fMaskH, fMaskA, fM);
  n_hs<<<4096, 256, 0, stream>>>(dH, fMaskH, dHs);
  n_w6x<<<16, 256, 0, stream>>>(dHs, dHs, nidx, dW6h, dW6a, fW1);
  n_mp<<<4096, 256, 0, stream>>>(dW6h, dHs, nidx, dMp);
  n_mm_add<<<4096, 256, 0, stream>>>(dMp, Wr, dHs, dH2);
  // ---- logp path (validated, unchanged) ----
  n_motor<<<64, 256, 0, stream>>>(dH2, Wm, bm, dMotD, fMotF);
  n_gate<<<1, 64, 0, stream>>>(dMotD, Wg, iSel, fC2);
  k_z2<<<dim3(250, FF), 256, 0, stream>>>(fMotF, Wf, iSel, fZ2);
  k_lse<<<128, 256, 0, stream>>>(fZ2, fLse);
  k_logp<<<dim3(125, BB), 256, 0, stream>>>(fZ2, fC2, fLse, out_logp);
  k_loss<<<1, 64, 0, stream>>>(out_logp, targets, out_loss, fBoost);
  // ---- pass-2 hard -> msg_h ----
  n_pi_dual<<<16, 256, 0, stream>>>(dH2, Wg, dPiH, dPiA, fPi);
  n_bc<<<4096, 256, 0, stream>>>(dH2, dPiH, e_fac, fBoost, dBc);
  n_w6x<<<16, 256, 0, stream>>>(dH2, dBc, nidx, dW2h, dW2a, fW2);
  n_mp<<<4096, 256, 0, stream>>>(dW2h, dBc, nidx, dMp);
  n_msg<<<4096, 256, 0, stream>>>(dMp, Wb, fMsgH);
  n_zero<<<4096, 256, 0, stream>>>(fCorr);
  // ---- BR_W2 (sparse: only rb with fW2) ----
  n_mp_f<<<4096, 256, 0, stream>>>(dW2a, dBc, nidx, fW2, dMpA);
  n_corr_f<<<4096, 256, 0, stream>>>(dMpA, Wb, fMsgH, fW2, fCorr);
  // ---- BR_PI (sparse: fPi + 1-hop closure) ----
  n_bc_sel<<<4096, 256, 0, stream>>>(dH2, dPiA, e_fac, fBoost, fPi, dBc, dBcA);
  n_close<<<16, 256, 0, stream>>>(fPi, nidx, cPi);
  n_w6_sel<<<16, 256, 0, stream>>>(dH2, dBcA, nidx, cPi, dW2h, dW2b);
  n_mp_f<<<4096, 256, 0, stream>>>(dW2b, dBcA, nidx, cPi, dMpA);
  n_corr_f<<<4096, 256, 0, stream>>>(dMpA, Wb, fMsgH, cPi, fCorr);
  // ---- BR_W1 (sparse: fW1 + 1-hop closure) ----
  n_mp_f<<<4096, 256, 0, stream>>>(dW6a, dHs, nidx, fW1, dMpA);
  n_h2_sel<<<4096, 256, 0, stream>>>(dMpA, Wr, dHs, fW1, dH2, dH2b);
  n_pi_sel<<<16, 256, 0, stream>>>(dH2b, Wg, fW1, dPiH, dPiH2);
  n_bc_sel<<<4096, 256, 0, stream>>>(dH2b, dPiH2, e_fac, fBoost, fW1, dBc, dBcA);
  n_close<<<16, 256, 0, stream>>>(fW1, nidx, cW1);
  n_w6_sel<<<16, 256, 0, stream>>>(dH2b, dBcA, nidx, cW1, dW2h, dW2b);
  n_mp_f<<<4096, 256, 0, stream>>>(dW2b, dBcA, nidx, cW1, dMpA);
  n_corr_f<<<4096, 256, 0, stream>>>(dMpA, Wb, fMsgH, cW1, fCorr);
  // ---- BR_M (sparse: fM + closures) ----
  n_hs_sel<<<4096, 256, 0, stream>>>(dH, fMaskA, fM, dHs, dHsM);
  n_close<<<16, 256, 0, stream>>>(fM, nidx, cM);
  n_w6_sel<<<16, 256, 0, stream>>>(dHsM, dHsM, nidx, cM, dW6h, dW6b);
  n_mp_f<<<4096, 256, 0, stream>>>(dW6b, dHsM, nidx, cM, dMpA);
  n_h2_sel<<<4096, 256, 0, stream>>>(dMpA, Wr, dHsM, cM, dH2, dH2b);
  n_pi_sel<<<16, 256, 0, stream>>>(dH2b, Wg, cM, dPiH, dPiH2);
  n_bc_sel<<<4096, 256, 0, stream>>>(dH2b, dPiH2, e_fac, fBoost, cM, dBc, dBcA);
  n_close<<<16, 256, 0, stream>>>(cM, nidx, cM2);
  n_w6_sel<<<16, 256, 0, stream>>>(dH2b, dBcA, nidx, cM2, dW2h, dW2b);
  n_mp_f<<<4096, 256, 0, stream>>>(dW2b, dBcA, nidx, cM2, dMpA);
  n_corr_f<<<4096, 256, 0, stream>>>(dMpA, Wb, fMsgH, cM2, fCorr);
  // ---- final ----
  n_final<<<4096, 256, 0, stream>>>(fMsgH, fCorr, out_msg);
}

// Round 18
// 1357.284 us; speedup vs baseline: 2.1615x; 1.1679x over previous
//
#include <hip/hip_runtime.h>

#define RR 64
#define BB 64
#define DD 256
#define DFF_ 1024
#define VV 32000
#define FF 7

#define TIE_BAND(a, b) (2e-6 * (1.0 + 0.5 * (fabs(a) + fabs(b))))
#define BR_CLAMP 0.30f
#define TOT_CLAMP 0.19f

__device__ __forceinline__ float clampf(float x, float c) {
  return fminf(fmaxf(x, -c), c);
}

// =================== tiled trunk kernels (register-blocked, order-identical) ===================

// hid = gelu(x@W1+b1); grid (8,64), 256 thr; thread owns 8b x 4f
__global__ void t_hid(const float* __restrict__ x, const float* __restrict__ W1,
                      const float* __restrict__ b1, double* __restrict__ hid) {
  int r = blockIdx.y, fc = blockIdx.x;
  int t = threadIdx.x;
  int fg = t & 31, bg = t >> 5;
  __shared__ float xs[64][65];             // [d][b] padded
  __shared__ float w1t[64][128];           // [d][f]
  double acc[8][4];
#pragma unroll
  for (int i = 0; i < 8; ++i)
#pragma unroll
    for (int j = 0; j < 4; ++j) acc[i][j] = 0.0;
  const float* xr = x + (size_t)r * BB * DD;
  const float* w1r = W1 + (size_t)r * DD * DFF_;
  for (int dt = 0; dt < 4; ++dt) {
    for (int i = t; i < 4096; i += 256) {
      int d = i & 63, b = i >> 6;
      xs[d][b] = xr[b * DD + dt * 64 + d];
    }
    for (int i = t; i < 8192; i += 256) {
      int dd = i >> 7, ff = i & 127;
      w1t[dd][ff] = w1r[(size_t)(dt * 64 + dd) * DFF_ + fc * 128 + ff];
    }
    __syncthreads();
    for (int d = 0; d < 64; ++d) {         // global k ascending, single accumulator
      double bv[8], wv[4];
#pragma unroll
      for (int i = 0; i < 8; ++i) bv[i] = (double)xs[d][bg * 8 + i];
#pragma unroll
      for (int j = 0; j < 4; ++j) wv[j] = (double)w1t[d][fg * 4 + j];
#pragma unroll
      for (int i = 0; i < 8; ++i)
#pragma unroll
        for (int j = 0; j < 4; ++j) acc[i][j] += bv[i] * wv[j];
    }
    __syncthreads();
  }
#pragma unroll
  for (int i = 0; i < 8; ++i) {
    int b = bg * 8 + i;
#pragma unroll
    for (int j = 0; j < 4; ++j) {
      int f = fc * 128 + fg * 4 + j;
      double v = acc[i][j] + (double)b1[r * DFF_ + f];
      hid[((size_t)(r * BB + b)) * DFF_ + f] =
          0.5 * v * (1.0 + erf(v * 0.70710678118654752440));
    }
  }
}

// H = h + CTAU*h; grid (4,64), 256 thr; thread owns 4b x 4d
__global__ void t_H(const double* __restrict__ hid, const float* __restrict__ W2,
                    const float* __restrict__ b2, double* __restrict__ H) {
  int r = blockIdx.y, dc = blockIdx.x;
  int t = threadIdx.x;
  int dg = t & 15, bg = t >> 4;
  __shared__ double ht[64][65];            // [f][b] padded
  __shared__ float wt[64][64];             // [f][d]
  double acc[4][4];
#pragma unroll
  for (int i = 0; i < 4; ++i)
#pragma unroll
    for (int j = 0; j < 4; ++j) acc[i][j] = 0.0;
  const double* hr = hid + (size_t)r * BB * DFF_;
  const float* w2r = W2 + (size_t)r * DFF_ * DD;
  for (int ft = 0; ft < 16; ++ft) {
    for (int i = t; i < 4096; i += 256) {
      int f = i & 63, b = i >> 6;
      ht[f][b] = hr[(size_t)b * DFF_ + ft * 64 + f];
    }
    for (int i = t; i < 4096; i += 256) {
      int f = i >> 6, d = i & 63;
      wt[f][d] = w2r[(size_t)(ft * 64 + f) * DD + dc * 64 + d];
    }
    __syncthreads();
    for (int f = 0; f < 64; ++f) {         // global k ascending, single accumulator
      double hb[4], wv[4];
#pragma unroll
      for (int i = 0; i < 4; ++i) hb[i] = ht[f][bg * 4 + i];
#pragma unroll
      for (int j = 0; j < 4; ++j) wv[j] = (double)wt[f][dg * 4 + j];
#pragma unroll
      for (int i = 0; i < 4; ++i)
#pragma unroll
        for (int j = 0; j < 4; ++j) acc[i][j] += hb[i] * wv[j];
    }
    __syncthreads();
  }
#pragma unroll
  for (int i = 0; i < 4; ++i) {
    int b = bg * 4 + i;
#pragma unroll
    for (int j = 0; j < 4; ++j) {
      int d = dc * 64 + dg * 4 + j;
      double h = acc[i][j] + (double)b2[r * DD + d];
      H[((size_t)(r * BB + b)) * DD + d] = h + 0.20333333 * h;
    }
  }
}

// =================== sequential gate kernels (r16-frozen selection scores) ===================

__global__ void n_scg(const double* __restrict__ H, const float* __restrict__ wg,
                      double* __restrict__ scg) {
  int idx = blockIdx.x * 256 + threadIdx.x;
  int r = idx >> 6, b = idx & 63;
  const double* hp = H + (size_t)idx * DD;
  double a = 0.0;
  for (int d = 0; d < DD; ++d) a += hp[d] * (double)wg[d];
  scg[b * RR + r] = a;
}

// hard mask + inclusive alt + per-rb flag ; 1 block x 64
__global__ void n_mask_dual(const double* __restrict__ scg, float* __restrict__ maskH,
                            float* __restrict__ maskA, int* __restrict__ flagM) {
  int b = threadIdx.x;
  double v[64], w[64];
  for (int r = 0; r < RR; ++r) { v[r] = scg[b * RR + r]; w[r] = v[r]; }
  double k6 = 0.0, k7 = 0.0;
  int i6 = -1, i7 = -1;
  for (int it = 0; it < 7; ++it) {
    int mi = 0;
    for (int r = 1; r < RR; ++r) if (w[r] > w[mi]) mi = r;
    if (it == 5) { k6 = w[mi]; i6 = mi; }
    if (it == 6) { k7 = w[mi]; i7 = mi; }
    w[mi] = -INFINITY;
  }
  double gap = k6 - k7;
  int tie = (gap > 0.0 && gap < TIE_BAND(k6, k7)) ? 1 : 0;
  for (int r = 0; r < RR; ++r) {
    float mh = (v[r] >= k6 || r == 0 || r == RR - 1) ? 1.f : 0.f;
    maskH[b * RR + r] = mh;
    maskA[b * RR + r] = tie ? ((v[r] >= k7 || r == 0 || r == RR - 1) ? 1.f : 0.f) : mh;
    flagM[r * BB + b] = 0;
  }
  if (tie) {
    flagM[i6 * BB + b] = 1;
    flagM[i7 * BB + b] = 1;
  }
}

__global__ void n_hs(const double* __restrict__ H, const float* __restrict__ mask,
                     double* __restrict__ Hs) {
  int idx = blockIdx.x * 256 + threadIdx.x;
  int r = idx >> 14;
  int b = (idx >> 8) & 63;
  Hs[idx] = H[idx] * (double)mask[b * RR + r];
}

// top-4 gated softmax, hard + inclusive alt + flag ; 16 blocks x 256 (sequential)
__global__ void n_w6x(const double* __restrict__ self, const double* __restrict__ nb,
                      const int* __restrict__ nidx, double* __restrict__ wout,
                      double* __restrict__ walt, int* __restrict__ flag) {
  int idx = blockIdx.x * 256 + threadIdx.x;
  int r = idx >> 6, b = idx & 63;
  const double* sp = self + (size_t)idx * DD;
  double sc[6];
  for (int k = 0; k < 6; ++k) {
    int nr = nidx[r * 6 + k];
    const double* qp = nb + ((size_t)(nr * BB + b)) * DD;
    double a = 0.0;
    for (int d = 0; d < DD; ++d) a += sp[d] * qp[d];
    sc[k] = a * 0.0625;
  }
  double srt[6];
  for (int k = 0; k < 6; ++k) srt[k] = sc[k];
  for (int i = 0; i < 5; ++i) {
    int mi = i;
    for (int j = i + 1; j < 6; ++j) if (srt[j] > srt[mi]) mi = j;
    double tmp = srt[i]; srt[i] = srt[mi]; srt[mi] = tmp;
  }
  double s4 = srt[3], s5 = srt[4], mx = srt[0];
  double e[6], s = 0.0;
  for (int k = 0; k < 6; ++k) {
    e[k] = (sc[k] >= s4) ? exp(sc[k] - mx) : 0.0;
    s += e[k];
  }
  for (int k = 0; k < 6; ++k) wout[(size_t)idx * 6 + k] = e[k] / s;
  double gap = s4 - s5;
  int inband = (gap > 0.0 && gap < TIE_BAND(s4, s5)) ? 1 : 0;
  flag[idx] = inband;
  if (inband) {
    double ea[6], sa = 0.0;
    for (int k = 0; k < 6; ++k) {
      ea[k] = (sc[k] >= s5) ? exp(sc[k] - mx) : 0.0;   // inclusive keep-5
      sa += ea[k];
    }
    for (int k = 0; k < 6; ++k) walt[(size_t)idx * 6 + k] = ea[k] / sa;
  } else {
    for (int k = 0; k < 6; ++k) walt[(size_t)idx * 6 + k] = e[k] / s;
  }
}

// recompute-or-copy hard top-4 softmax ; 16 blocks x 256 (sequential)
__global__ void n_w6_sel(const double* __restrict__ self, const double* __restrict__ nb,
                         const int* __restrict__ nidx, const int* __restrict__ flag,
                         const double* __restrict__ wH, double* __restrict__ wout) {
  int idx = blockIdx.x * 256 + threadIdx.x;
  if (!flag[idx]) {
    for (int k = 0; k < 6; ++k) wout[(size_t)idx * 6 + k] = wH[(size_t)idx * 6 + k];
    return;
  }
  int r = idx >> 6, b = idx & 63;
  const double* sp = self + (size_t)idx * DD;
  double sc[6];
  for (int k = 0; k < 6; ++k) {
    int nr = nidx[r * 6 + k];
    const double* qp = nb + ((size_t)(nr * BB + b)) * DD;
    double a = 0.0;
    for (int d = 0; d < DD; ++d) a += sp[d] * qp[d];
    sc[k] = a * 0.0625;
  }
  double srt[6];
  for (int k = 0; k < 6; ++k) srt[k] = sc[k];
  for (int i = 0; i < 5; ++i) {
    int mi = i;
    for (int j = i + 1; j < 6; ++j) if (srt[j] > srt[mi]) mi = j;
    double tmp = srt[i]; srt[i] = srt[mi]; srt[mi] = tmp;
  }
  double s4 = srt[3], mx = srt[0];
  double e[6], s = 0.0;
  for (int k = 0; k < 6; ++k) {
    e[k] = (sc[k] >= s4) ? exp(sc[k] - mx) : 0.0;
    s += e[k];
  }
  for (int k = 0; k < 6; ++k) wout[(size_t)idx * 6 + k] = e[k] / s;
}

__global__ void n_mp(const double* __restrict__ w, const double* __restrict__ nb,
                     const int* __restrict__ nidx, double* __restrict__ mp) {
  int rb = blockIdx.x;
  int r = rb >> 6, b = rb & 63;
  int t = threadIdx.x;
  double a = 0.0;
  for (int k = 0; k < 6; ++k) {
    int nr = nidx[r * 6 + k];
    a += w[(size_t)rb * 6 + k] * nb[((size_t)(nr * BB + b)) * DD + t];
  }
  mp[(size_t)rb * DD + t] = a;
}

__global__ void n_mp_f(const double* __restrict__ w, const double* __restrict__ nb,
                       const int* __restrict__ nidx, const int* __restrict__ flag,
                       double* __restrict__ mp) {
  int rb = blockIdx.x;
  if (!flag[rb]) return;
  int r = rb >> 6, b = rb & 63;
  int t = threadIdx.x;
  double a = 0.0;
  for (int k = 0; k < 6; ++k) {
    int nr = nidx[r * 6 + k];
    a += w[(size_t)rb * 6 + k] * nb[((size_t)(nr * BB + b)) * DD + t];
  }
  mp[(size_t)rb * DD + t] = a;
}

__global__ void n_mm_add(const double* __restrict__ mp, const float* __restrict__ Wmat,
                         const double* __restrict__ Hs, double* __restrict__ H2) {
  int rb = blockIdx.x;
  int t = threadIdx.x;
  const double* mpp = mp + (size_t)rb * DD;
  double a = 0.0;
  for (int d = 0; d < DD; ++d) a += mpp[d] * (double)Wmat[d * DD + t];
  H2[(size_t)rb * DD + t] = Hs[(size_t)rb * DD + t] + a;
}

__global__ void n_h2_sel(const double* __restrict__ mp, const float* __restrict__ Wmat,
                         const double* __restrict__ Hs, const int* __restrict__ flag,
                         const double* __restrict__ H2H, double* __restrict__ H2out) {
  int rb = blockIdx.x;
  int t = threadIdx.x;
  size_t i = (size_t)rb * DD + t;
  if (!flag[rb]) { H2out[i] = H2H[i]; return; }
  const double* mpp = mp + (size_t)rb * DD;
  double a = 0.0;
  for (int d = 0; d < DD; ++d) a += mpp[d] * (double)Wmat[d * DD + t];
  H2out[i] = Hs[i] + a;
}

__global__ void n_hs_sel(const double* __restrict__ H, const float* __restrict__ maskA,
                         const int* __restrict__ flag, const double* __restrict__ HsH,
                         double* __restrict__ HsM) {
  int rb = blockIdx.x;
  int t = threadIdx.x;
  size_t i = (size_t)rb * DD + t;
  if (!flag[rb]) { HsM[i] = HsH[i]; return; }
  int r = rb >> 6, b = rb & 63;
  HsM[i] = H[i] * (double)maskA[b * RR + r];
}

__global__ void n_msg(const double* __restrict__ mp, const float* __restrict__ Wmat,
                      float* __restrict__ msgH) {
  int rb = blockIdx.x;
  int t = threadIdx.x;
  const double* mpp = mp + (size_t)rb * DD;
  double a = 0.0;
  for (int d = 0; d < DD; ++d) a += mpp[d] * (double)Wmat[d * DD + t];
  msgH[(size_t)rb * DD + t] = (float)a;
}

__global__ void n_zero(float* __restrict__ p) {
  p[blockIdx.x * 256 + threadIdx.x] = 0.f;
}

__global__ void n_corr_f(const double* __restrict__ mp, const float* __restrict__ Wmat,
                         const float* __restrict__ msgH, const int* __restrict__ flag,
                         float* __restrict__ corr) {
  int rb = blockIdx.x;
  if (!flag[rb]) return;
  int t = threadIdx.x;
  const double* mpp = mp + (size_t)rb * DD;
  double a = 0.0;
  for (int d = 0; d < DD; ++d) a += mpp[d] * (double)Wmat[d * DD + t];
  size_t i = (size_t)rb * DD + t;
  corr[i] += clampf((float)a - msgH[i], BR_CLAMP);
}

__global__ void n_final(const float* __restrict__ msgH, const float* __restrict__ corr,
                        float* __restrict__ out) {
  int i = blockIdx.x * 256 + threadIdx.x;
  out[i] = msgH[i] + clampf(corr[i], TOT_CLAMP);
}

__global__ void n_close(const int* __restrict__ in, const int* __restrict__ nidx,
                        int* __restrict__ out) {
  int idx = blockIdx.x * 256 + threadIdx.x;
  int r = idx >> 6, b = idx & 63;
  int v = in[idx];
  for (int k = 0; k < 6; ++k) v |= in[nidx[r * 6 + k] * BB + b];
  out[idx] = v;
}

__global__ void n_motor(const double* __restrict__ H2, const float* __restrict__ Wm,
                        const float* __restrict__ bm, double* __restrict__ motD,
                        float* __restrict__ motF) {
  int b = blockIdx.x, t = threadIdx.x;
  const double* hp = H2 + ((size_t)((RR - 1) * BB + b)) * DD;
  double a = 0.0;
  for (int d = 0; d < DD; ++d) a += hp[d] * (double)Wm[d * DD + t];
  double mo = a + (double)bm[t];
  motD[b * DD + t] = mo;
  motF[b * DD + t] = (float)mo;
}

__global__ void n_gate(const double* __restrict__ motD, const float* __restrict__ Wg,
                       int* __restrict__ sel, float* __restrict__ c2) {
  int b = threadIdx.x;
  double g[FF];
  for (int f = 0; f < FF; ++f) {
    double a = 0.0;
    for (int d = 0; d < DD; ++d) a += motD[b * DD + d] * (double)Wg[d * FF + f];
    g[f] = a;
  }
  double m1 = -INFINITY, m2 = -INFINITY;
  int i1 = -1, i2 = -1;
  for (int f = 0; f < FF; ++f) {
    if (g[f] > m1) { m2 = m1; i2 = i1; m1 = g[f]; i1 = f; }
    else if (g[f] > m2) { m2 = g[f]; i2 = f; }
  }
  double s = 0.0;
  for (int f = 0; f < FF; ++f)
    if (g[f] >= m2) s += exp(g[f] - m1);
  double lse = m1 + log(s);
  sel[b * 2 + 0] = i1;
  sel[b * 2 + 1] = i2;
  c2[b * 2 + 0] = (float)(g[i1] - lse);
  c2[b * 2 + 1] = (float)(g[i2] - lse);
}

// pi hard + inclusive alt + flag ; 16 blocks x 256 (sequential)
__global__ void n_pi_dual(const double* __restrict__ H2, const float* __restrict__ Wg,
                          double* __restrict__ piH, double* __restrict__ piA,
                          int* __restrict__ flag) {
  int idx = blockIdx.x * 256 + threadIdx.x;
  const double* hp = H2 + (size_t)idx * DD;
  double gb[FF];
  for (int f = 0; f < FF; ++f) {
    double a = 0.0;
    for (int d = 0; d < DD; ++d) a += hp[d] * (double)Wg[d * FF + f];
    gb[f] = a;
  }
  double srt[FF];
  for (int f = 0; f < FF; ++f) srt[f] = gb[f];
  for (int i = 0; i < 3; ++i) {
    int mi = i;
    for (int j = i + 1; j < FF; ++j) if (srt[j] > srt[mi]) mi = j;
    double tp = srt[i]; srt[i] = srt[mi]; srt[mi] = tp;
  }
  double m1 = srt[0], m2 = srt[1], m3 = srt[2];
  double e[FF], s = 0.0;
  for (int f = 0; f < FF; ++f) {
    e[f] = (gb[f] >= m2) ? exp(gb[f] - m1) : 0.0;
    s += e[f];
  }
  for (int f = 0; f < FF; ++f) piH[(size_t)idx * FF + f] = e[f] / s;
  double gap = m2 - m3;
  int inband = (gap > 0.0 && gap < TIE_BAND(m2, m3)) ? 1 : 0;
  flag[idx] = inband;
  if (inband) {
    double ea[FF], sa = 0.0;
    for (int f = 0; f < FF; ++f) {
      ea[f] = (gb[f] >= m3) ? exp(gb[f] - m1) : 0.0;   // inclusive keep-3
      sa += ea[f];
    }
    for (int f = 0; f < FF; ++f) piA[(size_t)idx * FF + f] = ea[f] / sa;
  } else {
    for (int f = 0; f < FF; ++f) piA[(size_t)idx * FF + f] = e[f] / s;
  }
}

// recompute-or-copy hard pi ; 16 blocks x 256 (sequential)
__global__ void n_pi_sel(const double* __restrict__ H2, const float* __restrict__ Wg,
                         const int* __restrict__ flag, const double* __restrict__ piHsrc,
                         double* __restrict__ piout) {
  int idx = blockIdx.x * 256 + threadIdx.x;
  if (!flag[idx]) {
    for (int f = 0; f < FF; ++f) piout[(size_t)idx * FF + f] = piHsrc[(size_t)idx * FF + f];
    return;
  }
  const double* hp = H2 + (size_t)idx * DD;
  double gb[FF];
  for (int f = 0; f < FF; ++f) {
    double a = 0.0;
    for (int d = 0; d < DD; ++d) a += hp[d] * (double)Wg[d * FF + f];
    gb[f] = a;
  }
  double m1 = -INFINITY, m2 = -INFINITY;
  for (int f = 0; f < FF; ++f) {
    if (gb[f] > m1) { m2 = m1; m1 = gb[f]; }
    else if (gb[f] > m2) { m2 = gb[f]; }
  }
  double e[FF], s = 0.0;
  for (int f = 0; f < FF; ++f) {
    e[f] = (gb[f] >= m2) ? exp(gb[f] - m1) : 0.0;
    s += e[f];
  }
  for (int f = 0; f < FF; ++f) piout[(size_t)idx * FF + f] = e[f] / s;
}

__global__ void n_bc(const double* __restrict__ H2, const double* __restrict__ pi,
                     const float* __restrict__ e_fac, const float* __restrict__ boost_p,
                     double* __restrict__ Bc) {
  int rb = blockIdx.x, t = threadIdx.x;
  double ef = 0.0;
  for (int f = 0; f < FF; ++f) ef += pi[(size_t)rb * FF + f] * (double)e_fac[f * DD + t];
  double boost = (double)(*boost_p);
  Bc[(size_t)rb * DD + t] = H2[(size_t)rb * DD + t] * ef * boost;
}

__global__ void n_bc_sel(const double* __restrict__ H2, const double* __restrict__ pi,
                         const float* __restrict__ e_fac, const float* __restrict__ boost_p,
                         const int* __restrict__ flag, const double* __restrict__ BcH,
                         double* __restrict__ Bc2) {
  int rb = blockIdx.x, t = threadIdx.x;
  size_t i = (size_t)rb * DD + t;
  if (!flag[rb]) { Bc2[i] = BcH[i]; return; }
  double ef = 0.0;
  for (int f = 0; f < FF; ++f) ef += pi[(size_t)rb * FF + f] * (double)e_fac[f * DD + t];
  double boost = (double)(*boost_p);
  Bc2[i] = H2[i] * ef * boost;
}

// =================== f32 logp-path kernels ===================

// z2: register-tiled 8b x 8v; grid (125, 7), 256 thr  (validated r17)
__global__ void k_z2(const float* __restrict__ motor, const float* __restrict__ Wf,
                     const int* __restrict__ sel, float* __restrict__ z2) {
  int vc = blockIdx.x, f = blockIdx.y;
  int t = threadIdx.x;
  int vg = t & 31, bg = t >> 5;
  __shared__ float mt[32][65];
  __shared__ float wt[32][256];
  __shared__ int selL[128];
  if (t < 128) selL[t] = sel[t];
  float acc[8][8];
#pragma unroll
  for (int i = 0; i < 8; ++i)
#pragma unroll
    for (int j = 0; j < 8; ++j) acc[i][j] = 0.f;
  const float* wf = Wf + (size_t)f * DD * VV;
  for (int dt = 0; dt < 8; ++dt) {
    for (int i = t; i < 2048; i += 256) {
      int d = i & 31, b = i >> 5;
      mt[d][b] = motor[b * DD + dt * 32 + d];
    }
    for (int i = t; i < 8192; i += 256) {
      int d = i >> 8, v = i & 255;
      wt[d][v] = wf[(size_t)(dt * 32 + d) * VV + vc * 256 + v];
    }
    __syncthreads();
    for (int d = 0; d < 32; ++d) {
      float bv[8], wv[8];
#pragma unroll
      for (int i = 0; i < 8; ++i) bv[i] = mt[d][bg * 8 + i];
#pragma unroll
      for (int j = 0; j < 8; ++j) wv[j] = wt[d][vg + j * 32];
#pragma unroll
      for (int i = 0; i < 8; ++i)
#pragma unroll
        for (int j = 0; j < 8; ++j) acc[i][j] += bv[i] * wv[j];
    }
    __syncthreads();
  }
#pragma unroll
  for (int i = 0; i < 8; ++i) {
    int b = bg * 8 + i;
    int s0 = selL[b * 2 + 0], s1 = selL[b * 2 + 1];
    if (s0 == f) {
#pragma unroll
      for (int j = 0; j < 8; ++j)
        z2[((size_t)(b * 2 + 0)) * VV + vc * 256 + vg + j * 32] = acc[i][j];
    }
    if (s1 == f) {
#pragma unroll
      for (int j = 0; j < 8; ++j)
        z2[((size_t)(b * 2 + 1)) * VV + vc * 256 + vg + j * 32] = acc[i][j];
    }
  }
}

__global__ void k_lse(const float* __restrict__ z2, float* __restrict__ lse) {
  int row = blockIdx.x;
  int t = threadIdx.x;
  const float* zp = z2 + (size_t)row * VV;
  float m = -INFINITY, s = 0.f;
  for (int v = t; v < VV; v += 256) {
    float val = zp[v];
    if (val > m) { s = s * expf(m - val) + 1.f; m = val; }
    else s += expf(val - m);
  }
  __shared__ float sm[256], ss[256];
  sm[t] = m; ss[t] = s;
  __syncthreads();
  for (int off = 128; off > 0; off >>= 1) {
    if (t < off) {
      float m2 = sm[t + off], s2 = ss[t + off], m1 = sm[t], s1 = ss[t];
      float M = fmaxf(m1, m2);
      sm[t] = M;
      ss[t] = s1 * expf(m1 - M) + s2 * expf(m2 - M);
    }
    __syncthreads();
  }
  if (t == 0) lse[row] = sm[0] + logf(ss[0]);
}

__global__ void k_logp(const float* __restrict__ z2, const float* __restrict__ c2,
                       const float* __restrict__ lse, float* __restrict__ out_logp) {
  int b = blockIdx.y;
  int v = blockIdx.x * 256 + threadIdx.x;
  float a0 = c2[b * 2 + 0] - lse[b * 2 + 0] + z2[((size_t)(b * 2 + 0)) * VV + v];
  float a1 = c2[b * 2 + 1] - lse[b * 2 + 1] + z2[((size_t)(b * 2 + 1)) * VV + v];
  float M = fmaxf(a0, a1);
  out_logp[(size_t)b * VV + v] = M + logf(expf(a0 - M) + expf(a1 - M));
}

__global__ void k_loss(const float* __restrict__ out_logp, const int* __restrict__ targets,
                       float* __restrict__ out_loss, float* __restrict__ boost) {
  int b = threadIdx.x;
  float v = out_logp[(size_t)b * VV + targets[b]];
#pragma unroll
  for (int off = 32; off > 0; off >>= 1) v += __shfl_xor(v, off, 64);
  if (b == 0) {
    float loss = -v / 64.f;
    *out_loss = loss;
    *boost = 1.f + 2.f * ((loss > 0.7f) ? 1.f : 0.f);
  }
}

// =================== launch ===================
extern "C" void kernel_launch(void* const* d_in, const int* in_sizes, int n_in,
                              void* d_out, int out_size, void* d_ws, size_t ws_size,
                              hipStream_t stream) {
  const float* x       = (const float*)d_in[0];
  const int*   targets = (const int*)d_in[1];
  const int*   nidx    = (const int*)d_in[2];
  const float* W1      = (const float*)d_in[3];
  const float* b1      = (const float*)d_in[4];
  const float* W2      = (const float*)d_in[5];
  const float* b2      = (const float*)d_in[6];
  const float* w_gate  = (const float*)d_in[7];
  const float* Wr      = (const float*)d_in[8];
  const float* Wm      = (const float*)d_in[9];
  const float* bm      = (const float*)d_in[10];
  const float* Wg      = (const float*)d_in[11];
  const float* Wf      = (const float*)d_in[12];
  const float* e_fac   = (const float*)d_in[13];
  const float* Wb      = (const float*)d_in[14];

  float* out_logp = (float*)d_out;
  float* out_loss = out_logp + (size_t)BB * VV;
  float* out_msg  = out_loss + 1;

  double* dH   = (double*)d_ws;               // 1048576 d each
  double* dHs  = dH + 1048576;
  double* dHsM = dHs + 1048576;
  double* dH2  = dHsM + 1048576;
  double* dH2b = dH2 + 1048576;
  double* dBc  = dH2b + 1048576;
  double* dBcA = dBc + 1048576;
  double* dHid = dBcA + 1048576;              // 4194304 d region (hid; overlaid later)
  float*  fZ2  = (float*)dHid;                //   z2: doubles [0 .. 2048000)
  double* dMp  = dHid + 2097152;              //   [2097152 .. 3145728)
  double* dMpA = dHid + 3145728;              //   [3145728 .. 4194304)
  double* dScg = dHid + 4194304;              // 4096
  double* dW6h = dScg + 4096;                 // 24576 each
  double* dW6a = dW6h + 24576;
  double* dW6b = dW6a + 24576;
  double* dW2h = dW6b + 24576;
  double* dW2a = dW2h + 24576;
  double* dW2b = dW2a + 24576;
  double* dPiH = dW2b + 24576;                // 28672 each
  double* dPiA = dPiH + 28672;
  double* dPiH2= dPiA + 28672;
  double* dMotD= dPiH2 + 28672;               // 16384
  float*  fMaskH = (float*)(dMotD + 16384);   // 4096
  float*  fMaskA = fMaskH + 4096;             // 4096
  float*  fMsgH  = fMaskA + 4096;             // 1048576 f
  float*  fCorr  = fMsgH + 1048576;           // 1048576 f
  float*  fMotF  = fCorr + 1048576;           // 16384
  float*  fC2    = fMotF + 16384;             // 128
  float*  fLse   = fC2 + 128;                 // 128
  float*  fBoost = fLse + 128;                // 1
  int*    iSel   = (int*)(fBoost + 1);        // 128
  int*    fW1    = iSel + 128;                // 4096 each
  int*    fW2    = fW1 + 4096;
  int*    fPi    = fW2 + 4096;
  int*    fM     = fPi + 4096;
  int*    cPi    = fM + 4096;
  int*    cW1    = cPi + 4096;
  int*    cM     = cW1 + 4096;
  int*    cM2    = cM + 4096;

  // ---- trunk ----
  t_hid<<<dim3(8, 64), 256, 0, stream>>>(x, W1, b1, dHid);
  t_H<<<dim3(4, 64), 256, 0, stream>>>(dHid, W2, b2, dH);
  n_scg<<<16, 256, 0, stream>>>(dH, w_gate, dScg);
  n_mask_dual<<<1, 64, 0, stream>>>(dScg, fMaskH, fMaskA, fM);
  n_hs<<<4096, 256, 0, stream>>>(dH, fMaskH, dHs);
  n_w6x<<<16, 256, 0, stream>>>(dHs, dHs, nidx, dW6h, dW6a, fW1);
  n_mp<<<4096, 256, 0, stream>>>(dW6h, dHs, nidx, dMp);
  n_mm_add<<<4096, 256, 0, stream>>>(dMp, Wr, dHs, dH2);
  // ---- logp path ----
  n_motor<<<64, 256, 0, stream>>>(dH2, Wm, bm, dMotD, fMotF);
  n_gate<<<1, 64, 0, stream>>>(dMotD, Wg, iSel, fC2);
  k_z2<<<dim3(125, 7), 256, 0, stream>>>(fMotF, Wf, iSel, fZ2);
  k_lse<<<128, 256, 0, stream>>>(fZ2, fLse);
  k_logp<<<dim3(125, BB), 256, 0, stream>>>(fZ2, fC2, fLse, out_logp);
  k_loss<<<1, 64, 0, stream>>>(out_logp, targets, out_loss, fBoost);
  // ---- pass-2 hard -> msg_h ----
  n_pi_dual<<<16, 256, 0, stream>>>(dH2, Wg, dPiH, dPiA, fPi);
  n_bc<<<4096, 256, 0, stream>>>(dH2, dPiH, e_fac, fBoost, dBc);
  n_w6x<<<16, 256, 0, stream>>>(dH2, dBc, nidx, dW2h, dW2a, fW2);
  n_mp<<<4096, 256, 0, stream>>>(dW2h, dBc, nidx, dMp);
  n_msg<<<4096, 256, 0, stream>>>(dMp, Wb, fMsgH);
  n_zero<<<4096, 256, 0, stream>>>(fCorr);
  // ---- BR_W2 (sparse) ----
  n_mp_f<<<4096, 256, 0, stream>>>(dW2a, dBc, nidx, fW2, dMpA);
  n_corr_f<<<4096, 256, 0, stream>>>(dMpA, Wb, fMsgH, fW2, fCorr);
  // ---- BR_PI (sparse) ----
  n_bc_sel<<<4096, 256, 0, stream>>>(dH2, dPiA, e_fac, fBoost, fPi, dBc, dBcA);
  n_close<<<16, 256, 0, stream>>>(fPi, nidx, cPi);
  n_w6_sel<<<16, 256, 0, stream>>>(dH2, dBcA, nidx, cPi, dW2h, dW2b);
  n_mp_f<<<4096, 256, 0, stream>>>(dW2b, dBcA, nidx, cPi, dMpA);
  n_corr_f<<<4096, 256, 0, stream>>>(dMpA, Wb, fMsgH, cPi, fCorr);
  // ---- BR_W1 (sparse) ----
  n_mp_f<<<4096, 256, 0, stream>>>(dW6a, dHs, nidx, fW1, dMpA);
  n_h2_sel<<<4096, 256, 0, stream>>>(dMpA, Wr, dHs, fW1, dH2, dH2b);
  n_pi_sel<<<16, 256, 0, stream>>>(dH2b, Wg, fW1, dPiH, dPiH2);
  n_bc_sel<<<4096, 256, 0, stream>>>(dH2b, dPiH2, e_fac, fBoost, fW1, dBc, dBcA);
  n_close<<<16, 256, 0, stream>>>(fW1, nidx, cW1);
  n_w6_sel<<<16, 256, 0, stream>>>(dH2b, dBcA, nidx, cW1, dW2h, dW2b);
  n_mp_f<<<4096, 256, 0, stream>>>(dW2b, dBcA, nidx, cW1, dMpA);
  n_corr_f<<<4096, 256, 0, stream>>>(dMpA, Wb, fMsgH, cW1, fCorr);
  // ---- BR_M (sparse) ----
  n_hs_sel<<<4096, 256, 0, stream>>>(dH, fMaskA, fM, dHs, dHsM);
  n_close<<<16, 256, 0, stream>>>(fM, nidx, cM);
  n_w6_sel<<<16, 256, 0, stream>>>(dHsM, dHsM, nidx, cM, dW6h, dW6b);
  n_mp_f<<<4096, 256, 0, stream>>>(dW6b, dHsM, nidx, cM, dMpA);
  n_h2_sel<<<4096, 256, 0, stream>>>(dMpA, Wr, dHsM, cM, dH2, dH2b);
  n_pi_sel<<<16, 256, 0, stream>>>(dH2b, Wg, cM, dPiH, dPiH2);
  n_bc_sel<<<4096, 256, 0, stream>>>(dH2b, dPiH2, e_fac, fBoost, cM, dBc, dBcA);
  n_close<<<16, 256, 0, stream>>>(cM, nidx, cM2);
  n_w6_sel<<<16, 256, 0, stream>>>(dH2b, dBcA, nidx, cM2, dW2h, dW2b);
  n_mp_f<<<4096, 256, 0, stream>>>(dW2b, dBcA, nidx, cM2, dMpA);
  n_corr_f<<<4096, 256, 0, stream>>>(dMpA, Wb, fMsgH, cM2, fCorr);
  // ---- final ----
  n_final<<<4096, 256, 0, stream>>>(fMsgH, fCorr, out_msg);
}

// Round 19
// 939.218 us; speedup vs baseline: 3.1237x; 1.4451x over previous
//
#include <hip/hip_runtime.h>

#define RR 64
#define BB 64
#define DD 256
#define DFF_ 1024
#define VV 32000
#define FF 7

#define TIE_BAND(a, b) (2e-6 * (1.0 + 0.5 * (fabs(a) + fabs(b))))
#define BR_CLAMP 0.30f
#define TOT_CLAMP 0.19f

__device__ __forceinline__ float clampf(float x, float c) {
  return fminf(fmaxf(x, -c), c);
}

// =================== tiled trunk kernels (register-blocked, order-identical) ===================

// hid = gelu(x@W1+b1); grid (16,64), 256 thr; tile 64b x 64f; thread 4b x 4f
__global__ void t_hid(const float* __restrict__ x, const float* __restrict__ W1,
                      const float* __restrict__ b1, double* __restrict__ hid) {
  int fc = blockIdx.x, r = blockIdx.y;
  int t = threadIdx.x;
  int fg = t & 15, bg = t >> 4;
  __shared__ float xs[64][65];             // [d][b]
  __shared__ float w1t[64][64];            // [d][f]
  double acc[4][4];
#pragma unroll
  for (int i = 0; i < 4; ++i)
#pragma unroll
    for (int j = 0; j < 4; ++j) acc[i][j] = 0.0;
  const float* xr = x + (size_t)r * BB * DD;
  const float* w1r = W1 + (size_t)r * DD * DFF_;
  for (int dt = 0; dt < 4; ++dt) {
    for (int i = t; i < 4096; i += 256) {
      int d = i & 63, b = i >> 6;
      xs[d][b] = xr[b * DD + dt * 64 + d];
    }
    for (int i = t; i < 4096; i += 256) {
      int dd = i >> 6, ff = i & 63;
      w1t[dd][ff] = w1r[(size_t)(dt * 64 + dd) * DFF_ + fc * 64 + ff];
    }
    __syncthreads();
    for (int d = 0; d < 64; ++d) {         // global k ascending, single accumulator
      double bv[4], wv[4];
#pragma unroll
      for (int i = 0; i < 4; ++i) bv[i] = (double)xs[d][bg * 4 + i];
#pragma unroll
      for (int j = 0; j < 4; ++j) wv[j] = (double)w1t[d][fg * 4 + j];
#pragma unroll
      for (int i = 0; i < 4; ++i)
#pragma unroll
        for (int j = 0; j < 4; ++j) acc[i][j] += bv[i] * wv[j];
    }
    __syncthreads();
  }
#pragma unroll
  for (int i = 0; i < 4; ++i) {
    int b = bg * 4 + i;
#pragma unroll
    for (int j = 0; j < 4; ++j) {
      int f = fc * 64 + fg * 4 + j;
      double v = acc[i][j] + (double)b1[r * DFF_ + f];
      hid[((size_t)(r * BB + b)) * DFF_ + f] =
          0.5 * v * (1.0 + erf(v * 0.70710678118654752440));
    }
  }
}

// H = h + CTAU*h; grid (8,2,64), 256 thr; tile 32b x 32d; thread 2b x 2d
__global__ void t_H(const double* __restrict__ hid, const float* __restrict__ W2,
                    const float* __restrict__ b2, double* __restrict__ H) {
  int dc = blockIdx.x, bc = blockIdx.y, r = blockIdx.z;
  int t = threadIdx.x;
  int dg = t & 15, bg = t >> 4;
  __shared__ double ht[64][33];            // [f][b-half]
  __shared__ float wt[64][32];             // [f][d-chunk]
  double acc[2][2];
#pragma unroll
  for (int i = 0; i < 2; ++i)
#pragma unroll
    for (int j = 0; j < 2; ++j) acc[i][j] = 0.0;
  const double* hr = hid + (size_t)r * BB * DFF_;
  const float* w2r = W2 + (size_t)r * DFF_ * DD;
  for (int ft = 0; ft < 16; ++ft) {
    for (int i = t; i < 2048; i += 256) {
      int f = i & 63, b = i >> 6;
      ht[f][b] = hr[(size_t)(bc * 32 + b) * DFF_ + ft * 64 + f];
    }
    for (int i = t; i < 2048; i += 256) {
      int f = i >> 5, d = i & 31;
      wt[f][d] = w2r[(size_t)(ft * 64 + f) * DD + dc * 32 + d];
    }
    __syncthreads();
    for (int f = 0; f < 64; ++f) {         // global k ascending
      double hb[2], wv[2];
#pragma unroll
      for (int i = 0; i < 2; ++i) hb[i] = ht[f][bg * 2 + i];
#pragma unroll
      for (int j = 0; j < 2; ++j) wv[j] = (double)wt[f][dg * 2 + j];
#pragma unroll
      for (int i = 0; i < 2; ++i)
#pragma unroll
        for (int j = 0; j < 2; ++j) acc[i][j] += hb[i] * wv[j];
    }
    __syncthreads();
  }
#pragma unroll
  for (int i = 0; i < 2; ++i) {
    int b = bc * 32 + bg * 2 + i;
#pragma unroll
    for (int j = 0; j < 2; ++j) {
      int d = dc * 32 + dg * 2 + j;
      double h = acc[i][j] + (double)b2[r * DD + d];
      H[((size_t)(r * BB + b)) * DD + d] = h + 0.20333333 * h;
    }
  }
}

// =================== staged gate kernels (lane-0 serial, bitwise-frozen order) ===================

// scg: 1024 blocks x 256 (wave-per-site)
__global__ void n_scg(const double* __restrict__ H, const float* __restrict__ wg,
                      double* __restrict__ scg) {
  __shared__ double hbuf[4][256];
  __shared__ float wgs[256];
  int t = threadIdx.x;
  int wv = t >> 6, lane = t & 63;
  int idx = blockIdx.x * 4 + wv;
  int r = idx >> 6, b = idx & 63;
  const double* hp = H + (size_t)idx * DD;
  wgs[t] = wg[t];
#pragma unroll
  for (int j = 0; j < 4; ++j) hbuf[wv][lane + j * 64] = hp[lane + j * 64];
  __syncthreads();
  if (lane == 0) {
    double a = 0.0;
    for (int d = 0; d < DD; ++d) a += hbuf[wv][d] * (double)wgs[d];
    scg[b * RR + r] = a;
  }
}

// hard mask + inclusive alt + per-rb flag ; 1 block x 64
__global__ void n_mask_dual(const double* __restrict__ scg, float* __restrict__ maskH,
                            float* __restrict__ maskA, int* __restrict__ flagM) {
  int b = threadIdx.x;
  double v[64], w[64];
  for (int r = 0; r < RR; ++r) { v[r] = scg[b * RR + r]; w[r] = v[r]; }
  double k6 = 0.0, k7 = 0.0;
  int i6 = -1, i7 = -1;
  for (int it = 0; it < 7; ++it) {
    int mi = 0;
    for (int r = 1; r < RR; ++r) if (w[r] > w[mi]) mi = r;
    if (it == 5) { k6 = w[mi]; i6 = mi; }
    if (it == 6) { k7 = w[mi]; i7 = mi; }
    w[mi] = -INFINITY;
  }
  double gap = k6 - k7;
  int tie = (gap > 0.0 && gap < TIE_BAND(k6, k7)) ? 1 : 0;
  for (int r = 0; r < RR; ++r) {
    float mh = (v[r] >= k6 || r == 0 || r == RR - 1) ? 1.f : 0.f;
    maskH[b * RR + r] = mh;
    maskA[b * RR + r] = tie ? ((v[r] >= k7 || r == 0 || r == RR - 1) ? 1.f : 0.f) : mh;
    flagM[r * BB + b] = 0;
  }
  if (tie) {
    flagM[i6 * BB + b] = 1;
    flagM[i7 * BB + b] = 1;
  }
}

__global__ void n_hs(const double* __restrict__ H, const float* __restrict__ mask,
                     double* __restrict__ Hs) {
  int idx = blockIdx.x * 256 + threadIdx.x;
  int r = idx >> 14;
  int b = (idx >> 8) & 63;
  Hs[idx] = H[idx] * (double)mask[b * RR + r];
}

// top-4 gated softmax: block-per-site, staged, lane-0 serial ; 4096 blocks x 64
__global__ void n_w6x(const double* __restrict__ self, const double* __restrict__ nb,
                      const int* __restrict__ nidx, double* __restrict__ wout,
                      double* __restrict__ walt, int* __restrict__ flag) {
  __shared__ double sbuf[256];
  __shared__ double qbuf[6][256];
  int idx = blockIdx.x;
  int r = idx >> 6, b = idx & 63;
  int lane = threadIdx.x;
  const double* sp = self + (size_t)idx * DD;
#pragma unroll
  for (int j = 0; j < 4; ++j) sbuf[lane + j * 64] = sp[lane + j * 64];
  for (int k = 0; k < 6; ++k) {
    int nr = nidx[r * 6 + k];
    const double* qp = nb + ((size_t)(nr * BB + b)) * DD;
#pragma unroll
    for (int j = 0; j < 4; ++j) qbuf[k][lane + j * 64] = qp[lane + j * 64];
  }
  __syncthreads();
  if (lane == 0) {
    double sc[6];
    for (int k = 0; k < 6; ++k) {
      double a = 0.0;
      for (int d = 0; d < DD; ++d) a += sbuf[d] * qbuf[k][d];
      sc[k] = a * 0.0625;
    }
    double srt[6];
    for (int k = 0; k < 6; ++k) srt[k] = sc[k];
    for (int i = 0; i < 5; ++i) {
      int mi = i;
      for (int j = i + 1; j < 6; ++j) if (srt[j] > srt[mi]) mi = j;
      double tmp = srt[i]; srt[i] = srt[mi]; srt[mi] = tmp;
    }
    double s4 = srt[3], s5 = srt[4], mx = srt[0];
    double e[6], s = 0.0;
    for (int k = 0; k < 6; ++k) {
      e[k] = (sc[k] >= s4) ? exp(sc[k] - mx) : 0.0;
      s += e[k];
    }
    for (int k = 0; k < 6; ++k) wout[(size_t)idx * 6 + k] = e[k] / s;
    double gap = s4 - s5;
    int inband = (gap > 0.0 && gap < TIE_BAND(s4, s5)) ? 1 : 0;
    flag[idx] = inband;
    if (inband) {
      double ea[6], sa = 0.0;
      for (int k = 0; k < 6; ++k) {
        ea[k] = (sc[k] >= s5) ? exp(sc[k] - mx) : 0.0;   // inclusive keep-5
        sa += ea[k];
      }
      for (int k = 0; k < 6; ++k) walt[(size_t)idx * 6 + k] = ea[k] / sa;
    } else {
      for (int k = 0; k < 6; ++k) walt[(size_t)idx * 6 + k] = e[k] / s;
    }
  }
}

// recompute-or-copy hard top-4 softmax ; 4096 blocks x 64
__global__ void n_w6_sel(const double* __restrict__ self, const double* __restrict__ nb,
                         const int* __restrict__ nidx, const int* __restrict__ flag,
                         const double* __restrict__ wH, double* __restrict__ wout) {
  __shared__ double sbuf[256];
  __shared__ double qbuf[6][256];
  int idx = blockIdx.x;
  int r = idx >> 6, b = idx & 63;
  int lane = threadIdx.x;
  int inb = flag[idx];
  if (inb) {
    const double* sp = self + (size_t)idx * DD;
#pragma unroll
    for (int j = 0; j < 4; ++j) sbuf[lane + j * 64] = sp[lane + j * 64];
    for (int k = 0; k < 6; ++k) {
      int nr = nidx[r * 6 + k];
      const double* qp = nb + ((size_t)(nr * BB + b)) * DD;
#pragma unroll
      for (int j = 0; j < 4; ++j) qbuf[k][lane + j * 64] = qp[lane + j * 64];
    }
  }
  __syncthreads();
  if (!inb) {
    if (lane < 6) wout[(size_t)idx * 6 + lane] = wH[(size_t)idx * 6 + lane];
    return;
  }
  if (lane == 0) {
    double sc[6];
    for (int k = 0; k < 6; ++k) {
      double a = 0.0;
      for (int d = 0; d < DD; ++d) a += sbuf[d] * qbuf[k][d];
      sc[k] = a * 0.0625;
    }
    double srt[6];
    for (int k = 0; k < 6; ++k) srt[k] = sc[k];
    for (int i = 0; i < 4; ++i) {
      int mi = i;
      for (int j = i + 1; j < 6; ++j) if (srt[j] > srt[mi]) mi = j;
      double tmp = srt[i]; srt[i] = srt[mi]; srt[mi] = tmp;
    }
    double s4 = srt[3], mx = srt[0];
    double e[6], s = 0.0;
    for (int k = 0; k < 6; ++k) {
      e[k] = (sc[k] >= s4) ? exp(sc[k] - mx) : 0.0;
      s += e[k];
    }
    for (int k = 0; k < 6; ++k) wout[(size_t)idx * 6 + k] = e[k] / s;
  }
}

// =================== fused mp -> consumer kernels (LDS mp, same order) ===================

// H2 = Hs + (mp @ Wmat) ; 4096 blocks x 256
__global__ void f_mp_mm(const double* __restrict__ w, const double* __restrict__ nb,
                        const int* __restrict__ nidx, const float* __restrict__ Wmat,
                        const double* __restrict__ Hs, double* __restrict__ H2) {
  __shared__ double mpL[256];
  int rb = blockIdx.x;
  int r = rb >> 6, b = rb & 63;
  int t = threadIdx.x;
  double a = 0.0;
  for (int k = 0; k < 6; ++k) {
    int nr = nidx[r * 6 + k];
    a += w[(size_t)rb * 6 + k] * nb[((size_t)(nr * BB + b)) * DD + t];
  }
  mpL[t] = a;
  __syncthreads();
  double s2 = 0.0;
  for (int d = 0; d < DD; ++d) s2 += mpL[d] * (double)Wmat[d * DD + t];
  size_t i = (size_t)rb * DD + t;
  H2[i] = Hs[i] + s2;
}

// msgH = f32(mp @ Wmat) ; 4096 blocks x 256
__global__ void f_mp_msg(const double* __restrict__ w, const double* __restrict__ nb,
                         const int* __restrict__ nidx, const float* __restrict__ Wmat,
                         float* __restrict__ msgH) {
  __shared__ double mpL[256];
  int rb = blockIdx.x;
  int r = rb >> 6, b = rb & 63;
  int t = threadIdx.x;
  double a = 0.0;
  for (int k = 0; k < 6; ++k) {
    int nr = nidx[r * 6 + k];
    a += w[(size_t)rb * 6 + k] * nb[((size_t)(nr * BB + b)) * DD + t];
  }
  mpL[t] = a;
  __syncthreads();
  double s2 = 0.0;
  for (int d = 0; d < DD; ++d) s2 += mpL[d] * (double)Wmat[d * DD + t];
  msgH[(size_t)rb * DD + t] = (float)s2;
}

// corr += clamp(f32(mp @ Wmat) - msgH) gated ; 4096 blocks x 256
__global__ void f_mp_corr(const double* __restrict__ w, const double* __restrict__ nb,
                          const int* __restrict__ nidx, const int* __restrict__ flag,
                          const float* __restrict__ Wmat, const float* __restrict__ msgH,
                          float* __restrict__ corr) {
  int rb = blockIdx.x;
  if (!flag[rb]) return;
  __shared__ double mpL[256];
  int r = rb >> 6, b = rb & 63;
  int t = threadIdx.x;
  double a = 0.0;
  for (int k = 0; k < 6; ++k) {
    int nr = nidx[r * 6 + k];
    a += w[(size_t)rb * 6 + k] * nb[((size_t)(nr * BB + b)) * DD + t];
  }
  mpL[t] = a;
  __syncthreads();
  double s2 = 0.0;
  for (int d = 0; d < DD; ++d) s2 += mpL[d] * (double)Wmat[d * DD + t];
  size_t i = (size_t)rb * DD + t;
  corr[i] += clampf((float)s2 - msgH[i], BR_CLAMP);
}

// H2out = flag ? Hs + mp@Wmat : copy H2H ; 4096 blocks x 256
__global__ void f_mp_h2sel(const double* __restrict__ w, const double* __restrict__ nb,
                           const int* __restrict__ nidx, const int* __restrict__ flag,
                           const float* __restrict__ Wmat, const double* __restrict__ Hs,
                           const double* __restrict__ H2H, double* __restrict__ H2out) {
  int rb = blockIdx.x;
  int t = threadIdx.x;
  size_t i = (size_t)rb * DD + t;
  if (!flag[rb]) { H2out[i] = H2H[i]; return; }
  __shared__ double mpL[256];
  int r = rb >> 6, b = rb & 63;
  double a = 0.0;
  for (int k = 0; k < 6; ++k) {
    int nr = nidx[r * 6 + k];
    a += w[(size_t)rb * 6 + k] * nb[((size_t)(nr * BB + b)) * DD + t];
  }
  mpL[t] = a;
  __syncthreads();
  double s2 = 0.0;
  for (int d = 0; d < DD; ++d) s2 += mpL[d] * (double)Wmat[d * DD + t];
  H2out[i] = Hs[i] + s2;
}

// =================== misc kernels ===================

__global__ void n_hs_sel(const double* __restrict__ H, const float* __restrict__ maskA,
                         const int* __restrict__ flag, const double* __restrict__ HsH,
                         double* __restrict__ HsM) {
  int rb = blockIdx.x;
  int t = threadIdx.x;
  size_t i = (size_t)rb * DD + t;
  if (!flag[rb]) { HsM[i] = HsH[i]; return; }
  int r = rb >> 6, b = rb & 63;
  HsM[i] = H[i] * (double)maskA[b * RR + r];
}

__global__ void n_zero(float* __restrict__ p) {
  p[blockIdx.x * 256 + threadIdx.x] = 0.f;
}

__global__ void n_final(const float* __restrict__ msgH, const float* __restrict__ corr,
                        float* __restrict__ out) {
  int i = blockIdx.x * 256 + threadIdx.x;
  out[i] = msgH[i] + clampf(corr[i], TOT_CLAMP);
}

__global__ void n_close(const int* __restrict__ in, const int* __restrict__ nidx,
                        int* __restrict__ out) {
  int idx = blockIdx.x * 256 + threadIdx.x;
  int r = idx >> 6, b = idx & 63;
  int v = in[idx];
  for (int k = 0; k < 6; ++k) v |= in[nidx[r * 6 + k] * BB + b];
  out[idx] = v;
}

__global__ void n_motor(const double* __restrict__ H2, const float* __restrict__ Wm,
                        const float* __restrict__ bm, double* __restrict__ motD,
                        float* __restrict__ motF) {
  int b = blockIdx.x, t = threadIdx.x;
  const double* hp = H2 + ((size_t)((RR - 1) * BB + b)) * DD;
  double a = 0.0;
  for (int d = 0; d < DD; ++d) a += hp[d] * (double)Wm[d * DD + t];
  double mo = a + (double)bm[t];
  motD[b * DD + t] = mo;
  motF[b * DD + t] = (float)mo;
}

// facet top-2 gate: block-per-b, staged, lane-0 serial ; 64 blocks x 64
__global__ void n_gate(const double* __restrict__ motD, const float* __restrict__ Wg,
                       int* __restrict__ sel, float* __restrict__ c2) {
  __shared__ double mbuf[256];
  __shared__ float wgb[1792];
  int b = blockIdx.x;
  int lane = threadIdx.x;
#pragma unroll
  for (int j = 0; j < 4; ++j) mbuf[lane + j * 64] = motD[b * DD + lane + j * 64];
  for (int i = lane; i < 1792; i += 64) wgb[i] = Wg[i];
  __syncthreads();
  if (lane == 0) {
    double g[FF];
    for (int f = 0; f < FF; ++f) {
      double a = 0.0;
      for (int d = 0; d < DD; ++d) a += mbuf[d] * (double)wgb[d * FF + f];
      g[f] = a;
    }
    double m1 = -INFINITY, m2 = -INFINITY;
    int i1 = -1, i2 = -1;
    for (int f = 0; f < FF; ++f) {
      if (g[f] > m1) { m2 = m1; i2 = i1; m1 = g[f]; i1 = f; }
      else if (g[f] > m2) { m2 = g[f]; i2 = f; }
    }
    double s = 0.0;
    for (int f = 0; f < FF; ++f)
      if (g[f] >= m2) s += exp(g[f] - m1);
    double lse = m1 + log(s);
    sel[b * 2 + 0] = i1;
    sel[b * 2 + 1] = i2;
    c2[b * 2 + 0] = (float)(g[i1] - lse);
    c2[b * 2 + 1] = (float)(g[i2] - lse);
  }
}

// pi hard + inclusive alt + flag: wave-per-site staged ; 1024 blocks x 256
__global__ void n_pi_dual(const double* __restrict__ H2, const float* __restrict__ Wg,
                          double* __restrict__ piH, double* __restrict__ piA,
                          int* __restrict__ flag) {
  __shared__ double hbuf[4][256];
  __shared__ float wgb[1792];
  int t = threadIdx.x;
  int wv = t >> 6, lane = t & 63;
  int idx = blockIdx.x * 4 + wv;
  const double* hp = H2 + (size_t)idx * DD;
#pragma unroll
  for (int j = 0; j < 4; ++j) hbuf[wv][lane + j * 64] = hp[lane + j * 64];
  for (int i = t; i < 1792; i += 256) wgb[i] = Wg[i];
  __syncthreads();
  if (lane == 0) {
    double gb[FF];
    for (int f = 0; f < FF; ++f) {
      double a = 0.0;
      for (int d = 0; d < DD; ++d) a += hbuf[wv][d] * (double)wgb[d * FF + f];
      gb[f] = a;
    }
    double srt[FF];
    for (int f = 0; f < FF; ++f) srt[f] = gb[f];
    for (int i = 0; i < 3; ++i) {
      int mi = i;
      for (int j = i + 1; j < FF; ++j) if (srt[j] > srt[mi]) mi = j;
      double tp = srt[i]; srt[i] = srt[mi]; srt[mi] = tp;
    }
    double m1 = srt[0], m2 = srt[1], m3 = srt[2];
    double e[FF], s = 0.0;
    for (int f = 0; f < FF; ++f) {
      e[f] = (gb[f] >= m2) ? exp(gb[f] - m1) : 0.0;
      s += e[f];
    }
    for (int f = 0; f < FF; ++f) piH[(size_t)idx * FF + f] = e[f] / s;
    double gap = m2 - m3;
    int inband = (gap > 0.0 && gap < TIE_BAND(m2, m3)) ? 1 : 0;
    flag[idx] = inband;
    if (inband) {
      double ea[FF], sa = 0.0;
      for (int f = 0; f < FF; ++f) {
        ea[f] = (gb[f] >= m3) ? exp(gb[f] - m1) : 0.0;   // inclusive keep-3
        sa += ea[f];
      }
      for (int f = 0; f < FF; ++f) piA[(size_t)idx * FF + f] = ea[f] / sa;
    } else {
      for (int f = 0; f < FF; ++f) piA[(size_t)idx * FF + f] = e[f] / s;
    }
  }
}

// recompute-or-copy hard pi: wave-per-site staged ; 1024 blocks x 256
__global__ void n_pi_sel(const double* __restrict__ H2, const float* __restrict__ Wg,
                         const int* __restrict__ flag, const double* __restrict__ piHsrc,
                         double* __restrict__ piout) {
  __shared__ double hbuf[4][256];
  __shared__ float wgb[1792];
  int t = threadIdx.x;
  int wv = t >> 6, lane = t & 63;
  int idx = blockIdx.x * 4 + wv;
  int inb = flag[idx];
  if (inb) {
    const double* hp = H2 + (size_t)idx * DD;
#pragma unroll
    for (int j = 0; j < 4; ++j) hbuf[wv][lane + j * 64] = hp[lane + j * 64];
  }
  for (int i = t; i < 1792; i += 256) wgb[i] = Wg[i];
  __syncthreads();
  if (!inb) {
    if (lane < FF) piout[(size_t)idx * FF + lane] = piHsrc[(size_t)idx * FF + lane];
    return;
  }
  if (lane == 0) {
    double gb[FF];
    for (int f = 0; f < FF; ++f) {
      double a = 0.0;
      for (int d = 0; d < DD; ++d) a += hbuf[wv][d] * (double)wgb[d * FF + f];
      gb[f] = a;
    }
    double m1 = -INFINITY, m2 = -INFINITY;
    for (int f = 0; f < FF; ++f) {
      if (gb[f] > m1) { m2 = m1; m1 = gb[f]; }
      else if (gb[f] > m2) { m2 = gb[f]; }
    }
    double e[FF], s = 0.0;
    for (int f = 0; f < FF; ++f) {
      e[f] = (gb[f] >= m2) ? exp(gb[f] - m1) : 0.0;
      s += e[f];
    }
    for (int f = 0; f < FF; ++f) piout[(size_t)idx * FF + f] = e[f] / s;
  }
}

__global__ void n_bc(const double* __restrict__ H2, const double* __restrict__ pi,
                     const float* __restrict__ e_fac, const float* __restrict__ boost_p,
                     double* __restrict__ Bc) {
  int rb = blockIdx.x, t = threadIdx.x;
  double ef = 0.0;
  for (int f = 0; f < FF; ++f) ef += pi[(size_t)rb * FF + f] * (double)e_fac[f * DD + t];
  double boost = (double)(*boost_p);
  Bc[(size_t)rb * DD + t] = H2[(size_t)rb * DD + t] * ef * boost;
}

__global__ void n_bc_sel(const double* __restrict__ H2, const double* __restrict__ pi,
                         const float* __restrict__ e_fac, const float* __restrict__ boost_p,
                         const int* __restrict__ flag, const double* __restrict__ BcH,
                         double* __restrict__ Bc2) {
  int rb = blockIdx.x, t = threadIdx.x;
  size_t i = (size_t)rb * DD + t;
  if (!flag[rb]) { Bc2[i] = BcH[i]; return; }
  double ef = 0.0;
  for (int f = 0; f < FF; ++f) ef += pi[(size_t)rb * FF + f] * (double)e_fac[f * DD + t];
  double boost = (double)(*boost_p);
  Bc2[i] = H2[i] * ef * boost;
}

// =================== f32 logp-path kernels ===================

__global__ void k_z2(const float* __restrict__ motor, const float* __restrict__ Wf,
                     const int* __restrict__ sel, float* __restrict__ z2) {
  int vc = blockIdx.x, f = blockIdx.y;
  int t = threadIdx.x;
  int vg = t & 31, bg = t >> 5;
  __shared__ float mt[32][65];
  __shared__ float wt[32][256];
  __shared__ int selL[128];
  if (t < 128) selL[t] = sel[t];
  float acc[8][8];
#pragma unroll
  for (int i = 0; i < 8; ++i)
#pragma unroll
    for (int j = 0; j < 8; ++j) acc[i][j] = 0.f;
  const float* wf = Wf + (size_t)f * DD * VV;
  for (int dt = 0; dt < 8; ++dt) {
    for (int i = t; i < 2048; i += 256) {
      int d = i & 31, b = i >> 5;
      mt[d][b] = motor[b * DD + dt * 32 + d];
    }
    for (int i = t; i < 8192; i += 256) {
      int d = i >> 8, v = i & 255;
      wt[d][v] = wf[(size_t)(dt * 32 + d) * VV + vc * 256 + v];
    }
    __syncthreads();
    for (int d = 0; d < 32; ++d) {
      float bv[8], wv[8];
#pragma unroll
      for (int i = 0; i < 8; ++i) bv[i] = mt[d][bg * 8 + i];
#pragma unroll
      for (int j = 0; j < 8; ++j) wv[j] = wt[d][vg + j * 32];
#pragma unroll
      for (int i = 0; i < 8; ++i)
#pragma unroll
        for (int j = 0; j < 8; ++j) acc[i][j] += bv[i] * wv[j];
    }
    __syncthreads();
  }
#pragma unroll
  for (int i = 0; i < 8; ++i) {
    int b = bg * 8 + i;
    int s0 = selL[b * 2 + 0], s1 = selL[b * 2 + 1];
    if (s0 == f) {
#pragma unroll
      for (int j = 0; j < 8; ++j)
        z2[((size_t)(b * 2 + 0)) * VV + vc * 256 + vg + j * 32] = acc[i][j];
    }
    if (s1 == f) {
#pragma unroll
      for (int j = 0; j < 8; ++j)
        z2[((size_t)(b * 2 + 1)) * VV + vc * 256 + vg + j * 32] = acc[i][j];
    }
  }
}

__global__ void k_lse(const float* __restrict__ z2, float* __restrict__ lse) {
  int row = blockIdx.x;
  int t = threadIdx.x;
  const float* zp = z2 + (size_t)row * VV;
  float m = -INFINITY, s = 0.f;
  for (int v = t; v < VV; v += 256) {
    float val = zp[v];
    if (val > m) { s = s * expf(m - val) + 1.f; m = val; }
    else s += expf(val - m);
  }
  __shared__ float sm[256], ss[256];
  sm[t] = m; ss[t] = s;
  __syncthreads();
  for (int off = 128; off > 0; off >>= 1) {
    if (t < off) {
      float m2 = sm[t + off], s2 = ss[t + off], m1 = sm[t], s1 = ss[t];
      float M = fmaxf(m1, m2);
      sm[t] = M;
      ss[t] = s1 * expf(m1 - M) + s2 * expf(m2 - M);
    }
    __syncthreads();
  }
  if (t == 0) lse[row] = sm[0] + logf(ss[0]);
}

__global__ void k_logp(const float* __restrict__ z2, const float* __restrict__ c2,
                       const float* __restrict__ lse, float* __restrict__ out_logp) {
  int b = blockIdx.y;
  int v = blockIdx.x * 256 + threadIdx.x;
  float a0 = c2[b * 2 + 0] - lse[b * 2 + 0] + z2[((size_t)(b * 2 + 0)) * VV + v];
  float a1 = c2[b * 2 + 1] - lse[b * 2 + 1] + z2[((size_t)(b * 2 + 1)) * VV + v];
  float M = fmaxf(a0, a1);
  out_logp[(size_t)b * VV + v] = M + logf(expf(a0 - M) + expf(a1 - M));
}

__global__ void k_loss(const float* __restrict__ out_logp, const int* __restrict__ targets,
                       float* __restrict__ out_loss, float* __restrict__ boost) {
  int b = threadIdx.x;
  float v = out_logp[(size_t)b * VV + targets[b]];
#pragma unroll
  for (int off = 32; off > 0; off >>= 1) v += __shfl_xor(v, off, 64);
  if (b == 0) {
    float loss = -v / 64.f;
    *out_loss = loss;
    *boost = 1.f + 2.f * ((loss > 0.7f) ? 1.f : 0.f);
  }
}

// =================== launch ===================
extern "C" void kernel_launch(void* const* d_in, const int* in_sizes, int n_in,
                              void* d_out, int out_size, void* d_ws, size_t ws_size,
                              hipStream_t stream) {
  const float* x       = (const float*)d_in[0];
  const int*   targets = (const int*)d_in[1];
  const int*   nidx    = (const int*)d_in[2];
  const float* W1      = (const float*)d_in[3];
  const float* b1      = (const float*)d_in[4];
  const float* W2      = (const float*)d_in[5];
  const float* b2      = (const float*)d_in[6];
  const float* w_gate  = (const float*)d_in[7];
  const float* Wr      = (const float*)d_in[8];
  const float* Wm      = (const float*)d_in[9];
  const float* bm      = (const float*)d_in[10];
  const float* Wg      = (const float*)d_in[11];
  const float* Wf      = (const float*)d_in[12];
  const float* e_fac   = (const float*)d_in[13];
  const float* Wb      = (const float*)d_in[14];

  float* out_logp = (float*)d_out;
  float* out_loss = out_logp + (size_t)BB * VV;
  float* out_msg  = out_loss + 1;

  double* dH   = (double*)d_ws;               // 1048576 d each
  double* dHs  = dH + 1048576;
  double* dHsM = dHs + 1048576;
  double* dH2  = dHsM + 1048576;
  double* dH2b = dH2 + 1048576;
  double* dBc  = dH2b + 1048576;
  double* dBcA = dBc + 1048576;
  double* dHid = dBcA + 1048576;              // 4194304 d region (hid; overlaid later)
  float*  fZ2  = (float*)dHid;                //   z2: doubles [0 .. 2048000)
  double* dScg = dHid + 4194304;              // 4096
  double* dW6h = dScg + 4096;                 // 24576 each
  double* dW6a = dW6h + 24576;
  double* dW6b = dW6a + 24576;
  double* dW2h = dW6b + 24576;
  double* dW2a = dW2h + 24576;
  double* dW2b = dW2a + 24576;
  double* dPiH = dW2b + 24576;                // 28672 each
  double* dPiA = dPiH + 28672;
  double* dPiH2= dPiA + 28672;
  double* dMotD= dPiH2 + 28672;               // 16384
  float*  fMaskH = (float*)(dMotD + 16384);   // 4096
  float*  fMaskA = fMaskH + 4096;             // 4096
  float*  fMsgH  = fMaskA + 4096;             // 1048576 f
  float*  fCorr  = fMsgH + 1048576;           // 1048576 f
  float*  fMotF  = fCorr + 1048576;           // 16384
  float*  fC2    = fMotF + 16384;             // 128
  float*  fLse   = fC2 + 128;                 // 128
  float*  fBoost = fLse + 128;                // 1
  int*    iSel   = (int*)(fBoost + 1);        // 128
  int*    fW1    = iSel + 128;                // 4096 each
  int*    fW2    = fW1 + 4096;
  int*    fPi    = fW2 + 4096;
  int*    fM     = fPi + 4096;
  int*    cPi    = fM + 4096;
  int*    cW1    = cPi + 4096;
  int*    cM     = cW1 + 4096;
  int*    cM2    = cM + 4096;

  // ---- trunk ----
  t_hid<<<dim3(16, 64), 256, 0, stream>>>(x, W1, b1, dHid);
  t_H<<<dim3(8, 2, 64), 256, 0, stream>>>(dHid, W2, b2, dH);
  n_scg<<<1024, 256, 0, stream>>>(dH, w_gate, dScg);
  n_mask_dual<<<1, 64, 0, stream>>>(dScg, fMaskH, fMaskA, fM);
  n_hs<<<4096, 256, 0, stream>>>(dH, fMaskH, dHs);
  n_w6x<<<4096, 64, 0, stream>>>(dHs, dHs, nidx, dW6h, dW6a, fW1);
  f_mp_mm<<<4096, 256, 0, stream>>>(dW6h, dHs, nidx, Wr, dHs, dH2);
  // ---- logp path ----
  n_motor<<<64, 256, 0, stream>>>(dH2, Wm, bm, dMotD, fMotF);
  n_gate<<<64, 64, 0, stream>>>(dMotD, Wg, iSel, fC2);
  k_z2<<<dim3(125, 7), 256, 0, stream>>>(fMotF, Wf, iSel, fZ2);
  k_lse<<<128, 256, 0, stream>>>(fZ2, fLse);
  k_logp<<<dim3(125, BB), 256, 0, stream>>>(fZ2, fC2, fLse, out_logp);
  k_loss<<<1, 64, 0, stream>>>(out_logp, targets, out_loss, fBoost);
  // ---- pass-2 hard -> msg_h ----
  n_pi_dual<<<1024, 256, 0, stream>>>(dH2, Wg, dPiH, dPiA, fPi);
  n_bc<<<4096, 256, 0, stream>>>(dH2, dPiH, e_fac, fBoost, dBc);
  n_w6x<<<4096, 64, 0, stream>>>(dH2, dBc, nidx, dW2h, dW2a, fW2);
  f_mp_msg<<<4096, 256, 0, stream>>>(dW2h, dBc, nidx, Wb, fMsgH);
  n_zero<<<4096, 256, 0, stream>>>(fCorr);
  // ---- BR_W2 (sparse) ----
  f_mp_corr<<<4096, 256, 0, stream>>>(dW2a, dBc, nidx, fW2, Wb, fMsgH, fCorr);
  // ---- BR_PI (sparse) ----
  n_bc_sel<<<4096, 256, 0, stream>>>(dH2, dPiA, e_fac, fBoost, fPi, dBc, dBcA);
  n_close<<<16, 256, 0, stream>>>(fPi, nidx, cPi);
  n_w6_sel<<<4096, 64, 0, stream>>>(dH2, dBcA, nidx, cPi, dW2h, dW2b);
  f_mp_corr<<<4096, 256, 0, stream>>>(dW2b, dBcA, nidx, cPi, Wb, fMsgH, fCorr);
  // ---- BR_W1 (sparse) ----
  f_mp_h2sel<<<4096, 256, 0, stream>>>(dW6a, dHs, nidx, fW1, Wr, dHs, dH2, dH2b);
  n_pi_sel<<<1024, 256, 0, stream>>>(dH2b, Wg, fW1, dPiH, dPiH2);
  n_bc_sel<<<4096, 256, 0, stream>>>(dH2b, dPiH2, e_fac, fBoost, fW1, dBc, dBcA);
  n_close<<<16, 256, 0, stream>>>(fW1, nidx, cW1);
  n_w6_sel<<<4096, 64, 0, stream>>>(dH2b, dBcA, nidx, cW1, dW2h, dW2b);
  f_mp_corr<<<4096, 256, 0, stream>>>(dW2b, dBcA, nidx, cW1, Wb, fMsgH, fCorr);
  // ---- BR_M (sparse) ----
  n_hs_sel<<<4096, 256, 0, stream>>>(dH, fMaskA, fM, dHs, dHsM);
  n_close<<<16, 256, 0, stream>>>(fM, nidx, cM);
  n_w6_sel<<<4096, 64, 0, stream>>>(dHsM, dHsM, nidx, cM, dW6h, dW6b);
  f_mp_h2sel<<<4096, 256, 0, stream>>>(dW6b, dHsM, nidx, cM, Wr, dHsM, dH2, dH2b);
  n_pi_sel<<<1024, 256, 0, stream>>>(dH2b, Wg, cM, dPiH, dPiH2);
  n_bc_sel<<<4096, 256, 0, stream>>>(dH2b, dPiH2, e_fac, fBoost, cM, dBc, dBcA);
  n_close<<<16, 256, 0, stream>>>(cM, nidx, cM2);
  n_w6_sel<<<4096, 64, 0, stream>>>(dH2b, dBcA, nidx, cM2, dW2h, dW2b);
  f_mp_corr<<<4096, 256, 0, stream>>>(dW2b, dBcA, nidx, cM2, Wb, fMsgH, fCorr);
  // ---- final ----
  n_final<<<4096, 256, 0, stream>>>(fMsgH, fCorr, out_msg);
}

// Round 20
// 913.566 us; speedup vs baseline: 3.2114x; 1.0281x over previous
//
#include <hip/hip_runtime.h>

#define RR 64
#define BB 64
#define DD 256
#define DFF_ 1024
#define VV 32000
#define FF 7

#define TIE_BAND(a, b) (2e-6 * (1.0 + 0.5 * (fabs(a) + fabs(b))))
#define BR_CLAMP 0.30f
#define TOT_CLAMP 0.19f

__device__ __forceinline__ float clampf(float x, float c) {
  return fminf(fmaxf(x, -c), c);
}

// =================== tiled trunk kernels (register-blocked, order-identical) ===================

// hid = gelu(x@W1+b1); grid (16,64), 256 thr; tile 64b x 64f; thread 4b x 4f
__global__ void t_hid(const float* __restrict__ x, const float* __restrict__ W1,
                      const float* __restrict__ b1, double* __restrict__ hid) {
  int fc = blockIdx.x, r = blockIdx.y;
  int t = threadIdx.x;
  int fg = t & 15, bg = t >> 4;
  __shared__ float xs[64][65];
  __shared__ float w1t[64][64];
  double acc[4][4];
#pragma unroll
  for (int i = 0; i < 4; ++i)
#pragma unroll
    for (int j = 0; j < 4; ++j) acc[i][j] = 0.0;
  const float* xr = x + (size_t)r * BB * DD;
  const float* w1r = W1 + (size_t)r * DD * DFF_;
  for (int dt = 0; dt < 4; ++dt) {
    for (int i = t; i < 4096; i += 256) {
      int d = i & 63, b = i >> 6;
      xs[d][b] = xr[b * DD + dt * 64 + d];
    }
    for (int i = t; i < 4096; i += 256) {
      int dd = i >> 6, ff = i & 63;
      w1t[dd][ff] = w1r[(size_t)(dt * 64 + dd) * DFF_ + fc * 64 + ff];
    }
    __syncthreads();
    for (int d = 0; d < 64; ++d) {
      double bv[4], wv[4];
#pragma unroll
      for (int i = 0; i < 4; ++i) bv[i] = (double)xs[d][bg * 4 + i];
#pragma unroll
      for (int j = 0; j < 4; ++j) wv[j] = (double)w1t[d][fg * 4 + j];
#pragma unroll
      for (int i = 0; i < 4; ++i)
#pragma unroll
        for (int j = 0; j < 4; ++j) acc[i][j] += bv[i] * wv[j];
    }
    __syncthreads();
  }
#pragma unroll
  for (int i = 0; i < 4; ++i) {
    int b = bg * 4 + i;
#pragma unroll
    for (int j = 0; j < 4; ++j) {
      int f = fc * 64 + fg * 4 + j;
      double v = acc[i][j] + (double)b1[r * DFF_ + f];
      hid[((size_t)(r * BB + b)) * DFF_ + f] =
          0.5 * v * (1.0 + erf(v * 0.70710678118654752440));
    }
  }
}

// H = h + CTAU*h; grid (8,2,64), 256 thr; tile 32b x 32d
__global__ void t_H(const double* __restrict__ hid, const float* __restrict__ W2,
                    const float* __restrict__ b2, double* __restrict__ H) {
  int dc = blockIdx.x, bc = blockIdx.y, r = blockIdx.z;
  int t = threadIdx.x;
  int dg = t & 15, bg = t >> 4;
  __shared__ double ht[64][33];
  __shared__ float wt[64][32];
  double acc[2][2];
#pragma unroll
  for (int i = 0; i < 2; ++i)
#pragma unroll
    for (int j = 0; j < 2; ++j) acc[i][j] = 0.0;
  const double* hr = hid + (size_t)r * BB * DFF_;
  const float* w2r = W2 + (size_t)r * DFF_ * DD;
  for (int ft = 0; ft < 16; ++ft) {
    for (int i = t; i < 2048; i += 256) {
      int f = i & 63, b = i >> 6;
      ht[f][b] = hr[(size_t)(bc * 32 + b) * DFF_ + ft * 64 + f];
    }
    for (int i = t; i < 2048; i += 256) {
      int f = i >> 5, d = i & 31;
      wt[f][d] = w2r[(size_t)(ft * 64 + f) * DD + dc * 32 + d];
    }
    __syncthreads();
    for (int f = 0; f < 64; ++f) {
      double hb[2], wv[2];
#pragma unroll
      for (int i = 0; i < 2; ++i) hb[i] = ht[f][bg * 2 + i];
#pragma unroll
      for (int j = 0; j < 2; ++j) wv[j] = (double)wt[f][dg * 2 + j];
#pragma unroll
      for (int i = 0; i < 2; ++i)
#pragma unroll
        for (int j = 0; j < 2; ++j) acc[i][j] += hb[i] * wv[j];
    }
    __syncthreads();
  }
#pragma unroll
  for (int i = 0; i < 2; ++i) {
    int b = bc * 32 + bg * 2 + i;
#pragma unroll
    for (int j = 0; j < 2; ++j) {
      int d = dc * 32 + dg * 2 + j;
      double h = acc[i][j] + (double)b2[r * DD + d];
      H[((size_t)(r * BB + b)) * DD + d] = h + 0.20333333 * h;
    }
  }
}

// =================== staged gate kernels (lane-0 serial, bitwise-frozen order) ===================

__global__ void n_scg(const double* __restrict__ H, const float* __restrict__ wg,
                      double* __restrict__ scg) {
  __shared__ double hbuf[4][256];
  __shared__ float wgs[256];
  int t = threadIdx.x;
  int wv = t >> 6, lane = t & 63;
  int idx = blockIdx.x * 4 + wv;
  int r = idx >> 6, b = idx & 63;
  const double* hp = H + (size_t)idx * DD;
  wgs[t] = wg[t];
#pragma unroll
  for (int j = 0; j < 4; ++j) hbuf[wv][lane + j * 64] = hp[lane + j * 64];
  __syncthreads();
  if (lane == 0) {
    double a = 0.0;
    for (int d = 0; d < DD; ++d) a += hbuf[wv][d] * (double)wgs[d];
    scg[b * RR + r] = a;
  }
}

__global__ void n_mask_dual(const double* __restrict__ scg, float* __restrict__ maskH,
                            float* __restrict__ maskA, int* __restrict__ flagM) {
  int b = threadIdx.x;
  double v[64], w[64];
  for (int r = 0; r < RR; ++r) { v[r] = scg[b * RR + r]; w[r] = v[r]; }
  double k6 = 0.0, k7 = 0.0;
  int i6 = -1, i7 = -1;
  for (int it = 0; it < 7; ++it) {
    int mi = 0;
    for (int r = 1; r < RR; ++r) if (w[r] > w[mi]) mi = r;
    if (it == 5) { k6 = w[mi]; i6 = mi; }
    if (it == 6) { k7 = w[mi]; i7 = mi; }
    w[mi] = -INFINITY;
  }
  double gap = k6 - k7;
  int tie = (gap > 0.0 && gap < TIE_BAND(k6, k7)) ? 1 : 0;
  for (int r = 0; r < RR; ++r) {
    float mh = (v[r] >= k6 || r == 0 || r == RR - 1) ? 1.f : 0.f;
    maskH[b * RR + r] = mh;
    maskA[b * RR + r] = tie ? ((v[r] >= k7 || r == 0 || r == RR - 1) ? 1.f : 0.f) : mh;
    flagM[r * BB + b] = 0;
  }
  if (tie) {
    flagM[i6 * BB + b] = 1;
    flagM[i7 * BB + b] = 1;
  }
}

__global__ void n_hs(const double* __restrict__ H, const float* __restrict__ mask,
                     double* __restrict__ Hs) {
  int idx = blockIdx.x * 256 + threadIdx.x;
  int r = idx >> 14;
  int b = (idx >> 8) & 63;
  Hs[idx] = H[idx] * (double)mask[b * RR + r];
}

// Hs dirty-only ; 4096 blocks x 256
__global__ void n_hs_g(const double* __restrict__ H, const float* __restrict__ maskA,
                       const int* __restrict__ gate, double* __restrict__ HsM) {
  int rb = blockIdx.x;
  if (!gate[rb]) return;
  int t = threadIdx.x;
  size_t i = (size_t)rb * DD + t;
  int r = rb >> 6, b = rb & 63;
  HsM[i] = H[i] * (double)maskA[b * RR + r];
}

// top-4 gated softmax: block-per-site, staged, lane-0 serial ; 4096 blocks x 64
__global__ void n_w6x(const double* __restrict__ self, const double* __restrict__ nb,
                      const int* __restrict__ nidx, double* __restrict__ wout,
                      double* __restrict__ walt, int* __restrict__ flag) {
  __shared__ double sbuf[256];
  __shared__ double qbuf[6][256];
  int idx = blockIdx.x;
  int r = idx >> 6, b = idx & 63;
  int lane = threadIdx.x;
  const double* sp = self + (size_t)idx * DD;
#pragma unroll
  for (int j = 0; j < 4; ++j) sbuf[lane + j * 64] = sp[lane + j * 64];
  for (int k = 0; k < 6; ++k) {
    int nr = nidx[r * 6 + k];
    const double* qp = nb + ((size_t)(nr * BB + b)) * DD;
#pragma unroll
    for (int j = 0; j < 4; ++j) qbuf[k][lane + j * 64] = qp[lane + j * 64];
  }
  __syncthreads();
  if (lane == 0) {
    double sc[6];
    for (int k = 0; k < 6; ++k) {
      double a = 0.0;
      for (int d = 0; d < DD; ++d) a += sbuf[d] * qbuf[k][d];
      sc[k] = a * 0.0625;
    }
    double srt[6];
    for (int k = 0; k < 6; ++k) srt[k] = sc[k];
    for (int i = 0; i < 5; ++i) {
      int mi = i;
      for (int j = i + 1; j < 6; ++j) if (srt[j] > srt[mi]) mi = j;
      double tmp = srt[i]; srt[i] = srt[mi]; srt[mi] = tmp;
    }
    double s4 = srt[3], s5 = srt[4], mx = srt[0];
    double e[6], s = 0.0;
    for (int k = 0; k < 6; ++k) {
      e[k] = (sc[k] >= s4) ? exp(sc[k] - mx) : 0.0;
      s += e[k];
    }
    for (int k = 0; k < 6; ++k) wout[(size_t)idx * 6 + k] = e[k] / s;
    double gap = s4 - s5;
    int inband = (gap > 0.0 && gap < TIE_BAND(s4, s5)) ? 1 : 0;
    flag[idx] = inband;
    if (inband) {
      double ea[6], sa = 0.0;
      for (int k = 0; k < 6; ++k) {
        ea[k] = (sc[k] >= s5) ? exp(sc[k] - mx) : 0.0;   // inclusive keep-5
        sa += ea[k];
      }
      for (int k = 0; k < 6; ++k) walt[(size_t)idx * 6 + k] = ea[k] / sa;
    } else {
      for (int k = 0; k < 6; ++k) walt[(size_t)idx * 6 + k] = e[k] / s;
    }
  }
}

// dual-source recompute-or-copy hard top-4 softmax ; 4096 blocks x 64
__global__ void n_w6_sel_g(const double* __restrict__ selfD, const double* __restrict__ selfC,
                           const int* __restrict__ flagS,
                           const double* __restrict__ nbD, const double* __restrict__ nbC,
                           const int* __restrict__ flagN,
                           const int* __restrict__ nidx, const int* __restrict__ gate,
                           const double* __restrict__ wH, double* __restrict__ wout) {
  __shared__ double sbuf[256];
  __shared__ double qbuf[6][256];
  int idx = blockIdx.x;
  int r = idx >> 6, b = idx & 63;
  int lane = threadIdx.x;
  int g = gate[idx];
  if (g) {
    const double* sp = (flagS[idx] ? selfD : selfC) + (size_t)idx * DD;
#pragma unroll
    for (int j = 0; j < 4; ++j) sbuf[lane + j * 64] = sp[lane + j * 64];
    for (int k = 0; k < 6; ++k) {
      int nr = nidx[r * 6 + k];
      int ni = nr * BB + b;
      const double* qp = (flagN[ni] ? nbD : nbC) + (size_t)ni * DD;
#pragma unroll
      for (int j = 0; j < 4; ++j) qbuf[k][lane + j * 64] = qp[lane + j * 64];
    }
  }
  __syncthreads();
  if (!g) {
    if (lane < 6) wout[(size_t)idx * 6 + lane] = wH[(size_t)idx * 6 + lane];
    return;
  }
  if (lane == 0) {
    double sc[6];
    for (int k = 0; k < 6; ++k) {
      double a = 0.0;
      for (int d = 0; d < DD; ++d) a += sbuf[d] * qbuf[k][d];
      sc[k] = a * 0.0625;
    }
    double srt[6];
    for (int k = 0; k < 6; ++k) srt[k] = sc[k];
    for (int i = 0; i < 4; ++i) {
      int mi = i;
      for (int j = i + 1; j < 6; ++j) if (srt[j] > srt[mi]) mi = j;
      double tmp = srt[i]; srt[i] = srt[mi]; srt[mi] = tmp;
    }
    double s4 = srt[3], mx = srt[0];
    double e[6], s = 0.0;
    for (int k = 0; k < 6; ++k) {
      e[k] = (sc[k] >= s4) ? exp(sc[k] - mx) : 0.0;
      s += e[k];
    }
    for (int k = 0; k < 6; ++k) wout[(size_t)idx * 6 + k] = e[k] / s;
  }
}

// =================== fused mp -> consumer kernels ===================

// H2 = Hs + (mp @ Wmat) ; full ; 4096 blocks x 256
__global__ void f_mp_mm(const double* __restrict__ w, const double* __restrict__ nb,
                        const int* __restrict__ nidx, const float* __restrict__ Wmat,
                        const double* __restrict__ Hs, double* __restrict__ H2) {
  __shared__ double mpL[256];
  int rb = blockIdx.x;
  int r = rb >> 6, b = rb & 63;
  int t = threadIdx.x;
  double a = 0.0;
  for (int k = 0; k < 6; ++k) {
    int nr = nidx[r * 6 + k];
    a += w[(size_t)rb * 6 + k] * nb[((size_t)(nr * BB + b)) * DD + t];
  }
  mpL[t] = a;
  __syncthreads();
  double s2 = 0.0;
  for (int d = 0; d < DD; ++d) s2 += mpL[d] * (double)Wmat[d * DD + t];
  size_t i = (size_t)rb * DD + t;
  H2[i] = Hs[i] + s2;
}

// msgH = f32(mp @ Wmat) ; full ; 4096 blocks x 256
__global__ void f_mp_msg(const double* __restrict__ w, const double* __restrict__ nb,
                         const int* __restrict__ nidx, const float* __restrict__ Wmat,
                         float* __restrict__ msgH) {
  __shared__ double mpL[256];
  int rb = blockIdx.x;
  int r = rb >> 6, b = rb & 63;
  int t = threadIdx.x;
  double a = 0.0;
  for (int k = 0; k < 6; ++k) {
    int nr = nidx[r * 6 + k];
    a += w[(size_t)rb * 6 + k] * nb[((size_t)(nr * BB + b)) * DD + t];
  }
  mpL[t] = a;
  __syncthreads();
  double s2 = 0.0;
  for (int d = 0; d < DD; ++d) s2 += mpL[d] * (double)Wmat[d * DD + t];
  msgH[(size_t)rb * DD + t] = (float)s2;
}

// corr += clamp(...) gated, dual-source nb ; 4096 blocks x 256
__global__ void f_mp_corr_g(const double* __restrict__ w,
                            const double* __restrict__ nbD, const double* __restrict__ nbC,
                            const int* __restrict__ flagN,
                            const int* __restrict__ nidx, const int* __restrict__ gate,
                            const float* __restrict__ Wmat, const float* __restrict__ msgH,
                            float* __restrict__ corr) {
  int rb = blockIdx.x;
  if (!gate[rb]) return;
  __shared__ double mpL[256];
  int r = rb >> 6, b = rb & 63;
  int t = threadIdx.x;
  double a = 0.0;
  for (int k = 0; k < 6; ++k) {
    int nr = nidx[r * 6 + k];
    int ni = nr * BB + b;
    const double* q = flagN[ni] ? nbD : nbC;
    a += w[(size_t)rb * 6 + k] * q[(size_t)ni * DD + t];
  }
  mpL[t] = a;
  __syncthreads();
  double s2 = 0.0;
  for (int d = 0; d < DD; ++d) s2 += mpL[d] * (double)Wmat[d * DD + t];
  size_t i = (size_t)rb * DD + t;
  corr[i] += clampf((float)s2 - msgH[i], BR_CLAMP);
}

// H2 dirty-only, dual-source nb & Hs ; 4096 blocks x 256
__global__ void f_mp_h2_g(const double* __restrict__ w,
                          const double* __restrict__ nbD, const double* __restrict__ nbC,
                          const int* __restrict__ flagN,
                          const int* __restrict__ nidx, const float* __restrict__ Wmat,
                          const double* __restrict__ HsD, const double* __restrict__ HsC,
                          const int* __restrict__ flagHs,
                          const int* __restrict__ gate, double* __restrict__ H2out) {
  int rb = blockIdx.x;
  if (!gate[rb]) return;
  __shared__ double mpL[256];
  int r = rb >> 6, b = rb & 63;
  int t = threadIdx.x;
  double a = 0.0;
  for (int k = 0; k < 6; ++k) {
    int nr = nidx[r * 6 + k];
    int ni = nr * BB + b;
    const double* q = flagN[ni] ? nbD : nbC;
    a += w[(size_t)rb * 6 + k] * q[(size_t)ni * DD + t];
  }
  mpL[t] = a;
  __syncthreads();
  double s2 = 0.0;
  for (int d = 0; d < DD; ++d) s2 += mpL[d] * (double)Wmat[d * DD + t];
  size_t i = (size_t)rb * DD + t;
  const double* hs = flagHs[rb] ? HsD : HsC;
  H2out[i] = hs[i] + s2;
}

// =================== misc kernels ===================

__global__ void n_zero(float* __restrict__ p) {
  p[blockIdx.x * 256 + threadIdx.x] = 0.f;
}

__global__ void n_izero(int* __restrict__ p) {
  p[blockIdx.x * 256 + threadIdx.x] = 0;
}

__global__ void n_final(const float* __restrict__ msgH, const float* __restrict__ corr,
                        float* __restrict__ out) {
  int i = blockIdx.x * 256 + threadIdx.x;
  out[i] = msgH[i] + clampf(corr[i], TOT_CLAMP);
}

__global__ void n_close(const int* __restrict__ in, const int* __restrict__ nidx,
                        int* __restrict__ out) {
  int idx = blockIdx.x * 256 + threadIdx.x;
  int r = idx >> 6, b = idx & 63;
  int v = in[idx];
  for (int k = 0; k < 6; ++k) v |= in[nidx[r * 6 + k] * BB + b];
  out[idx] = v;
}

__global__ void n_motor(const double* __restrict__ H2, const float* __restrict__ Wm,
                        const float* __restrict__ bm, double* __restrict__ motD,
                        float* __restrict__ motF) {
  int b = blockIdx.x, t = threadIdx.x;
  const double* hp = H2 + ((size_t)((RR - 1) * BB + b)) * DD;
  double a = 0.0;
  for (int d = 0; d < DD; ++d) a += hp[d] * (double)Wm[d * DD + t];
  double mo = a + (double)bm[t];
  motD[b * DD + t] = mo;
  motF[b * DD + t] = (float)mo;
}

__global__ void n_gate(const double* __restrict__ motD, const float* __restrict__ Wg,
                       int* __restrict__ sel, float* __restrict__ c2) {
  __shared__ double mbuf[256];
  __shared__ float wgb[1792];
  int b = blockIdx.x;
  int lane = threadIdx.x;
#pragma unroll
  for (int j = 0; j < 4; ++j) mbuf[lane + j * 64] = motD[b * DD + lane + j * 64];
  for (int i = lane; i < 1792; i += 64) wgb[i] = Wg[i];
  __syncthreads();
  if (lane == 0) {
    double g[FF];
    for (int f = 0; f < FF; ++f) {
      double a = 0.0;
      for (int d = 0; d < DD; ++d) a += mbuf[d] * (double)wgb[d * FF + f];
      g[f] = a;
    }
    double m1 = -INFINITY, m2 = -INFINITY;
    int i1 = -1, i2 = -1;
    for (int f = 0; f < FF; ++f) {
      if (g[f] > m1) { m2 = m1; i2 = i1; m1 = g[f]; i1 = f; }
      else if (g[f] > m2) { m2 = g[f]; i2 = f; }
    }
    double s = 0.0;
    for (int f = 0; f < FF; ++f)
      if (g[f] >= m2) s += exp(g[f] - m1);
    double lse = m1 + log(s);
    sel[b * 2 + 0] = i1;
    sel[b * 2 + 1] = i2;
    c2[b * 2 + 0] = (float)(g[i1] - lse);
    c2[b * 2 + 1] = (float)(g[i2] - lse);
  }
}

// pi hard + inclusive alt + flag: wave-per-site staged ; 1024 blocks x 256
__global__ void n_pi_dual(const double* __restrict__ H2, const float* __restrict__ Wg,
                          double* __restrict__ piH, double* __restrict__ piA,
                          int* __restrict__ flag) {
  __shared__ double hbuf[4][256];
  __shared__ float wgb[1792];
  int t = threadIdx.x;
  int wv = t >> 6, lane = t & 63;
  int idx = blockIdx.x * 4 + wv;
  const double* hp = H2 + (size_t)idx * DD;
#pragma unroll
  for (int j = 0; j < 4; ++j) hbuf[wv][lane + j * 64] = hp[lane + j * 64];
  for (int i = t; i < 1792; i += 256) wgb[i] = Wg[i];
  __syncthreads();
  if (lane == 0) {
    double gb[FF];
    for (int f = 0; f < FF; ++f) {
      double a = 0.0;
      for (int d = 0; d < DD; ++d) a += hbuf[wv][d] * (double)wgb[d * FF + f];
      gb[f] = a;
    }
    double srt[FF];
    for (int f = 0; f < FF; ++f) srt[f] = gb[f];
    for (int i = 0; i < 3; ++i) {
      int mi = i;
      for (int j = i + 1; j < FF; ++j) if (srt[j] > srt[mi]) mi = j;
      double tp = srt[i]; srt[i] = srt[mi]; srt[mi] = tp;
    }
    double m1 = srt[0], m2 = srt[1], m3 = srt[2];
    double e[FF], s = 0.0;
    for (int f = 0; f < FF; ++f) {
      e[f] = (gb[f] >= m2) ? exp(gb[f] - m1) : 0.0;
      s += e[f];
    }
    for (int f = 0; f < FF; ++f) piH[(size_t)idx * FF + f] = e[f] / s;
    double gap = m2 - m3;
    int inband = (gap > 0.0 && gap < TIE_BAND(m2, m3)) ? 1 : 0;
    flag[idx] = inband;
    if (inband) {
      double ea[FF], sa = 0.0;
      for (int f = 0; f < FF; ++f) {
        ea[f] = (gb[f] >= m3) ? exp(gb[f] - m1) : 0.0;   // inclusive keep-3
        sa += ea[f];
      }
      for (int f = 0; f < FF; ++f) piA[(size_t)idx * FF + f] = ea[f] / sa;
    } else {
      for (int f = 0; f < FF; ++f) piA[(size_t)idx * FF + f] = e[f] / s;
    }
  }
}

// recompute-or-copy hard pi: wave-per-site staged ; 1024 blocks x 256
__global__ void n_pi_sel(const double* __restrict__ H2src, const float* __restrict__ Wg,
                         const int* __restrict__ gate, const double* __restrict__ piHsrc,
                         double* __restrict__ piout) {
  __shared__ double hbuf[4][256];
  __shared__ float wgb[1792];
  int t = threadIdx.x;
  int wv = t >> 6, lane = t & 63;
  int idx = blockIdx.x * 4 + wv;
  int g = gate[idx];
  if (g) {
    const double* hp = H2src + (size_t)idx * DD;
#pragma unroll
    for (int j = 0; j < 4; ++j) hbuf[wv][lane + j * 64] = hp[lane + j * 64];
  }
  for (int i = t; i < 1792; i += 256) wgb[i] = Wg[i];
  __syncthreads();
  if (!g) {
    if (lane < FF) piout[(size_t)idx * FF + lane] = piHsrc[(size_t)idx * FF + lane];
    return;
  }
  if (lane == 0) {
    double gb[FF];
    for (int f = 0; f < FF; ++f) {
      double a = 0.0;
      for (int d = 0; d < DD; ++d) a += hbuf[wv][d] * (double)wgb[d * FF + f];
      gb[f] = a;
    }
    double m1 = -INFINITY, m2 = -INFINITY;
    for (int f = 0; f < FF; ++f) {
      if (gb[f] > m1) { m2 = m1; m1 = gb[f]; }
      else if (gb[f] > m2) { m2 = gb[f]; }
    }
    double e[FF], s = 0.0;
    for (int f = 0; f < FF; ++f) {
      e[f] = (gb[f] >= m2) ? exp(gb[f] - m1) : 0.0;
      s += e[f];
    }
    for (int f = 0; f < FF; ++f) piout[(size_t)idx * FF + f] = e[f] / s;
  }
}

__global__ void n_bc(const double* __restrict__ H2, const double* __restrict__ pi,
                     const float* __restrict__ e_fac, const float* __restrict__ boost_p,
                     double* __restrict__ Bc) {
  int rb = blockIdx.x, t = threadIdx.x;
  double ef = 0.0;
  for (int f = 0; f < FF; ++f) ef += pi[(size_t)rb * FF + f] * (double)e_fac[f * DD + t];
  double boost = (double)(*boost_p);
  Bc[(size_t)rb * DD + t] = H2[(size_t)rb * DD + t] * ef * boost;
}

// Bc dirty-only ; 4096 blocks x 256
__global__ void n_bc_g(const double* __restrict__ H2src, const double* __restrict__ pi,
                       const float* __restrict__ e_fac, const float* __restrict__ boost_p,
                       const int* __restrict__ gate, double* __restrict__ Bc2) {
  int rb = blockIdx.x;
  if (!gate[rb]) return;
  int t = threadIdx.x;
  size_t i = (size_t)rb * DD + t;
  double ef = 0.0;
  for (int f = 0; f < FF; ++f) ef += pi[(size_t)rb * FF + f] * (double)e_fac[f * DD + t];
  double boost = (double)(*boost_p);
  Bc2[i] = H2src[i] * ef * boost;
}

// =================== f32 logp-path kernels ===================

// z2: register-tiled 8b x 8v; dt=16/d=16 tiles (LDS 21KB); grid (125, 7), 256 thr
__global__ void k_z2(const float* __restrict__ motor, const float* __restrict__ Wf,
                     const int* __restrict__ sel, float* __restrict__ z2) {
  int vc = blockIdx.x, f = blockIdx.y;
  int t = threadIdx.x;
  int vg = t & 31, bg = t >> 5;
  __shared__ float mt[16][65];
  __shared__ float wt[16][256];
  __shared__ int selL[128];
  if (t < 128) selL[t] = sel[t];
  float acc[8][8];
#pragma unroll
  for (int i = 0; i < 8; ++i)
#pragma unroll
    for (int j = 0; j < 8; ++j) acc[i][j] = 0.f;
  const float* wf = Wf + (size_t)f * DD * VV;
  for (int dt = 0; dt < 16; ++dt) {
    for (int i = t; i < 1024; i += 256) {
      int d = i & 15, b = i >> 4;
      mt[d][b] = motor[b * DD + dt * 16 + d];
    }
    for (int i = t; i < 4096; i += 256) {
      int d = i >> 8, v = i & 255;
      wt[d][v] = wf[(size_t)(dt * 16 + d) * VV + vc * 256 + v];
    }
    __syncthreads();
    for (int d = 0; d < 16; ++d) {
      float bv[8], wv[8];
#pragma unroll
      for (int i = 0; i < 8; ++i) bv[i] = mt[d][bg * 8 + i];
#pragma unroll
      for (int j = 0; j < 8; ++j) wv[j] = wt[d][vg + j * 32];
#pragma unroll
      for (int i = 0; i < 8; ++i)
#pragma unroll
        for (int j = 0; j < 8; ++j) acc[i][j] += bv[i] * wv[j];
    }
    __syncthreads();
  }
#pragma unroll
  for (int i = 0; i < 8; ++i) {
    int b = bg * 8 + i;
    int s0 = selL[b * 2 + 0], s1 = selL[b * 2 + 1];
    if (s0 == f) {
#pragma unroll
      for (int j = 0; j < 8; ++j)
        z2[((size_t)(b * 2 + 0)) * VV + vc * 256 + vg + j * 32] = acc[i][j];
    }
    if (s1 == f) {
#pragma unroll
      for (int j = 0; j < 8; ++j)
        z2[((size_t)(b * 2 + 1)) * VV + vc * 256 + vg + j * 32] = acc[i][j];
    }
  }
}

__global__ void k_lse(const float* __restrict__ z2, float* __restrict__ lse) {
  int row = blockIdx.x;
  int t = threadIdx.x;
  const float* zp = z2 + (size_t)row * VV;
  float m = -INFINITY, s = 0.f;
  for (int v = t; v < VV; v += 256) {
    float val = zp[v];
    if (val > m) { s = s * expf(m - val) + 1.f; m = val; }
    else s += expf(val - m);
  }
  __shared__ float sm[256], ss[256];
  sm[t] = m; ss[t] = s;
  __syncthreads();
  for (int off = 128; off > 0; off >>= 1) {
    if (t < off) {
      float m2 = sm[t + off], s2 = ss[t + off], m1 = sm[t], s1 = ss[t];
      float M = fmaxf(m1, m2);
      sm[t] = M;
      ss[t] = s1 * expf(m1 - M) + s2 * expf(m2 - M);
    }
    __syncthreads();
  }
  if (t == 0) lse[row] = sm[0] + logf(ss[0]);
}

__global__ void k_logp(const float* __restrict__ z2, const float* __restrict__ c2,
                       const float* __restrict__ lse, float* __restrict__ out_logp) {
  int b = blockIdx.y;
  int v = blockIdx.x * 256 + threadIdx.x;
  float a0 = c2[b * 2 + 0] - lse[b * 2 + 0] + z2[((size_t)(b * 2 + 0)) * VV + v];
  float a1 = c2[b * 2 + 1] - lse[b * 2 + 1] + z2[((size_t)(b * 2 + 1)) * VV + v];
  float M = fmaxf(a0, a1);
  out_logp[(size_t)b * VV + v] = M + logf(expf(a0 - M) + expf(a1 - M));
}

__global__ void k_loss(const float* __restrict__ out_logp, const int* __restrict__ targets,
                       float* __restrict__ out_loss, float* __restrict__ boost) {
  int b = threadIdx.x;
  float v = out_logp[(size_t)b * VV + targets[b]];
#pragma unroll
  for (int off = 32; off > 0; off >>= 1) v += __shfl_xor(v, off, 64);
  if (b == 0) {
    float loss = -v / 64.f;
    *out_loss = loss;
    *boost = 1.f + 2.f * ((loss > 0.7f) ? 1.f : 0.f);
  }
}

// =================== launch ===================
extern "C" void kernel_launch(void* const* d_in, const int* in_sizes, int n_in,
                              void* d_out, int out_size, void* d_ws, size_t ws_size,
                              hipStream_t stream) {
  const float* x       = (const float*)d_in[0];
  const int*   targets = (const int*)d_in[1];
  const int*   nidx    = (const int*)d_in[2];
  const float* W1      = (const float*)d_in[3];
  const float* b1      = (const float*)d_in[4];
  const float* W2      = (const float*)d_in[5];
  const float* b2      = (const float*)d_in[6];
  const float* w_gate  = (const float*)d_in[7];
  const float* Wr      = (const float*)d_in[8];
  const float* Wm      = (const float*)d_in[9];
  const float* bm      = (const float*)d_in[10];
  const float* Wg      = (const float*)d_in[11];
  const float* Wf      = (const float*)d_in[12];
  const float* e_fac   = (const float*)d_in[13];
  const float* Wb      = (const float*)d_in[14];

  float* out_logp = (float*)d_out;
  float* out_loss = out_logp + (size_t)BB * VV;
  float* out_msg  = out_loss + 1;

  double* dH   = (double*)d_ws;               // 1048576 d each
  double* dHs  = dH + 1048576;
  double* dHsM = dHs + 1048576;
  double* dH2  = dHsM + 1048576;
  double* dH2b = dH2 + 1048576;
  double* dBc  = dH2b + 1048576;
  double* dBcA = dBc + 1048576;
  double* dHid = dBcA + 1048576;              // 4194304 d region (hid; overlaid later)
  float*  fZ2  = (float*)dHid;                //   z2: doubles [0 .. 2048000)
  double* dScg = dHid + 4194304;              // 4096
  double* dW6h = dScg + 4096;                 // 24576 each
  double* dW6a = dW6h + 24576;
  double* dW6b = dW6a + 24576;
  double* dW2h = dW6b + 24576;
  double* dW2a = dW2h + 24576;
  double* dW2b = dW2a + 24576;
  double* dPiH = dW2b + 24576;                // 28672 each
  double* dPiA = dPiH + 28672;
  double* dPiH2= dPiA + 28672;
  double* dMotD= dPiH2 + 28672;               // 16384
  float*  fMaskH = (float*)(dMotD + 16384);   // 4096
  float*  fMaskA = fMaskH + 4096;             // 4096
  float*  fMsgH  = fMaskA + 4096;             // 1048576 f
  float*  fCorr  = fMsgH + 1048576;           // 1048576 f
  float*  fMotF  = fCorr + 1048576;           // 16384
  float*  fC2    = fMotF + 16384;             // 128
  float*  fLse   = fC2 + 128;                 // 128
  float*  fBoost = fLse + 128;                // 1
  int*    iSel   = (int*)(fBoost + 1);        // 128
  int*    fW1    = iSel + 128;                // 4096 each
  int*    fW2    = fW1 + 4096;
  int*    fPi    = fW2 + 4096;
  int*    fM     = fPi + 4096;
  int*    cPi    = fM + 4096;
  int*    cW1    = cPi + 4096;
  int*    cM     = cW1 + 4096;
  int*    cM2    = cM + 4096;
  int*    iZero  = cM2 + 4096;

  // ---- trunk ----
  t_hid<<<dim3(16, 64), 256, 0, stream>>>(x, W1, b1, dHid);
  t_H<<<dim3(8, 2, 64), 256, 0, stream>>>(dHid, W2, b2, dH);
  n_scg<<<1024, 256, 0, stream>>>(dH, w_gate, dScg);
  n_mask_dual<<<1, 64, 0, stream>>>(dScg, fMaskH, fMaskA, fM);
  n_hs<<<4096, 256, 0, stream>>>(dH, fMaskH, dHs);
  n_w6x<<<4096, 64, 0, stream>>>(dHs, dHs, nidx, dW6h, dW6a, fW1);
  f_mp_mm<<<4096, 256, 0, stream>>>(dW6h, dHs, nidx, Wr, dHs, dH2);
  // ---- logp path ----
  n_motor<<<64, 256, 0, stream>>>(dH2, Wm, bm, dMotD, fMotF);
  n_gate<<<64, 64, 0, stream>>>(dMotD, Wg, iSel, fC2);
  k_z2<<<dim3(125, 7), 256, 0, stream>>>(fMotF, Wf, iSel, fZ2);
  k_lse<<<128, 256, 0, stream>>>(fZ2, fLse);
  k_logp<<<dim3(125, BB), 256, 0, stream>>>(fZ2, fC2, fLse, out_logp);
  k_loss<<<1, 64, 0, stream>>>(out_logp, targets, out_loss, fBoost);
  // ---- pass-2 hard -> msg_h ----
  n_pi_dual<<<1024, 256, 0, stream>>>(dH2, Wg, dPiH, dPiA, fPi);
  n_bc<<<4096, 256, 0, stream>>>(dH2, dPiH, e_fac, fBoost, dBc);
  n_w6x<<<4096, 64, 0, stream>>>(dH2, dBc, nidx, dW2h, dW2a, fW2);
  f_mp_msg<<<4096, 256, 0, stream>>>(dW2h, dBc, nidx, Wb, fMsgH);
  n_zero<<<4096, 256, 0, stream>>>(fCorr);
  n_izero<<<16, 256, 0, stream>>>(iZero);
  // ---- BR_W2 (sparse, nb clean) ----
  f_mp_corr_g<<<4096, 256, 0, stream>>>(dW2a, dBc, dBc, iZero, nidx, fW2, Wb, fMsgH, fCorr);
  // ---- BR_PI (sparse) ----
  n_bc_g<<<4096, 256, 0, stream>>>(dH2, dPiA, e_fac, fBoost, fPi, dBcA);
  n_close<<<16, 256, 0, stream>>>(fPi, nidx, cPi);
  n_w6_sel_g<<<4096, 64, 0, stream>>>(dH2, dH2, iZero, dBcA, dBc, fPi, nidx, cPi, dW2h, dW2b);
  f_mp_corr_g<<<4096, 256, 0, stream>>>(dW2b, dBcA, dBc, fPi, nidx, cPi, Wb, fMsgH, fCorr);
  // ---- BR_W1 (sparse) ----
  f_mp_h2_g<<<4096, 256, 0, stream>>>(dW6a, dHs, dHs, iZero, nidx, Wr, dHs, dHs, iZero, fW1, dH2b);
  n_pi_sel<<<1024, 256, 0, stream>>>(dH2b, Wg, fW1, dPiH, dPiH2);
  n_bc_g<<<4096, 256, 0, stream>>>(dH2b, dPiH2, e_fac, fBoost, fW1, dBcA);
  n_close<<<16, 256, 0, stream>>>(fW1, nidx, cW1);
  n_w6_sel_g<<<4096, 64, 0, stream>>>(dH2b, dH2, fW1, dBcA, dBc, fW1, nidx, cW1, dW2h, dW2b);
  f_mp_corr_g<<<4096, 256, 0, stream>>>(dW2b, dBcA, dBc, fW1, nidx, cW1, Wb, fMsgH, fCorr);
  // ---- BR_M (sparse) ----
  n_hs_g<<<4096, 256, 0, stream>>>(dH, fMaskA, fM, dHsM);
  n_close<<<16, 256, 0, stream>>>(fM, nidx, cM);
  n_w6_sel_g<<<4096, 64, 0, stream>>>(dHsM, dHs, fM, dHsM, dHs, fM, nidx, cM, dW6h, dW6b);
  f_mp_h2_g<<<4096, 256, 0, stream>>>(dW6b, dHsM, dHs, fM, nidx, Wr, dHsM, dHs, fM, cM, dH2b);
  n_pi_sel<<<1024, 256, 0, stream>>>(dH2b, Wg, cM, dPiH, dPiH2);
  n_bc_g<<<4096, 256, 0, stream>>>(dH2b, dPiH2, e_fac, fBoost, cM, dBcA);
  n_close<<<16, 256, 0, stream>>>(cM, nidx, cM2);
  n_w6_sel_g<<<4096, 64, 0, stream>>>(dH2b, dH2, cM, dBcA, dBc, cM, nidx, cM2, dW2h, dW2b);
  f_mp_corr_g<<<4096, 256, 0, stream>>>(dW2b, dBcA, dBc, cM, nidx, cM2, Wb, fMsgH, fCorr);
  // ---- final ----
  n_final<<<4096, 256, 0, stream>>>(fMsgH, fCorr, out_msg);
}

// Round 21
// 912.522 us; speedup vs baseline: 3.2151x; 1.0011x over previous
//
#include <hip/hip_runtime.h>

#define RR 64
#define BB 64
#define DD 256
#define DFF_ 1024
#define VV 32000
#define FF 7

#define TIE_BAND(a, b) (2e-6 * (1.0 + 0.5 * (fabs(a) + fabs(b))))
#define BR_CLAMP 0.30f
#define TOT_CLAMP 0.19f

__device__ __forceinline__ float clampf(float x, float c) {
  return fminf(fmaxf(x, -c), c);
}

// =================== tiled trunk kernels (register-blocked, order-identical) ===================

// hid = gelu(x@W1+b1); grid (16,64), 256 thr; tile 64b x 64f; thread 4b x 4f
__global__ void t_hid(const float* __restrict__ x, const float* __restrict__ W1,
                      const float* __restrict__ b1, double* __restrict__ hid) {
  int fc = blockIdx.x, r = blockIdx.y;
  int t = threadIdx.x;
  int fg = t & 15, bg = t >> 4;
  __shared__ float xs[64][65];
  __shared__ float w1t[64][64];
  double acc[4][4];
#pragma unroll
  for (int i = 0; i < 4; ++i)
#pragma unroll
    for (int j = 0; j < 4; ++j) acc[i][j] = 0.0;
  const float* xr = x + (size_t)r * BB * DD;
  const float* w1r = W1 + (size_t)r * DD * DFF_;
  for (int dt = 0; dt < 4; ++dt) {
    for (int i = t; i < 4096; i += 256) {
      int d = i & 63, b = i >> 6;
      xs[d][b] = xr[b * DD + dt * 64 + d];
    }
    for (int i = t; i < 4096; i += 256) {
      int dd = i >> 6, ff = i & 63;
      w1t[dd][ff] = w1r[(size_t)(dt * 64 + dd) * DFF_ + fc * 64 + ff];
    }
    __syncthreads();
    for (int d = 0; d < 64; ++d) {
      double bv[4], wv[4];
#pragma unroll
      for (int i = 0; i < 4; ++i) bv[i] = (double)xs[d][bg * 4 + i];
#pragma unroll
      for (int j = 0; j < 4; ++j) wv[j] = (double)w1t[d][fg * 4 + j];
#pragma unroll
      for (int i = 0; i < 4; ++i)
#pragma unroll
        for (int j = 0; j < 4; ++j) acc[i][j] += bv[i] * wv[j];
    }
    __syncthreads();
  }
#pragma unroll
  for (int i = 0; i < 4; ++i) {
    int b = bg * 4 + i;
#pragma unroll
    for (int j = 0; j < 4; ++j) {
      int f = fc * 64 + fg * 4 + j;
      double v = acc[i][j] + (double)b1[r * DFF_ + f];
      hid[((size_t)(r * BB + b)) * DFF_ + f] =
          0.5 * v * (1.0 + erf(v * 0.70710678118654752440));
    }
  }
}

// H = h + CTAU*h; grid (4,2,64), 256 thr; tile 32b x 64d; thread 4b x 2d
__global__ void t_H(const double* __restrict__ hid, const float* __restrict__ W2,
                    const float* __restrict__ b2, double* __restrict__ H) {
  int dc = blockIdx.x, bc = blockIdx.y, r = blockIdx.z;
  int t = threadIdx.x;
  int dg = t & 31, bg = t >> 5;
  __shared__ double ht[64][33];            // [f][b-half]
  __shared__ float wt[64][64];             // [f][d-chunk]
  double acc[4][2];
#pragma unroll
  for (int i = 0; i < 4; ++i)
#pragma unroll
    for (int j = 0; j < 2; ++j) acc[i][j] = 0.0;
  const double* hr = hid + (size_t)r * BB * DFF_;
  const float* w2r = W2 + (size_t)r * DFF_ * DD;
  for (int ft = 0; ft < 16; ++ft) {
    for (int i = t; i < 2048; i += 256) {
      int f = i & 63, b = i >> 6;
      ht[f][b] = hr[(size_t)(bc * 32 + b) * DFF_ + ft * 64 + f];
    }
    for (int i = t; i < 4096; i += 256) {
      int f = i >> 6, d = i & 63;
      wt[f][d] = w2r[(size_t)(ft * 64 + f) * DD + dc * 64 + d];
    }
    __syncthreads();
    for (int f = 0; f < 64; ++f) {         // global k ascending
      double hb[4], wv[2];
#pragma unroll
      for (int i = 0; i < 4; ++i) hb[i] = ht[f][bg * 4 + i];
#pragma unroll
      for (int j = 0; j < 2; ++j) wv[j] = (double)wt[f][dg * 2 + j];
#pragma unroll
      for (int i = 0; i < 4; ++i)
#pragma unroll
        for (int j = 0; j < 2; ++j) acc[i][j] += hb[i] * wv[j];
    }
    __syncthreads();
  }
#pragma unroll
  for (int i = 0; i < 4; ++i) {
    int b = bc * 32 + bg * 4 + i;
#pragma unroll
    for (int j = 0; j < 2; ++j) {
      int d = dc * 64 + dg * 2 + j;
      double h = acc[i][j] + (double)b2[r * DD + d];
      H[((size_t)(r * BB + b)) * DD + d] = h + 0.20333333 * h;
    }
  }
}

// =================== staged gate kernels (lane-0 serial, bitwise-frozen order) ===================

__global__ void n_scg(const double* __restrict__ H, const float* __restrict__ wg,
                      double* __restrict__ scg) {
  __shared__ double hbuf[4][256];
  __shared__ float wgs[256];
  int t = threadIdx.x;
  int wv = t >> 6, lane = t & 63;
  int idx = blockIdx.x * 4 + wv;
  int r = idx >> 6, b = idx & 63;
  const double* hp = H + (size_t)idx * DD;
  wgs[t] = wg[t];
#pragma unroll
  for (int j = 0; j < 4; ++j) hbuf[wv][lane + j * 64] = hp[lane + j * 64];
  __syncthreads();
  if (lane == 0) {
    double a = 0.0;
    for (int d = 0; d < DD; ++d) a += hbuf[wv][d] * (double)wgs[d];
    scg[b * RR + r] = a;
  }
}

__global__ void n_mask_dual(const double* __restrict__ scg, float* __restrict__ maskH,
                            float* __restrict__ maskA, int* __restrict__ flagM) {
  int b = threadIdx.x;
  double v[64], w[64];
  for (int r = 0; r < RR; ++r) { v[r] = scg[b * RR + r]; w[r] = v[r]; }
  double k6 = 0.0, k7 = 0.0;
  int i6 = -1, i7 = -1;
  for (int it = 0; it < 7; ++it) {
    int mi = 0;
    for (int r = 1; r < RR; ++r) if (w[r] > w[mi]) mi = r;
    if (it == 5) { k6 = w[mi]; i6 = mi; }
    if (it == 6) { k7 = w[mi]; i7 = mi; }
    w[mi] = -INFINITY;
  }
  double gap = k6 - k7;
  int tie = (gap > 0.0 && gap < TIE_BAND(k6, k7)) ? 1 : 0;
  for (int r = 0; r < RR; ++r) {
    float mh = (v[r] >= k6 || r == 0 || r == RR - 1) ? 1.f : 0.f;
    maskH[b * RR + r] = mh;
    maskA[b * RR + r] = tie ? ((v[r] >= k7 || r == 0 || r == RR - 1) ? 1.f : 0.f) : mh;
    flagM[r * BB + b] = 0;
  }
  if (tie) {
    flagM[i6 * BB + b] = 1;
    flagM[i7 * BB + b] = 1;
  }
}

__global__ void n_hs(const double* __restrict__ H, const float* __restrict__ mask,
                     double* __restrict__ Hs) {
  int idx = blockIdx.x * 256 + threadIdx.x;
  int r = idx >> 14;
  int b = (idx >> 8) & 63;
  Hs[idx] = H[idx] * (double)mask[b * RR + r];
}

__global__ void n_hs_g(const double* __restrict__ H, const float* __restrict__ maskA,
                       const int* __restrict__ gate, double* __restrict__ HsM) {
  int rb = blockIdx.x;
  if (!gate[rb]) return;
  int t = threadIdx.x;
  size_t i = (size_t)rb * DD + t;
  int r = rb >> 6, b = rb & 63;
  HsM[i] = H[i] * (double)maskA[b * RR + r];
}

// top-4 gated softmax: block-per-site, staged, lane-0 serial ; 4096 blocks x 64
__global__ void n_w6x(const double* __restrict__ self, const double* __restrict__ nb,
                      const int* __restrict__ nidx, double* __restrict__ wout,
                      double* __restrict__ walt, int* __restrict__ flag) {
  __shared__ double sbuf[256];
  __shared__ double qbuf[6][256];
  int idx = blockIdx.x;
  int r = idx >> 6, b = idx & 63;
  int lane = threadIdx.x;
  const double* sp = self + (size_t)idx * DD;
#pragma unroll
  for (int j = 0; j < 4; ++j) sbuf[lane + j * 64] = sp[lane + j * 64];
  for (int k = 0; k < 6; ++k) {
    int nr = nidx[r * 6 + k];
    const double* qp = nb + ((size_t)(nr * BB + b)) * DD;
#pragma unroll
    for (int j = 0; j < 4; ++j) qbuf[k][lane + j * 64] = qp[lane + j * 64];
  }
  __syncthreads();
  if (lane == 0) {
    double sc[6];
    for (int k = 0; k < 6; ++k) {
      double a = 0.0;
      for (int d = 0; d < DD; ++d) a += sbuf[d] * qbuf[k][d];
      sc[k] = a * 0.0625;
    }
    double srt[6];
    for (int k = 0; k < 6; ++k) srt[k] = sc[k];
    for (int i = 0; i < 5; ++i) {
      int mi = i;
      for (int j = i + 1; j < 6; ++j) if (srt[j] > srt[mi]) mi = j;
      double tmp = srt[i]; srt[i] = srt[mi]; srt[mi] = tmp;
    }
    double s4 = srt[3], s5 = srt[4], mx = srt[0];
    double e[6], s = 0.0;
    for (int k = 0; k < 6; ++k) {
      e[k] = (sc[k] >= s4) ? exp(sc[k] - mx) : 0.0;
      s += e[k];
    }
    for (int k = 0; k < 6; ++k) wout[(size_t)idx * 6 + k] = e[k] / s;
    double gap = s4 - s5;
    int inband = (gap > 0.0 && gap < TIE_BAND(s4, s5)) ? 1 : 0;
    flag[idx] = inband;
    if (inband) {
      double ea[6], sa = 0.0;
      for (int k = 0; k < 6; ++k) {
        ea[k] = (sc[k] >= s5) ? exp(sc[k] - mx) : 0.0;   // inclusive keep-5
        sa += ea[k];
      }
      for (int k = 0; k < 6; ++k) walt[(size_t)idx * 6 + k] = ea[k] / sa;
    } else {
      for (int k = 0; k < 6; ++k) walt[(size_t)idx * 6 + k] = e[k] / s;
    }
  }
}

// dual-source recompute-or-copy hard top-4 softmax ; 4096 blocks x 64
__global__ void n_w6_sel_g(const double* __restrict__ selfD, const double* __restrict__ selfC,
                           const int* __restrict__ flagS,
                           const double* __restrict__ nbD, const double* __restrict__ nbC,
                           const int* __restrict__ flagN,
                           const int* __restrict__ nidx, const int* __restrict__ gate,
                           const double* __restrict__ wH, double* __restrict__ wout) {
  __shared__ double sbuf[256];
  __shared__ double qbuf[6][256];
  int idx = blockIdx.x;
  int r = idx >> 6, b = idx & 63;
  int lane = threadIdx.x;
  int g = gate[idx];
  if (g) {
    const double* sp = (flagS[idx] ? selfD : selfC) + (size_t)idx * DD;
#pragma unroll
    for (int j = 0; j < 4; ++j) sbuf[lane + j * 64] = sp[lane + j * 64];
    for (int k = 0; k < 6; ++k) {
      int nr = nidx[r * 6 + k];
      int ni = nr * BB + b;
      const double* qp = (flagN[ni] ? nbD : nbC) + (size_t)ni * DD;
#pragma unroll
      for (int j = 0; j < 4; ++j) qbuf[k][lane + j * 64] = qp[lane + j * 64];
    }
  }
  __syncthreads();
  if (!g) {
    if (lane < 6) wout[(size_t)idx * 6 + lane] = wH[(size_t)idx * 6 + lane];
    return;
  }
  if (lane == 0) {
    double sc[6];
    for (int k = 0; k < 6; ++k) {
      double a = 0.0;
      for (int d = 0; d < DD; ++d) a += sbuf[d] * qbuf[k][d];
      sc[k] = a * 0.0625;
    }
    double srt[6];
    for (int k = 0; k < 6; ++k) srt[k] = sc[k];
    for (int i = 0; i < 4; ++i) {
      int mi = i;
      for (int j = i + 1; j < 6; ++j) if (srt[j] > srt[mi]) mi = j;
      double tmp = srt[i]; srt[i] = srt[mi]; srt[mi] = tmp;
    }
    double s4 = srt[3], mx = srt[0];
    double e[6], s = 0.0;
    for (int k = 0; k < 6; ++k) {
      e[k] = (sc[k] >= s4) ? exp(sc[k] - mx) : 0.0;
      s += e[k];
    }
    for (int k = 0; k < 6; ++k) wout[(size_t)idx * 6 + k] = e[k] / s;
  }
}

// =================== fused mp -> consumer kernels ===================

__global__ void f_mp_mm(const double* __restrict__ w, const double* __restrict__ nb,
                        const int* __restrict__ nidx, const float* __restrict__ Wmat,
                        const double* __restrict__ Hs, double* __restrict__ H2) {
  __shared__ double mpL[256];
  int rb = blockIdx.x;
  int r = rb >> 6, b = rb & 63;
  int t = threadIdx.x;
  double a = 0.0;
  for (int k = 0; k < 6; ++k) {
    int nr = nidx[r * 6 + k];
    a += w[(size_t)rb * 6 + k] * nb[((size_t)(nr * BB + b)) * DD + t];
  }
  mpL[t] = a;
  __syncthreads();
  double s2 = 0.0;
  for (int d = 0; d < DD; ++d) s2 += mpL[d] * (double)Wmat[d * DD + t];
  size_t i = (size_t)rb * DD + t;
  H2[i] = Hs[i] + s2;
}

// msgH = f32(mp @ Wmat); also zeroes corr ; 4096 blocks x 256
__global__ void f_mp_msg(const double* __restrict__ w, const double* __restrict__ nb,
                         const int* __restrict__ nidx, const float* __restrict__ Wmat,
                         float* __restrict__ msgH, float* __restrict__ corr) {
  __shared__ double mpL[256];
  int rb = blockIdx.x;
  int r = rb >> 6, b = rb & 63;
  int t = threadIdx.x;
  double a = 0.0;
  for (int k = 0; k < 6; ++k) {
    int nr = nidx[r * 6 + k];
    a += w[(size_t)rb * 6 + k] * nb[((size_t)(nr * BB + b)) * DD + t];
  }
  mpL[t] = a;
  __syncthreads();
  double s2 = 0.0;
  for (int d = 0; d < DD; ++d) s2 += mpL[d] * (double)Wmat[d * DD + t];
  size_t i = (size_t)rb * DD + t;
  msgH[i] = (float)s2;
  corr[i] = 0.f;
}

__global__ void f_mp_corr_g(const double* __restrict__ w,
                            const double* __restrict__ nbD, const double* __restrict__ nbC,
                            const int* __restrict__ flagN,
                            const int* __restrict__ nidx, const int* __restrict__ gate,
                            const float* __restrict__ Wmat, const float* __restrict__ msgH,
                            float* __restrict__ corr) {
  int rb = blockIdx.x;
  if (!gate[rb]) return;
  __shared__ double mpL[256];
  int r = rb >> 6, b = rb & 63;
  int t = threadIdx.x;
  double a = 0.0;
  for (int k = 0; k < 6; ++k) {
    int nr = nidx[r * 6 + k];
    int ni = nr * BB + b;
    const double* q = flagN[ni] ? nbD : nbC;
    a += w[(size_t)rb * 6 + k] * q[(size_t)ni * DD + t];
  }
  mpL[t] = a;
  __syncthreads();
  double s2 = 0.0;
  for (int d = 0; d < DD; ++d) s2 += mpL[d] * (double)Wmat[d * DD + t];
  size_t i = (size_t)rb * DD + t;
  corr[i] += clampf((float)s2 - msgH[i], BR_CLAMP);
}

__global__ void f_mp_h2_g(const double* __restrict__ w,
                          const double* __restrict__ nbD, const double* __restrict__ nbC,
                          const int* __restrict__ flagN,
                          const int* __restrict__ nidx, const float* __restrict__ Wmat,
                          const double* __restrict__ HsD, const double* __restrict__ HsC,
                          const int* __restrict__ flagHs,
                          const int* __restrict__ gate, double* __restrict__ H2out) {
  int rb = blockIdx.x;
  if (!gate[rb]) return;
  __shared__ double mpL[256];
  int r = rb >> 6, b = rb & 63;
  int t = threadIdx.x;
  double a = 0.0;
  for (int k = 0; k < 6; ++k) {
    int nr = nidx[r * 6 + k];
    int ni = nr * BB + b;
    const double* q = flagN[ni] ? nbD : nbC;
    a += w[(size_t)rb * 6 + k] * q[(size_t)ni * DD + t];
  }
  mpL[t] = a;
  __syncthreads();
  double s2 = 0.0;
  for (int d = 0; d < DD; ++d) s2 += mpL[d] * (double)Wmat[d * DD + t];
  size_t i = (size_t)rb * DD + t;
  const double* hs = flagHs[rb] ? HsD : HsC;
  H2out[i] = hs[i] + s2;
}

// =================== fused pi -> Bc kernels ===================

// hard: computes pi (lane-0 serial, frozen order), writes piA+flag, then Bc ; 1024 blocks x 256
__global__ void f_pibc(const double* __restrict__ H2, const float* __restrict__ Wg,
                       const float* __restrict__ e_fac, const float* __restrict__ boost_p,
                       double* __restrict__ piA, int* __restrict__ flag,
                       double* __restrict__ Bc) {
  __shared__ double hbuf[4][256];
  __shared__ float wgb[1792];
  __shared__ double piL[4][FF];
  int t = threadIdx.x;
  int wv = t >> 6, lane = t & 63;
  int idx = blockIdx.x * 4 + wv;
  const double* hp = H2 + (size_t)idx * DD;
#pragma unroll
  for (int j = 0; j < 4; ++j) hbuf[wv][lane + j * 64] = hp[lane + j * 64];
  for (int i = t; i < 1792; i += 256) wgb[i] = Wg[i];
  __syncthreads();
  if (lane == 0) {
    double gb[FF];
    for (int f = 0; f < FF; ++f) {
      double a = 0.0;
      for (int d = 0; d < DD; ++d) a += hbuf[wv][d] * (double)wgb[d * FF + f];
      gb[f] = a;
    }
    double srt[FF];
    for (int f = 0; f < FF; ++f) srt[f] = gb[f];
    for (int i = 0; i < 3; ++i) {
      int mi = i;
      for (int j = i + 1; j < FF; ++j) if (srt[j] > srt[mi]) mi = j;
      double tp = srt[i]; srt[i] = srt[mi]; srt[mi] = tp;
    }
    double m1 = srt[0], m2 = srt[1], m3 = srt[2];
    double e[FF], s = 0.0;
    for (int f = 0; f < FF; ++f) {
      e[f] = (gb[f] >= m2) ? exp(gb[f] - m1) : 0.0;
      s += e[f];
    }
    for (int f = 0; f < FF; ++f) piL[wv][f] = e[f] / s;
    double gap = m2 - m3;
    int inband = (gap > 0.0 && gap < TIE_BAND(m2, m3)) ? 1 : 0;
    flag[idx] = inband;
    if (inband) {
      double ea[FF], sa = 0.0;
      for (int f = 0; f < FF; ++f) {
        ea[f] = (gb[f] >= m3) ? exp(gb[f] - m1) : 0.0;   // inclusive keep-3
        sa += ea[f];
      }
      for (int f = 0; f < FF; ++f) piA[(size_t)idx * FF + f] = ea[f] / sa;
    } else {
      for (int f = 0; f < FF; ++f) piA[(size_t)idx * FF + f] = e[f] / s;
    }
  }
  __syncthreads();
  double boost = (double)(*boost_p);
#pragma unroll
  for (int j = 0; j < 4; ++j) {
    int d = lane + j * 64;
    double ef = 0.0;
    for (int f = 0; f < FF; ++f) ef += piL[wv][f] * (double)e_fac[f * DD + d];
    Bc[(size_t)idx * DD + d] = hbuf[wv][d] * ef * boost;
  }
}

// branch: gated; computes hard pi from H2src then Bc2 (no pi output) ; 1024 blocks x 256
__global__ void f_pibc_g(const double* __restrict__ H2src, const float* __restrict__ Wg,
                         const float* __restrict__ e_fac, const float* __restrict__ boost_p,
                         const int* __restrict__ gate, double* __restrict__ Bc2) {
  __shared__ double hbuf[4][256];
  __shared__ float wgb[1792];
  __shared__ double piL[4][FF];
  int t = threadIdx.x;
  int wv = t >> 6, lane = t & 63;
  int idx = blockIdx.x * 4 + wv;
  int g = gate[idx];
  if (g) {
    const double* hp = H2src + (size_t)idx * DD;
#pragma unroll
    for (int j = 0; j < 4; ++j) hbuf[wv][lane + j * 64] = hp[lane + j * 64];
  }
  for (int i = t; i < 1792; i += 256) wgb[i] = Wg[i];
  __syncthreads();
  if (g && lane == 0) {
    double gb[FF];
    for (int f = 0; f < FF; ++f) {
      double a = 0.0;
      for (int d = 0; d < DD; ++d) a += hbuf[wv][d] * (double)wgb[d * FF + f];
      gb[f] = a;
    }
    double m1 = -INFINITY, m2 = -INFINITY;
    for (int f = 0; f < FF; ++f) {
      if (gb[f] > m1) { m2 = m1; m1 = gb[f]; }
      else if (gb[f] > m2) { m2 = gb[f]; }
    }
    double e[FF], s = 0.0;
    for (int f = 0; f < FF; ++f) {
      e[f] = (gb[f] >= m2) ? exp(gb[f] - m1) : 0.0;
      s += e[f];
    }
    for (int f = 0; f < FF; ++f) piL[wv][f] = e[f] / s;
  }
  __syncthreads();
  if (!g) return;
  double boost = (double)(*boost_p);
#pragma unroll
  for (int j = 0; j < 4; ++j) {
    int d = lane + j * 64;
    double ef = 0.0;
    for (int f = 0; f < FF; ++f) ef += piL[wv][f] * (double)e_fac[f * DD + d];
    Bc2[(size_t)idx * DD + d] = hbuf[wv][d] * ef * boost;
  }
}

// Bc dirty-only from piA (BR_PI) ; 4096 blocks x 256
__global__ void n_bc_g(const double* __restrict__ H2src, const double* __restrict__ pi,
                       const float* __restrict__ e_fac, const float* __restrict__ boost_p,
                       const int* __restrict__ gate, double* __restrict__ Bc2) {
  int rb = blockIdx.x;
  if (!gate[rb]) return;
  int t = threadIdx.x;
  size_t i = (size_t)rb * DD + t;
  double ef = 0.0;
  for (int f = 0; f < FF; ++f) ef += pi[(size_t)rb * FF + f] * (double)e_fac[f * DD + t];
  double boost = (double)(*boost_p);
  Bc2[i] = H2src[i] * ef * boost;
}

// =================== misc kernels ===================

__global__ void n_final(const float* __restrict__ msgH, const float* __restrict__ corr,
                        float* __restrict__ out) {
  int i = blockIdx.x * 256 + threadIdx.x;
  out[i] = msgH[i] + clampf(corr[i], TOT_CLAMP);
}

__global__ void n_izero(int* __restrict__ p) {
  p[blockIdx.x * 256 + threadIdx.x] = 0;
}

// closure of 2 independent flag arrays ; 32 blocks x 256
__global__ void n_close2(const int* __restrict__ inA, int* __restrict__ outA,
                         const int* __restrict__ inB, int* __restrict__ outB,
                         const int* __restrict__ nidx) {
  int gi = blockIdx.x * 256 + threadIdx.x;
  const int* in = (gi < 4096) ? inA : inB;
  int* out = (gi < 4096) ? outA : outB;
  int idx = gi & 4095;
  int r = idx >> 6, b = idx & 63;
  int v = in[idx];
  for (int k = 0; k < 6; ++k) v |= in[nidx[r * 6 + k] * BB + b];
  out[idx] = v;
}

__global__ void n_motor(const double* __restrict__ H2, const float* __restrict__ Wm,
                        const float* __restrict__ bm, double* __restrict__ motD,
                        float* __restrict__ motF) {
  int b = blockIdx.x, t = threadIdx.x;
  const double* hp = H2 + ((size_t)((RR - 1) * BB + b)) * DD;
  double a = 0.0;
  for (int d = 0; d < DD; ++d) a += hp[d] * (double)Wm[d * DD + t];
  double mo = a + (double)bm[t];
  motD[b * DD + t] = mo;
  motF[b * DD + t] = (float)mo;
}

__global__ void n_gate(const double* __restrict__ motD, const float* __restrict__ Wg,
                       int* __restrict__ sel, float* __restrict__ c2) {
  __shared__ double mbuf[256];
  __shared__ float wgb[1792];
  int b = blockIdx.x;
  int lane = threadIdx.x;
#pragma unroll
  for (int j = 0; j < 4; ++j) mbuf[lane + j * 64] = motD[b * DD + lane + j * 64];
  for (int i = lane; i < 1792; i += 64) wgb[i] = Wg[i];
  __syncthreads();
  if (lane == 0) {
    double g[FF];
    for (int f = 0; f < FF; ++f) {
      double a = 0.0;
      for (int d = 0; d < DD; ++d) a += mbuf[d] * (double)wgb[d * FF + f];
      g[f] = a;
    }
    double m1 = -INFINITY, m2 = -INFINITY;
    int i1 = -1, i2 = -1;
    for (int f = 0; f < FF; ++f) {
      if (g[f] > m1) { m2 = m1; i2 = i1; m1 = g[f]; i1 = f; }
      else if (g[f] > m2) { m2 = g[f]; i2 = f; }
    }
    double s = 0.0;
    for (int f = 0; f < FF; ++f)
      if (g[f] >= m2) s += exp(g[f] - m1);
    double lse = m1 + log(s);
    sel[b * 2 + 0] = i1;
    sel[b * 2 + 1] = i2;
    c2[b * 2 + 0] = (float)(g[i1] - lse);
    c2[b * 2 + 1] = (float)(g[i2] - lse);
  }
}

// =================== f32 logp-path kernels ===================

__global__ void k_z2(const float* __restrict__ motor, const float* __restrict__ Wf,
                     const int* __restrict__ sel, float* __restrict__ z2) {
  int vc = blockIdx.x, f = blockIdx.y;
  int t = threadIdx.x;
  int vg = t & 31, bg = t >> 5;
  __shared__ float mt[16][65];
  __shared__ float wt[16][256];
  __shared__ int selL[128];
  if (t < 128) selL[t] = sel[t];
  float acc[8][8];
#pragma unroll
  for (int i = 0; i < 8; ++i)
#pragma unroll
    for (int j = 0; j < 8; ++j) acc[i][j] = 0.f;
  const float* wf = Wf + (size_t)f * DD * VV;
  for (int dt = 0; dt < 16; ++dt) {
    for (int i = t; i < 1024; i += 256) {
      int d = i & 15, b = i >> 4;
      mt[d][b] = motor[b * DD + dt * 16 + d];
    }
    for (int i = t; i < 4096; i += 256) {
      int d = i >> 8, v = i & 255;
      wt[d][v] = wf[(size_t)(dt * 16 + d) * VV + vc * 256 + v];
    }
    __syncthreads();
    for (int d = 0; d < 16; ++d) {
      float bv[8], wv[8];
#pragma unroll
      for (int i = 0; i < 8; ++i) bv[i] = mt[d][bg * 8 + i];
#pragma unroll
      for (int j = 0; j < 8; ++j) wv[j] = wt[d][vg + j * 32];
#pragma unroll
      for (int i = 0; i < 8; ++i)
#pragma unroll
        for (int j = 0; j < 8; ++j) acc[i][j] += bv[i] * wv[j];
    }
    __syncthreads();
  }
#pragma unroll
  for (int i = 0; i < 8; ++i) {
    int b = bg * 8 + i;
    int s0 = selL[b * 2 + 0], s1 = selL[b * 2 + 1];
    if (s0 == f) {
#pragma unroll
      for (int j = 0; j < 8; ++j)
        z2[((size_t)(b * 2 + 0)) * VV + vc * 256 + vg + j * 32] = acc[i][j];
    }
    if (s1 == f) {
#pragma unroll
      for (int j = 0; j < 8; ++j)
        z2[((size_t)(b * 2 + 1)) * VV + vc * 256 + vg + j * 32] = acc[i][j];
    }
  }
}

__global__ void k_lse(const float* __restrict__ z2, float* __restrict__ lse) {
  int row = blockIdx.x;
  int t = threadIdx.x;
  const float* zp = z2 + (size_t)row * VV;
  float m = -INFINITY, s = 0.f;
  for (int v = t; v < VV; v += 256) {
    float val = zp[v];
    if (val > m) { s = s * expf(m - val) + 1.f; m = val; }
    else s += expf(val - m);
  }
  __shared__ float sm[256], ss[256];
  sm[t] = m; ss[t] = s;
  __syncthreads();
  for (int off = 128; off > 0; off >>= 1) {
    if (t < off) {
      float m2 = sm[t + off], s2 = ss[t + off], m1 = sm[t], s1 = ss[t];
      float M = fmaxf(m1, m2);
      sm[t] = M;
      ss[t] = s1 * expf(m1 - M) + s2 * expf(m2 - M);
    }
    __syncthreads();
  }
  if (t == 0) lse[row] = sm[0] + logf(ss[0]);
}

__global__ void k_logp(const float* __restrict__ z2, const float* __restrict__ c2,
                       const float* __restrict__ lse, float* __restrict__ out_logp) {
  int b = blockIdx.y;
  int v = blockIdx.x * 256 + threadIdx.x;
  float a0 = c2[b * 2 + 0] - lse[b * 2 + 0] + z2[((size_t)(b * 2 + 0)) * VV + v];
  float a1 = c2[b * 2 + 1] - lse[b * 2 + 1] + z2[((size_t)(b * 2 + 1)) * VV + v];
  float M = fmaxf(a0, a1);
  out_logp[(size_t)b * VV + v] = M + logf(expf(a0 - M) + expf(a1 - M));
}

__global__ void k_loss(const float* __restrict__ out_logp, const int* __restrict__ targets,
                       float* __restrict__ out_loss, float* __restrict__ boost) {
  int b = threadIdx.x;
  float v = out_logp[(size_t)b * VV + targets[b]];
#pragma unroll
  for (int off = 32; off > 0; off >>= 1) v += __shfl_xor(v, off, 64);
  if (b == 0) {
    float loss = -v / 64.f;
    *out_loss = loss;
    *boost = 1.f + 2.f * ((loss > 0.7f) ? 1.f : 0.f);
  }
}

// =================== launch ===================
extern "C" void kernel_launch(void* const* d_in, const int* in_sizes, int n_in,
                              void* d_out, int out_size, void* d_ws, size_t ws_size,
                              hipStream_t stream) {
  const float* x       = (const float*)d_in[0];
  const int*   targets = (const int*)d_in[1];
  const int*   nidx    = (const int*)d_in[2];
  const float* W1      = (const float*)d_in[3];
  const float* b1      = (const float*)d_in[4];
  const float* W2      = (const float*)d_in[5];
  const float* b2      = (const float*)d_in[6];
  const float* w_gate  = (const float*)d_in[7];
  const float* Wr      = (const float*)d_in[8];
  const float* Wm      = (const float*)d_in[9];
  const float* bm      = (const float*)d_in[10];
  const float* Wg      = (const float*)d_in[11];
  const float* Wf      = (const float*)d_in[12];
  const float* e_fac   = (const float*)d_in[13];
  const float* Wb      = (const float*)d_in[14];

  float* out_logp = (float*)d_out;
  float* out_loss = out_logp + (size_t)BB * VV;
  float* out_msg  = out_loss + 1;

  double* dH   = (double*)d_ws;               // 1048576 d each
  double* dHs  = dH + 1048576;
  double* dHsM = dHs + 1048576;
  double* dH2  = dHsM + 1048576;
  double* dH2b = dH2 + 1048576;
  double* dBc  = dH2b + 1048576;
  double* dBcA = dBc + 1048576;
  double* dHid = dBcA + 1048576;              // 4194304 d region (hid; overlaid later)
  float*  fZ2  = (float*)dHid;                //   z2: doubles [0 .. 2048000)
  double* dScg = dHid + 4194304;              // 4096
  double* dW6h = dScg + 4096;                 // 24576 each
  double* dW6a = dW6h + 24576;
  double* dW6b = dW6a + 24576;
  double* dW2h = dW6b + 24576;
  double* dW2a = dW2h + 24576;
  double* dW2b = dW2a + 24576;
  double* dPiA = dW2b + 24576;                // 28672
  double* dMotD= dPiA + 28672;                // 16384
  float*  fMaskH = (float*)(dMotD + 16384);   // 4096
  float*  fMaskA = fMaskH + 4096;             // 4096
  float*  fMsgH  = fMaskA + 4096;             // 1048576 f
  float*  fCorr  = fMsgH + 1048576;           // 1048576 f
  float*  fMotF  = fCorr + 1048576;           // 16384
  float*  fC2    = fMotF + 16384;             // 128
  float*  fLse   = fC2 + 128;                 // 128
  float*  fBoost = fLse + 128;                // 1
  int*    iSel   = (int*)(fBoost + 1);        // 128
  int*    fW1    = iSel + 128;                // 4096 each
  int*    fW2    = fW1 + 4096;
  int*    fPi    = fW2 + 4096;
  int*    fM     = fPi + 4096;
  int*    cPi    = fM + 4096;
  int*    cW1    = cPi + 4096;
  int*    cM     = cW1 + 4096;
  int*    cM2    = cM + 4096;
  int*    iZero  = cM2 + 4096;

  // ---- trunk ----
  t_hid<<<dim3(16, 64), 256, 0, stream>>>(x, W1, b1, dHid);
  t_H<<<dim3(4, 2, 64), 256, 0, stream>>>(dHid, W2, b2, dH);
  n_scg<<<1024, 256, 0, stream>>>(dH, w_gate, dScg);
  n_mask_dual<<<1, 64, 0, stream>>>(dScg, fMaskH, fMaskA, fM);
  n_hs<<<4096, 256, 0, stream>>>(dH, fMaskH, dHs);
  n_izero<<<16, 256, 0, stream>>>(iZero);
  n_w6x<<<4096, 64, 0, stream>>>(dHs, dHs, nidx, dW6h, dW6a, fW1);
  f_mp_mm<<<4096, 256, 0, stream>>>(dW6h, dHs, nidx, Wr, dHs, dH2);
  // ---- logp path ----
  n_motor<<<64, 256, 0, stream>>>(dH2, Wm, bm, dMotD, fMotF);
  n_gate<<<64, 64, 0, stream>>>(dMotD, Wg, iSel, fC2);
  k_z2<<<dim3(125, 7), 256, 0, stream>>>(fMotF, Wf, iSel, fZ2);
  k_lse<<<128, 256, 0, stream>>>(fZ2, fLse);
  k_logp<<<dim3(125, BB), 256, 0, stream>>>(fZ2, fC2, fLse, out_logp);
  k_loss<<<1, 64, 0, stream>>>(out_logp, targets, out_loss, fBoost);
  // ---- pass-2 hard -> msg_h ----
  f_pibc<<<1024, 256, 0, stream>>>(dH2, Wg, e_fac, fBoost, dPiA, fPi, dBc);
  n_w6x<<<4096, 64, 0, stream>>>(dH2, dBc, nidx, dW2h, dW2a, fW2);
  f_mp_msg<<<4096, 256, 0, stream>>>(dW2h, dBc, nidx, Wb, fMsgH, fCorr);
  // closures for W1 and M (flags ready early)
  n_close2<<<32, 256, 0, stream>>>(fW1, cW1, fM, cM, nidx);
  // ---- BR_W2 (sparse, nb clean) ----
  f_mp_corr_g<<<4096, 256, 0, stream>>>(dW2a, dBc, dBc, iZero, nidx, fW2, Wb, fMsgH, fCorr);
  // ---- BR_PI (sparse) ----
  n_bc_g<<<4096, 256, 0, stream>>>(dH2, dPiA, e_fac, fBoost, fPi, dBcA);
  n_close2<<<32, 256, 0, stream>>>(fPi, cPi, cM, cM2, nidx);
  n_w6_sel_g<<<4096, 64, 0, stream>>>(dH2, dH2, iZero, dBcA, dBc, fPi, nidx, cPi, dW2h, dW2b);
  f_mp_corr_g<<<4096, 256, 0, stream>>>(dW2b, dBcA, dBc, fPi, nidx, cPi, Wb, fMsgH, fCorr);
  // ---- BR_W1 (sparse) ----
  f_mp_h2_g<<<4096, 256, 0, stream>>>(dW6a, dHs, dHs, iZero, nidx, Wr, dHs, dHs, iZero, fW1, dH2b);
  f_pibc_g<<<1024, 256, 0, stream>>>(dH2b, Wg, e_fac, fBoost, fW1, dBcA);
  n_w6_sel_g<<<4096, 64, 0, stream>>>(dH2b, dH2, fW1, dBcA, dBc, fW1, nidx, cW1, dW2h, dW2b);
  f_mp_corr_g<<<4096, 256, 0, stream>>>(dW2b, dBcA, dBc, fW1, nidx, cW1, Wb, fMsgH, fCorr);
  // ---- BR_M (sparse) ----
  n_hs_g<<<4096, 256, 0, stream>>>(dH, fMaskA, fM, dHsM);
  n_w6_sel_g<<<4096, 64, 0, stream>>>(dHsM, dHs, fM, dHsM, dHs, fM, nidx, cM, dW6h, dW6b);
  f_mp_h2_g<<<4096, 256, 0, stream>>>(dW6b, dHsM, dHs, fM, nidx, Wr, dHsM, dHs, fM, cM, dH2b);
  f_pibc_g<<<1024, 256, 0, stream>>>(dH2b, Wg, e_fac, fBoost, cM, dBcA);
  n_w6_sel_g<<<4096, 64, 0, stream>>>(dH2b, dH2, cM, dBcA, dBc, cM, nidx, cM2, dW2h, dW2b);
  f_mp_corr_g<<<4096, 256, 0, stream>>>(dW2b, dBcA, dBc, cM, nidx, cM2, Wb, fMsgH, fCorr);
  // ---- final ----
  n_final<<<4096, 256, 0, stream>>>(fMsgH, fCorr, out_msg);
}